// Round 2
// baseline (1441.816 us; speedup 1.0000x reference)
//
#include <hip/hip_runtime.h>

// Problem constants
constexpr int kB = 8;
constexpr int kN = 2046;
constexpr int kC = 2048;   // kN + 2
constexpr int kD = 128;
constexpr int kJ = 128;
constexpr int kL = 2;

// ---------- bf16 helpers ----------
__device__ __forceinline__ float bf2f(unsigned short h) {
  union { unsigned u; float f; } x; x.u = ((unsigned)h) << 16; return x.f;
}
__device__ __forceinline__ unsigned short f2bf(float f) {
  union { float f; unsigned u; } x; x.f = f;
  unsigned u = x.u;
  if ((u & 0x7fffffffu) > 0x7f800000u) return (unsigned short)((u >> 16) | 0x40);
  return (unsigned short)((u + 0x7fffu + ((u >> 16) & 1u)) >> 16);
}

// ---------- workspace layout (float offsets) ----------
constexpr size_t OF_FEATS  = 0;
constexpr size_t OF_SEQ    = OF_FEATS + (size_t)kB * kC * kD;
constexpr size_t OF_ATTN   = OF_SEQ   + (size_t)kB * kC * kD;
constexpr size_t OF_V      = OF_ATTN  + (size_t)kB * kC * kD;
constexpr size_t OF_SQ     = OF_V     + (size_t)kB * kC * kD;
constexpr size_t OF_SK     = OF_SQ    + (size_t)kB * kC;
constexpr size_t OF_M      = OF_SK    + (size_t)kB * kC;
constexpr size_t OF_ZI     = OF_M     + (size_t)kB * kC;
constexpr size_t OF_U      = OF_ZI    + (size_t)kB * kC;   // uq[128], uk[128], cc
constexpr size_t OF_PART   = OF_U     + 384;               // 16*kB*kD
constexpr size_t OF_PARAMS = OF_PART  + 2048;
constexpr int    PA_TOTAL  = 396048;                       // padded param arena
constexpr size_t OF_FLAG   = OF_PARAMS + PA_TOTAL;

// param arena offsets (floats)
constexpr int PA_INIT_BP_W = 0;       // 16384
constexpr int PA_INIT_BP_B = 16384;   // 128
constexpr int PA_INIT_EP_W = 16512;   // 16384
constexpr int PA_INIT_EP_B = 32896;   // 128
constexpr int PA_BE_BP_W   = 33024;   // 32768 (L,D,D)
constexpr int PA_BE_BP_B   = 65792;   // 256
constexpr int PA_BE_EP_W   = 66048;   // 32768
constexpr int PA_BE_EP_B   = 98816;   // 256
constexpr int PA_SEQ_W     = 99072;   // 98304 (L,3D,D)
constexpr int PA_SEQ_B     = 197376;  // 256
constexpr int PA_ATTN_W    = 197632;  // 98304 (L,D,3D)
constexpr int PA_ATTN_B    = 295936;  // 768
constexpr int PA_SCORE_W   = 296704;  // 512
constexpr int PA_SCORE_B   = 297216;  // 2 (padded to 8)
constexpr int PA_AO_W      = 297224;  // 32768
constexpr int PA_AO_B      = 329992;  // 256
constexpr int PA_MIX_W     = 330248;  // 65536
constexpr int PA_MIX_B     = 395784;  // 256  -> end 396040

// ---------- K0: dtype sniff. bf16-packed words have exponent bits in [14:7]. ----------
__global__ __launch_bounds__(256) void k_detect(const unsigned* __restrict__ x, int* __restrict__ flag) {
  int t = threadIdx.x;
  int hits = 0;
  #pragma unroll
  for (int q = 0; q < 4; ++q) {
    unsigned w = x[t * 4 + q];            // words 0..1023 of operation_features
    unsigned e0 = (w >> 7) & 0xFFu;       // low-half bf16 exponent if packed; mantissa bits if f32
    hits += (e0 == 0u || (e0 >= 96u && e0 <= 134u)) ? 1 : 0;
  }
  __shared__ int s[256];
  s[t] = hits; __syncthreads();
  for (int off = 128; off > 0; off >>= 1) { if (t < off) s[t] += s[t + off]; __syncthreads(); }
  if (t == 0) *flag = (s[0] >= 512) ? 1 : 0;   // 1 = bf16, 0 = f32
}

// ---------- K0b: convert all params to f32 arena ----------
struct ConvPtrs { const void* p[18]; };

__global__ __launch_bounds__(256) void k_conv(ConvPtrs cp, float* __restrict__ dst,
                                              const int* __restrict__ flag) {
  constexpr int off[18] = {PA_INIT_BP_W, PA_INIT_BP_B, PA_INIT_EP_W, PA_INIT_EP_B,
                           PA_BE_BP_W, PA_BE_BP_B, PA_BE_EP_W, PA_BE_EP_B,
                           PA_SEQ_W, PA_SEQ_B, PA_ATTN_W, PA_ATTN_B,
                           PA_SCORE_W, PA_SCORE_B, PA_AO_W, PA_AO_B, PA_MIX_W, PA_MIX_B};
  constexpr int cnt[18] = {16384, 128, 16384, 128, 32768, 256, 32768, 256,
                           98304, 256, 98304, 768, 512, 2, 32768, 256, 65536, 256};
  int idx = blockIdx.x * 256 + threadIdx.x;
  if (idx >= PA_TOTAL) return;
  int t = 0;
  #pragma unroll
  for (int i = 1; i < 18; ++i) if (idx >= off[i]) t = i;
  int rel = idx - off[t];
  if (rel >= cnt[t]) return;
  const void* src = cp.p[t];
  float v = (*flag) ? bf2f(((const unsigned short*)src)[rel]) : ((const float*)src)[rel];
  dst[idx] = v;
}

// ---------- K1: ops -> feats rows 0..N-1 (f32) ----------
__global__ __launch_bounds__(256) void k_cast_ops(const void* __restrict__ ops,
                                                  float* __restrict__ feats,
                                                  const int* __restrict__ flag) {
  int idx = blockIdx.x * 256 + threadIdx.x;      // B*N*D/2 pairs
  int elem = idx * 2;
  int b = elem / (kN * kD);
  int r = elem - b * (kN * kD);
  float2 f;
  if (*flag) {
    unsigned u = ((const unsigned*)ops)[idx];
    f.x = bf2f((unsigned short)(u & 0xffffu));
    f.y = bf2f((unsigned short)(u >> 16));
  } else {
    f = ((const float2*)ops)[idx];
  }
  *(float2*)(feats + (size_t)b * kC * kD + r) = f;
}

// ---------- K2: begin/end pooling: mean(gather) @ W + b -> dst rows N, N+1 ----------
__global__ __launch_bounds__(128) void k_begin_end(
    const float* __restrict__ src, const int* __restrict__ bidx, const int* __restrict__ eidx,
    const float* __restrict__ bp_w, const float* __restrict__ bp_b,
    const float* __restrict__ ep_w, const float* __restrict__ ep_b,
    float* __restrict__ dst)
{
  int b = blockIdx.x, sel = blockIdx.y;
  int d = threadIdx.x;
  const int* idx = sel ? (eidx + b * kJ) : (bidx + b * kJ);
  const float* w    = sel ? ep_w : bp_w;
  const float* bias = sel ? ep_b : bp_b;
  __shared__ float m[kD];
  float acc = 0.f;
  const float* sb = src + (size_t)b * kC * kD;
  for (int j = 0; j < kJ; ++j) acc += sb[(size_t)idx[j] * kD + d];
  m[d] = acc * (1.0f / kJ);
  __syncthreads();
  float o = bias[d];
  for (int k = 0; k < kD; k += 4) {
    float4 xv = *(const float4*)(&m[k]);
    o += xv.x * w[(k + 0) * kD + d] + xv.y * w[(k + 1) * kD + d]
       + xv.z * w[(k + 2) * kD + d] + xv.w * w[(k + 3) * kD + d];
  }
  dst[(size_t)b * kC * kD + (size_t)(kN + sel) * kD + d] = o;
}

// ---------- K4: seq_mix ----------
__global__ __launch_bounds__(128) void k_seq_mix(
    const float* __restrict__ feats, const int* __restrict__ relations,
    const float* __restrict__ w, const float* __restrict__ bias, float* __restrict__ seq)
{
  int b = blockIdx.y;
  int n0 = blockIdx.x * 8;
  int d = threadIdx.x;
  __shared__ float xs[8][3 * kD];
  const float* fb = feats + (size_t)b * kC * kD;
  #pragma unroll
  for (int r = 0; r < 8; ++r) {
    int n = n0 + r;
    if (n >= kN) { xs[r][d] = 0.f; xs[r][kD + d] = 0.f; xs[r][2 * kD + d] = 0.f; continue; }
    int rp = relations[((size_t)b * kN + n) * 2 + 0];
    int rs = relations[((size_t)b * kN + n) * 2 + 1];
    int p = (rp < 0) ? kN : rp;
    int s = (rs < 0) ? (kN + 1) : rs;
    xs[r][d]          = fb[(size_t)n * kD + d];
    xs[r][kD + d]     = fb[(size_t)p * kD + d];
    xs[r][2 * kD + d] = fb[(size_t)s * kD + d];
  }
  __syncthreads();
  float bv = bias[d];
  float acc[8];
  #pragma unroll
  for (int r = 0; r < 8; ++r) acc[r] = bv;
  for (int k = 0; k < 3 * kD; k += 4) {
    float w0 = w[(size_t)(k + 0) * kD + d];
    float w1 = w[(size_t)(k + 1) * kD + d];
    float w2 = w[(size_t)(k + 2) * kD + d];
    float w3 = w[(size_t)(k + 3) * kD + d];
    #pragma unroll
    for (int r = 0; r < 8; ++r) {
      float4 xv = *(const float4*)(&xs[r][k]);
      acc[r] += xv.x * w0 + xv.y * w1 + xv.z * w2 + xv.w * w3;
    }
  }
  #pragma unroll
  for (int r = 0; r < 8; ++r) {
    int n = n0 + r;
    if (n < kN) seq[(size_t)b * kC * kD + (size_t)n * kD + d] = acc[r];
  }
}

// ---------- K5a: u-vectors ----------
__global__ __launch_bounds__(128) void k_uvec(
    const float* __restrict__ attn_w, const float* __restrict__ attn_b,
    const float* __restrict__ score_w, const float* __restrict__ score_b, float* __restrict__ u)
{
  int k = threadIdx.x;
  __shared__ float sw[2 * kD];
  sw[k] = score_w[k]; sw[kD + k] = score_w[kD + k];
  __syncthreads();
  const float* wr = attn_w + (size_t)k * (3 * kD);
  float uq = 0.f, uk = 0.f;
  #pragma unroll 4
  for (int d2 = 0; d2 < kD; ++d2) {
    uq += wr[d2] * sw[d2];
    uk += wr[kD + d2] * sw[kD + d2];
  }
  u[k] = uq; u[kD + k] = uk;
  __shared__ float red[kD];
  red[k] = attn_b[k] * sw[k] + attn_b[kD + k] * sw[kD + k];
  __syncthreads();
  if (k == 0) {
    float s = score_b[0];
    for (int i = 0; i < kD; ++i) s += red[i];
    u[2 * kD] = s;
  }
}

// ---------- K5b: sq/sk row scalars ----------
__global__ __launch_bounds__(256) void k_sqsk(const float* __restrict__ feats,
                                              const float* __restrict__ u,
                                              float* __restrict__ sq, float* __restrict__ sk) {
  int wave = threadIdx.x >> 6, lane = threadIdx.x & 63;
  int row = blockIdx.x * 4 + wave;
  const float* x = feats + (size_t)row * kD;
  float2 xv  = *(const float2*)(x + 2 * lane);
  float2 uqv = *(const float2*)(u + 2 * lane);
  float2 ukv = *(const float2*)(u + kD + 2 * lane);
  float a  = xv.x * uqv.x + xv.y * uqv.y;
  float b2 = xv.x * ukv.x + xv.y * ukv.y;
  for (int off = 32; off > 0; off >>= 1) { a += __shfl_down(a, off); b2 += __shfl_down(b2, off); }
  if (lane == 0) { sq[row] = a + u[2 * kD]; sk[row] = b2; }
}

// ---------- K5c/K8: row-GEMM out[row,:] = x[row,:] @ W + bias ----------
__global__ __launch_bounds__(128) void k_gemm_rows(
    const float* __restrict__ x, const float* __restrict__ w, int wstride,
    const float* __restrict__ bias, float* __restrict__ out)
{
  int row0 = blockIdx.x * 8;
  int d = threadIdx.x;
  __shared__ float xs[8][kD];
  #pragma unroll
  for (int r = 0; r < 8; ++r) xs[r][d] = x[(size_t)(row0 + r) * kD + d];
  __syncthreads();
  float bv = bias[d];
  float acc[8];
  #pragma unroll
  for (int r = 0; r < 8; ++r) acc[r] = bv;
  for (int k = 0; k < kD; k += 4) {
    float w0 = w[(size_t)(k + 0) * wstride + d];
    float w1 = w[(size_t)(k + 1) * wstride + d];
    float w2 = w[(size_t)(k + 2) * wstride + d];
    float w3 = w[(size_t)(k + 3) * wstride + d];
    #pragma unroll
    for (int r = 0; r < 8; ++r) {
      float4 xv = *(const float4*)(&xs[r][k]);
      acc[r] += xv.x * w0 + xv.y * w1 + xv.z * w2 + xv.w * w3;
    }
  }
  #pragma unroll
  for (int r = 0; r < 8; ++r) out[(size_t)(row0 + r) * kD + d] = acc[r];
}

// ---------- K6: softmax row stats. val = mask ? lrelu(sq_i + sk_j) : 0 ----------
template <typename MT>
__device__ __forceinline__ void stats_body(const MT* __restrict__ mask,
                                           const float* __restrict__ sq,
                                           const float* __restrict__ sk,
                                           float* __restrict__ Mrow, float* __restrict__ Zinv) {
  int wave = (int)threadIdx.x >> 6, lane = (int)threadIdx.x & 63;
  int row = blockIdx.x * 4 + wave;
  int b = row >> 11;
  int i = row & (kC - 1);
  float a = sq[row];
  const float* skb = sk + (size_t)b * kC;
  float vals[32];
  float mx = 0.f;
  if (i < kN) {
    const MT* mrow = mask + ((size_t)b * kN + i) * kN;
    #pragma unroll
    for (int t = 0; t < 32; ++t) {
      int j = t * 64 + lane;
      float val = 0.f;
      if (j < kN && mrow[j] != (MT)0) {
        float s = a + skb[j];
        val = (s >= 0.f) ? s : 0.01f * s;
      }
      vals[t] = val;
      mx = fmaxf(mx, val);
    }
  } else {
    #pragma unroll
    for (int t = 0; t < 32; ++t) {
      int j = t * 64 + lane;
      float val = 0.f;
      if (j == i) {
        float s = a + skb[j];
        val = (s >= 0.f) ? s : 0.01f * s;
      }
      vals[t] = val;
      mx = fmaxf(mx, val);
    }
  }
  for (int off = 32; off > 0; off >>= 1) mx = fmaxf(mx, __shfl_down(mx, off));
  mx = __shfl(mx, 0);
  float zs = 0.f;
  #pragma unroll
  for (int t = 0; t < 32; ++t) zs += __expf(vals[t] - mx);
  for (int off = 32; off > 0; off >>= 1) zs += __shfl_down(zs, off);
  if (lane == 0) { Mrow[row] = mx; Zinv[row] = 1.0f / zs; }
}

__global__ __launch_bounds__(256) void k_stats(const void* __restrict__ mask,
                                               const float* __restrict__ sq,
                                               const float* __restrict__ sk,
                                               float* __restrict__ Mrow, float* __restrict__ Zinv,
                                               const int* __restrict__ flag) {
  if (*flag) stats_body<unsigned short>((const unsigned short*)mask, sq, sk, Mrow, Zinv);
  else       stats_body<unsigned>((const unsigned*)mask, sq, sk, Mrow, Zinv);
}

// ---------- K7: PV accumulation (P recomputed on the fly) ----------
template <typename MT>
__device__ __forceinline__ void pv_body(const MT* __restrict__ mask, const float* __restrict__ sq,
                                        const float* __restrict__ sk, const float* __restrict__ Mrow,
                                        const float* __restrict__ Zinv, const float* __restrict__ v,
                                        float* __restrict__ outw) {
  constexpr int TI = 32, TJ = 64;
  int b = blockIdx.y;
  int i0 = blockIdx.x * TI;
  int t = threadIdx.x;
  __shared__ float vt[TJ][kD];        // 32 KB
  __shared__ float pt[TJ][TI + 4];    // stride 36 f = 144 B (16B-aligned rows)
  int d4 = (t & 31) * 4;
  int rg = t >> 5;
  float acc[4][4];
  #pragma unroll
  for (int r = 0; r < 4; ++r)
    #pragma unroll
    for (int q = 0; q < 4; ++q) acc[r][q] = 0.f;

  const float* skb = sk + (size_t)b * kC;
  for (int j0 = 0; j0 < kC; j0 += TJ) {
    __syncthreads();
    const float4* vsrc = (const float4*)(v + ((size_t)b * kC + j0) * kD);
    float4* vdst = (float4*)(&vt[0][0]);
    #pragma unroll
    for (int q = 0; q < 8; ++q) vdst[q * 256 + t] = vsrc[q * 256 + t];
    #pragma unroll
    for (int q = 0; q < 8; ++q) {
      int e = q * 256 + t;
      int il = e >> 6;
      int jl = e & 63;
      int i = i0 + il;
      int j = j0 + jl;
      int row = b * kC + i;
      bool mnz;
      if (i < kN) mnz = (j < kN) && (mask[((size_t)b * kN + i) * kN + j] != (MT)0);
      else        mnz = (j == i);
      float val = 0.f;
      if (mnz) {
        float s = sq[row] + skb[j];
        val = (s >= 0.f) ? s : 0.01f * s;
      }
      pt[jl][il] = __expf(val - Mrow[row]) * Zinv[row];
    }
    __syncthreads();
    #pragma unroll 4
    for (int jj = 0; jj < TJ; ++jj) {
      float4 vv = *(const float4*)(&vt[jj][d4]);
      float4 pv = *(const float4*)(&pt[jj][rg * 4]);
      acc[0][0] += pv.x * vv.x; acc[0][1] += pv.x * vv.y; acc[0][2] += pv.x * vv.z; acc[0][3] += pv.x * vv.w;
      acc[1][0] += pv.y * vv.x; acc[1][1] += pv.y * vv.y; acc[1][2] += pv.y * vv.z; acc[1][3] += pv.y * vv.w;
      acc[2][0] += pv.z * vv.x; acc[2][1] += pv.z * vv.y; acc[2][2] += pv.z * vv.z; acc[2][3] += pv.z * vv.w;
      acc[3][0] += pv.w * vv.x; acc[3][1] += pv.w * vv.y; acc[3][2] += pv.w * vv.z; acc[3][3] += pv.w * vv.w;
    }
  }
  #pragma unroll
  for (int r = 0; r < 4; ++r) {
    int i = i0 + rg * 4 + r;
    float4 o; o.x = acc[r][0]; o.y = acc[r][1]; o.z = acc[r][2]; o.w = acc[r][3];
    *(float4*)(outw + ((size_t)b * kC + i) * kD + d4) = o;
  }
}

__global__ __launch_bounds__(256) void k_attn_pv(const void* __restrict__ mask,
    const float* __restrict__ sq, const float* __restrict__ sk, const float* __restrict__ Mrow,
    const float* __restrict__ Zinv, const float* __restrict__ v, float* __restrict__ outw,
    const int* __restrict__ flag) {
  if (*flag) pv_body<unsigned short>((const unsigned short*)mask, sq, sk, Mrow, Zinv, v, outw);
  else       pv_body<unsigned>((const unsigned*)mask, sq, sk, Mrow, Zinv, v, outw);
}

// ---------- K9: mix ----------
__global__ __launch_bounds__(128) void k_mix(
    const float* __restrict__ seq, const float* __restrict__ attn2,
    const float* __restrict__ w, const float* __restrict__ bias, float* __restrict__ feats)
{
  int row0 = blockIdx.x * 8;
  int d = threadIdx.x;
  __shared__ float xs[8][2 * kD];
  #pragma unroll
  for (int r = 0; r < 8; ++r) {
    xs[r][d]      = seq[(size_t)(row0 + r) * kD + d];
    xs[r][kD + d] = attn2[(size_t)(row0 + r) * kD + d];
  }
  __syncthreads();
  float bv = bias[d];
  float acc[8];
  #pragma unroll
  for (int r = 0; r < 8; ++r) acc[r] = bv;
  for (int k = 0; k < 2 * kD; k += 4) {
    float w0 = w[(size_t)(k + 0) * kD + d];
    float w1 = w[(size_t)(k + 1) * kD + d];
    float w2 = w[(size_t)(k + 2) * kD + d];
    float w3 = w[(size_t)(k + 3) * kD + d];
    #pragma unroll
    for (int r = 0; r < 8; ++r) {
      float4 xv = *(const float4*)(&xs[r][k]);
      acc[r] += xv.x * w0 + xv.y * w1 + xv.z * w2 + xv.w * w3;
    }
  }
  #pragma unroll
  for (int r = 0; r < 8; ++r) feats[(size_t)(row0 + r) * kD + d] = acc[r];
}

// ---------- K10: outputs ----------
__global__ __launch_bounds__(128) void k_part(const float* __restrict__ feats, float* __restrict__ part) {
  int b = blockIdx.x >> 4, g = blockIdx.x & 15, d = threadIdx.x;
  float s = 0.f;
  for (int c = g * 128; c < g * 128 + 128; ++c) s += feats[((size_t)b * kC + c) * kD + d];
  part[(size_t)blockIdx.x * kD + d] = s;
}
__global__ __launch_bounds__(128) void k_mean(const float* __restrict__ part, void* __restrict__ out,
                                              const int* __restrict__ flag) {
  int b = blockIdx.x, d = threadIdx.x;
  float s = 0.f;
  for (int g = 0; g < 16; ++g) s += part[((size_t)b * 16 + g) * kD + d];
  float r = s * (1.0f / kC);
  if (*flag) ((unsigned short*)out)[b * kD + d] = f2bf(r);
  else       ((float*)out)[b * kD + d] = r;
}
__global__ __launch_bounds__(256) void k_cast_out(const float* __restrict__ feats, void* __restrict__ out,
                                                  const int* __restrict__ flag) {
  int idx = blockIdx.x * 256 + threadIdx.x;   // B*C*D/2 pairs
  float2 f = *(const float2*)(feats + (size_t)idx * 2);
  if (*flag) {
    unsigned* o = (unsigned*)((unsigned short*)out + kB * kD);
    o[idx] = (unsigned)f2bf(f.x) | ((unsigned)f2bf(f.y) << 16);
  } else {
    float2* o = (float2*)((float*)out + kB * kD);
    o[idx] = f;
  }
}

extern "C" void kernel_launch(void* const* d_in, const int* in_sizes, int n_in,
                              void* d_out, int out_size, void* d_ws, size_t ws_size,
                              hipStream_t stream) {
  const int* relations = (const int*)d_in[2];
  const int* begins    = (const int*)d_in[3];
  const int* ends      = (const int*)d_in[4];

  float* ws    = (float*)d_ws;
  float* feats = ws + OF_FEATS;
  float* seq   = ws + OF_SEQ;
  float* attnw = ws + OF_ATTN;
  float* vbuf  = ws + OF_V;
  float* sq    = ws + OF_SQ;
  float* sk    = ws + OF_SK;
  float* Mrow  = ws + OF_M;
  float* Zinv  = ws + OF_ZI;
  float* u     = ws + OF_U;
  float* part  = ws + OF_PART;
  float* prm   = ws + OF_PARAMS;
  int*   flag  = (int*)(ws + OF_FLAG);

  // dtype sniff + param conversion
  k_detect<<<1, 256, 0, stream>>>((const unsigned*)d_in[0], flag);
  ConvPtrs cp;
  for (int i = 0; i < 18; ++i) cp.p[i] = d_in[5 + i];
  k_conv<<<(PA_TOTAL + 255) / 256, 256, 0, stream>>>(cp, prm, flag);

  // init: feats = [ops; begin; end]
  k_cast_ops<<<4092, 256, 0, stream>>>(d_in[0], feats, flag);
  k_begin_end<<<dim3(kB, 2), 128, 0, stream>>>(feats, begins, ends,
      prm + PA_INIT_BP_W, prm + PA_INIT_BP_B, prm + PA_INIT_EP_W, prm + PA_INIT_EP_B, feats);

  for (int l = 0; l < kL; ++l) {
    const float* aw = prm + PA_ATTN_W + (size_t)l * kD * 3 * kD;
    const float* ab = prm + PA_ATTN_B + (size_t)l * 3 * kD;

    k_begin_end<<<dim3(kB, 2), 128, 0, stream>>>(feats, begins, ends,
        prm + PA_BE_BP_W + (size_t)l * kD * kD, prm + PA_BE_BP_B + (size_t)l * kD,
        prm + PA_BE_EP_W + (size_t)l * kD * kD, prm + PA_BE_EP_B + (size_t)l * kD, seq);
    k_seq_mix<<<dim3(256, kB), 128, 0, stream>>>(feats, relations,
        prm + PA_SEQ_W + (size_t)l * 3 * kD * kD, prm + PA_SEQ_B + (size_t)l * kD, seq);

    k_uvec<<<1, 128, 0, stream>>>(aw, ab,
        prm + PA_SCORE_W + (size_t)l * 2 * kD, prm + PA_SCORE_B + l, u);
    k_sqsk<<<4096, 256, 0, stream>>>(feats, u, sq, sk);
    k_gemm_rows<<<2048, 128, 0, stream>>>(feats, aw + 2 * kD, 3 * kD, ab + 2 * kD, vbuf);
    k_stats<<<4096, 256, 0, stream>>>(d_in[1], sq, sk, Mrow, Zinv, flag);
    k_attn_pv<<<dim3(64, kB), 256, 0, stream>>>(d_in[1], sq, sk, Mrow, Zinv, vbuf, attnw, flag);
    k_gemm_rows<<<2048, 128, 0, stream>>>(attnw,
        prm + PA_AO_W + (size_t)l * kD * kD, kD, prm + PA_AO_B + (size_t)l * kD, vbuf);
    k_mix<<<2048, 128, 0, stream>>>(seq, vbuf,
        prm + PA_MIX_W + (size_t)l * 2 * kD * kD, prm + PA_MIX_B + (size_t)l * kD, feats);
  }

  k_part<<<128, 128, 0, stream>>>(feats, part);
  k_mean<<<kB, 128, 0, stream>>>(part, d_out, flag);
  k_cast_out<<<4096, 256, 0, stream>>>(feats, d_out, flag);
}

// Round 3
// 681.324 us; speedup vs baseline: 2.1162x; 2.1162x over previous
//
#include <hip/hip_runtime.h>

// Problem constants
constexpr int kB = 8;
constexpr int kN = 2046;
constexpr int kC = 2048;   // kN + 2
constexpr int kD = 128;
constexpr int kJ = 128;
constexpr int kL = 2;

typedef short bfrag8 __attribute__((ext_vector_type(8)));
typedef float f32x4 __attribute__((ext_vector_type(4)));

// ---------- bf16 helpers ----------
__device__ __forceinline__ float bf2f(unsigned short h) {
  union { unsigned u; float f; } x; x.u = ((unsigned)h) << 16; return x.f;
}
__device__ __forceinline__ unsigned short f2bf(float f) {
  union { float f; unsigned u; } x; x.f = f;
  unsigned u = x.u;
  if ((u & 0x7fffffffu) > 0x7f800000u) return (unsigned short)((u >> 16) | 0x40);
  return (unsigned short)((u + 0x7fffu + ((u >> 16) & 1u)) >> 16);
}
__device__ __forceinline__ unsigned short f2bf_fast(float f) {  // no NaN inputs
  union { float f; unsigned u; } x; x.f = f;
  return (unsigned short)((x.u + 0x7fffu + ((x.u >> 16) & 1u)) >> 16);
}

// ---------- workspace layout (float offsets) ----------
constexpr size_t OF_FEATS  = 0;
constexpr size_t OF_SEQ    = OF_FEATS + (size_t)kB * kC * kD;
constexpr size_t OF_ATTN   = OF_SEQ   + (size_t)kB * kC * kD;
constexpr size_t OF_V      = OF_ATTN  + (size_t)kB * kC * kD;  // Vt bf16 (4MB) + bits (4MB)
constexpr size_t OF_SQ     = OF_V     + (size_t)kB * kC * kD;
constexpr size_t OF_SK     = OF_SQ    + (size_t)kB * kC;
constexpr size_t OF_M      = OF_SK    + (size_t)kB * kC;
constexpr size_t OF_ZI     = OF_M     + (size_t)kB * kC;
constexpr size_t OF_U      = OF_ZI    + (size_t)kB * kC;   // uq[128], uk[128], cc
constexpr size_t OF_PART   = OF_U     + 384;               // 16*kB*kD
constexpr size_t OF_PARAMS = OF_PART  + 2048;
constexpr int    PA_TOTAL  = 396048;
constexpr size_t OF_FLAG   = OF_PARAMS + PA_TOTAL;

// param arena offsets (floats)
constexpr int PA_INIT_BP_W = 0;
constexpr int PA_INIT_BP_B = 16384;
constexpr int PA_INIT_EP_W = 16512;
constexpr int PA_INIT_EP_B = 32896;
constexpr int PA_BE_BP_W   = 33024;
constexpr int PA_BE_BP_B   = 65792;
constexpr int PA_BE_EP_W   = 66048;
constexpr int PA_BE_EP_B   = 98816;
constexpr int PA_SEQ_W     = 99072;
constexpr int PA_SEQ_B     = 197376;
constexpr int PA_ATTN_W    = 197632;
constexpr int PA_ATTN_B    = 295936;
constexpr int PA_SCORE_W   = 296704;
constexpr int PA_SCORE_B   = 297216;
constexpr int PA_AO_W      = 297224;
constexpr int PA_AO_B      = 329992;
constexpr int PA_MIX_W     = 330248;
constexpr int PA_MIX_B     = 395784;

// ---------- K0: dtype sniff ----------
__global__ __launch_bounds__(256) void k_detect(const unsigned* __restrict__ x, int* __restrict__ flag) {
  int t = threadIdx.x;
  int hits = 0;
  #pragma unroll
  for (int q = 0; q < 4; ++q) {
    unsigned w = x[t * 4 + q];
    unsigned e0 = (w >> 7) & 0xFFu;
    hits += (e0 == 0u || (e0 >= 96u && e0 <= 134u)) ? 1 : 0;
  }
  __shared__ int s[256];
  s[t] = hits; __syncthreads();
  for (int off = 128; off > 0; off >>= 1) { if (t < off) s[t] += s[t + off]; __syncthreads(); }
  if (t == 0) *flag = (s[0] >= 512) ? 1 : 0;
}

// ---------- K0b: params -> f32 arena ----------
struct ConvPtrs { const void* p[18]; };

__global__ __launch_bounds__(256) void k_conv(ConvPtrs cp, float* __restrict__ dst,
                                              const int* __restrict__ flag) {
  constexpr int off[18] = {PA_INIT_BP_W, PA_INIT_BP_B, PA_INIT_EP_W, PA_INIT_EP_B,
                           PA_BE_BP_W, PA_BE_BP_B, PA_BE_EP_W, PA_BE_EP_B,
                           PA_SEQ_W, PA_SEQ_B, PA_ATTN_W, PA_ATTN_B,
                           PA_SCORE_W, PA_SCORE_B, PA_AO_W, PA_AO_B, PA_MIX_W, PA_MIX_B};
  constexpr int cnt[18] = {16384, 128, 16384, 128, 32768, 256, 32768, 256,
                           98304, 256, 98304, 768, 512, 2, 32768, 256, 65536, 256};
  int idx = blockIdx.x * 256 + threadIdx.x;
  if (idx >= PA_TOTAL) return;
  int t = 0;
  #pragma unroll
  for (int i = 1; i < 18; ++i) if (idx >= off[i]) t = i;
  int rel = idx - off[t];
  if (rel >= cnt[t]) return;
  const void* src = cp.p[t];
  float v = (*flag) ? bf2f(((const unsigned short*)src)[rel]) : ((const float*)src)[rel];
  dst[idx] = v;
}

// ---------- K1: ops -> feats rows 0..N-1 ----------
__global__ __launch_bounds__(256) void k_cast_ops(const void* __restrict__ ops,
                                                  float* __restrict__ feats,
                                                  const int* __restrict__ flag) {
  int idx = blockIdx.x * 256 + threadIdx.x;
  int elem = idx * 2;
  int b = elem / (kN * kD);
  int r = elem - b * (kN * kD);
  float2 f;
  if (*flag) {
    unsigned u = ((const unsigned*)ops)[idx];
    f.x = bf2f((unsigned short)(u & 0xffffu));
    f.y = bf2f((unsigned short)(u >> 16));
  } else {
    f = ((const float2*)ops)[idx];
  }
  *(float2*)(feats + (size_t)b * kC * kD + r) = f;
}

// ---------- K1b: mask -> bit array. bits[(b*kC+i)*32 + t] covers j = t*64..t*64+63 ----------
__global__ __launch_bounds__(256) void k_maskbits(const void* __restrict__ mask,
                                                  unsigned long long* __restrict__ bits,
                                                  const int* __restrict__ flag) {
  int wave = threadIdx.x >> 6, lane = threadIdx.x & 63;
  int r = blockIdx.x * 4 + wave;            // 0..B*kN-1
  int b = r / kN;
  int i = r - b * kN;
  bool isbf = (*flag != 0);
  const unsigned short* mh = (const unsigned short*)mask + (size_t)r * kN;
  const unsigned*       mw = (const unsigned*)mask + (size_t)r * kN;
  unsigned long long* brow = bits + ((size_t)b * kC + i) * 32;
  for (int t = 0; t < 32; ++t) {
    int j = t * 64 + lane;
    bool nz = false;
    if (j < kN) nz = isbf ? (mh[j] != 0) : (mw[j] != 0);
    unsigned long long bm = __ballot(nz);
    if (lane == 0) brow[t] = bm;
  }
}

// ---------- K2: begin/end pooling ----------
__global__ __launch_bounds__(128) void k_begin_end(
    const float* __restrict__ src, const int* __restrict__ bidx, const int* __restrict__ eidx,
    const float* __restrict__ bp_w, const float* __restrict__ bp_b,
    const float* __restrict__ ep_w, const float* __restrict__ ep_b,
    float* __restrict__ dst)
{
  int b = blockIdx.x, sel = blockIdx.y;
  int d = threadIdx.x;
  const int* idx = sel ? (eidx + b * kJ) : (bidx + b * kJ);
  const float* w    = sel ? ep_w : bp_w;
  const float* bias = sel ? ep_b : bp_b;
  __shared__ float m[kD];
  float acc = 0.f;
  const float* sb = src + (size_t)b * kC * kD;
  for (int j = 0; j < kJ; ++j) acc += sb[(size_t)idx[j] * kD + d];
  m[d] = acc * (1.0f / kJ);
  __syncthreads();
  float o = bias[d];
  for (int k = 0; k < kD; k += 4) {
    float4 xv = *(const float4*)(&m[k]);
    o += xv.x * w[(k + 0) * kD + d] + xv.y * w[(k + 1) * kD + d]
       + xv.z * w[(k + 2) * kD + d] + xv.w * w[(k + 3) * kD + d];
  }
  dst[(size_t)b * kC * kD + (size_t)(kN + sel) * kD + d] = o;
}

// ---------- K4: seq_mix ----------
__global__ __launch_bounds__(128) void k_seq_mix(
    const float* __restrict__ feats, const int* __restrict__ relations,
    const float* __restrict__ w, const float* __restrict__ bias, float* __restrict__ seq)
{
  int b = blockIdx.y;
  int n0 = blockIdx.x * 8;
  int d = threadIdx.x;
  __shared__ float xs[8][3 * kD];
  const float* fb = feats + (size_t)b * kC * kD;
  #pragma unroll
  for (int r = 0; r < 8; ++r) {
    int n = n0 + r;
    if (n >= kN) { xs[r][d] = 0.f; xs[r][kD + d] = 0.f; xs[r][2 * kD + d] = 0.f; continue; }
    int rp = relations[((size_t)b * kN + n) * 2 + 0];
    int rs = relations[((size_t)b * kN + n) * 2 + 1];
    int p = (rp < 0) ? kN : rp;
    int s = (rs < 0) ? (kN + 1) : rs;
    xs[r][d]          = fb[(size_t)n * kD + d];
    xs[r][kD + d]     = fb[(size_t)p * kD + d];
    xs[r][2 * kD + d] = fb[(size_t)s * kD + d];
  }
  __syncthreads();
  float bv = bias[d];
  float acc[8];
  #pragma unroll
  for (int r = 0; r < 8; ++r) acc[r] = bv;
  for (int k = 0; k < 3 * kD; k += 4) {
    float w0 = w[(size_t)(k + 0) * kD + d];
    float w1 = w[(size_t)(k + 1) * kD + d];
    float w2 = w[(size_t)(k + 2) * kD + d];
    float w3 = w[(size_t)(k + 3) * kD + d];
    #pragma unroll
    for (int r = 0; r < 8; ++r) {
      float4 xv = *(const float4*)(&xs[r][k]);
      acc[r] += xv.x * w0 + xv.y * w1 + xv.z * w2 + xv.w * w3;
    }
  }
  #pragma unroll
  for (int r = 0; r < 8; ++r) {
    int n = n0 + r;
    if (n < kN) seq[(size_t)b * kC * kD + (size_t)n * kD + d] = acc[r];
  }
}

// ---------- K5a: u-vectors ----------
__global__ __launch_bounds__(128) void k_uvec(
    const float* __restrict__ attn_w, const float* __restrict__ attn_b,
    const float* __restrict__ score_w, const float* __restrict__ score_b, float* __restrict__ u)
{
  int k = threadIdx.x;
  __shared__ float sw[2 * kD];
  sw[k] = score_w[k]; sw[kD + k] = score_w[kD + k];
  __syncthreads();
  const float* wr = attn_w + (size_t)k * (3 * kD);
  float uq = 0.f, uk = 0.f;
  #pragma unroll 4
  for (int d2 = 0; d2 < kD; ++d2) {
    uq += wr[d2] * sw[d2];
    uk += wr[kD + d2] * sw[kD + d2];
  }
  u[k] = uq; u[kD + k] = uk;
  __shared__ float red[kD];
  red[k] = attn_b[k] * sw[k] + attn_b[kD + k] * sw[kD + k];
  __syncthreads();
  if (k == 0) {
    float s = score_b[0];
    for (int i = 0; i < kD; ++i) s += red[i];
    u[2 * kD] = s;
  }
}

// ---------- K5b: sq/sk row scalars ----------
__global__ __launch_bounds__(256) void k_sqsk(const float* __restrict__ feats,
                                              const float* __restrict__ u,
                                              float* __restrict__ sq, float* __restrict__ sk) {
  int wave = threadIdx.x >> 6, lane = threadIdx.x & 63;
  int row = blockIdx.x * 4 + wave;
  const float* x = feats + (size_t)row * kD;
  float2 xv  = *(const float2*)(x + 2 * lane);
  float2 uqv = *(const float2*)(u + 2 * lane);
  float2 ukv = *(const float2*)(u + kD + 2 * lane);
  float a  = xv.x * uqv.x + xv.y * uqv.y;
  float b2 = xv.x * ukv.x + xv.y * ukv.y;
  for (int off = 32; off > 0; off >>= 1) { a += __shfl_down(a, off); b2 += __shfl_down(b2, off); }
  if (lane == 0) { sq[row] = a + u[2 * kD]; sk[row] = b2; }
}

// ---------- K5c: v-projection -> Vt bf16 transposed [B][D][C] ----------
__global__ __launch_bounds__(128) void k_vproj(
    const float* __restrict__ x, const float* __restrict__ w,
    const float* __restrict__ bias, unsigned short* __restrict__ Vt)
{
  int row0 = blockIdx.x * 8;
  int d = threadIdx.x;
  __shared__ float xs[8][kD];
  #pragma unroll
  for (int r = 0; r < 8; ++r) xs[r][d] = x[(size_t)(row0 + r) * kD + d];
  __syncthreads();
  float bv = bias[d];
  float acc[8];
  #pragma unroll
  for (int r = 0; r < 8; ++r) acc[r] = bv;
  for (int k = 0; k < kD; k += 4) {
    float w0 = w[(size_t)(k + 0) * (3 * kD) + d];
    float w1 = w[(size_t)(k + 1) * (3 * kD) + d];
    float w2 = w[(size_t)(k + 2) * (3 * kD) + d];
    float w3 = w[(size_t)(k + 3) * (3 * kD) + d];
    #pragma unroll
    for (int r = 0; r < 8; ++r) {
      float4 xv = *(const float4*)(&xs[r][k]);
      acc[r] += xv.x * w0 + xv.y * w1 + xv.z * w2 + xv.w * w3;
    }
  }
  int b = row0 >> 11;
  int c0 = row0 & (kC - 1);
  unsigned short us[8];
  #pragma unroll
  for (int r = 0; r < 8; ++r) us[r] = f2bf_fast(acc[r]);
  uint4 pk;
  pk.x = us[0] | ((unsigned)us[1] << 16);
  pk.y = us[2] | ((unsigned)us[3] << 16);
  pk.z = us[4] | ((unsigned)us[5] << 16);
  pk.w = us[6] | ((unsigned)us[7] << 16);
  *(uint4*)(Vt + ((size_t)b * kD + d) * kC + c0) = pk;
}

// ---------- K6: softmax row stats from bitmask ----------
__global__ __launch_bounds__(256) void k_stats(const unsigned long long* __restrict__ bits,
                                               const float* __restrict__ sq,
                                               const float* __restrict__ sk,
                                               float* __restrict__ Mrow, float* __restrict__ Zinv) {
  int wave = (int)threadIdx.x >> 6, lane = (int)threadIdx.x & 63;
  int row = blockIdx.x * 4 + wave;
  int b = row >> 11;
  int i = row & (kC - 1);
  float a = sq[row];
  const float* skb = sk + (size_t)b * kC;
  float vals[32];
  float mx = 0.f;
  if (i < kN) {
    const unsigned long long* brow = bits + ((size_t)b * kC + i) * 32;
    #pragma unroll
    for (int t = 0; t < 32; ++t) {
      unsigned long long bm = brow[t];
      int j = t * 64 + lane;
      float val = 0.f;
      if ((bm >> lane) & 1ull) {
        float s = a + skb[j];
        val = fmaxf(s, 0.01f * s);
      }
      vals[t] = val;
      mx = fmaxf(mx, val);
    }
  } else {
    #pragma unroll
    for (int t = 0; t < 32; ++t) {
      int j = t * 64 + lane;
      float val = 0.f;
      if (j == i) {
        float s = a + skb[j];
        val = fmaxf(s, 0.01f * s);
      }
      vals[t] = val;
      mx = fmaxf(mx, val);
    }
  }
  for (int off = 32; off > 0; off >>= 1) mx = fmaxf(mx, __shfl_down(mx, off));
  mx = __shfl(mx, 0);
  float zs = 0.f;
  #pragma unroll
  for (int t = 0; t < 32; ++t) zs += __expf(vals[t] - mx);
  for (int off = 32; off > 0; off >>= 1) zs += __shfl_down(zs, off);
  if (lane == 0) { Mrow[row] = mx; Zinv[row] = 1.0f / zs; }
}

// ---------- K7: MFMA PV. Block = 32 i-rows x 128 d-cols; P built in A-frag layout in LDS ----------
__device__ __forceinline__ f32x4 mfma16(bfrag8 a, bfrag8 b, f32x4 c) {
  return __builtin_amdgcn_mfma_f32_16x16x32_bf16(a, b, c, 0, 0, 0);
}

__global__ __launch_bounds__(256) void k_attn_pv_mfma(
    const unsigned* __restrict__ bits,         // u32 view, row stride 64 u32
    const float* __restrict__ sq, const float* __restrict__ sk,
    const float* __restrict__ Mrow, const float* __restrict__ Zinv,
    const unsigned short* __restrict__ Vt,     // [B][D][C] bf16
    float* __restrict__ outw)                  // [B][C][D] f32
{
  int b = blockIdx.y;
  int i0 = blockIdx.x * 32;
  int t = threadIdx.x;
  int lane = t & 63;
  int w = t >> 6;

  __shared__ unsigned short pshare[2][1024];   // 2 x (32x32 bf16) = 4 KB
  __shared__ float sklds[kC];                  // 8 KB
  __shared__ unsigned bitlds[2048];            // 32 rows x 64 u32 = 8 KB

  // stage sk + bits
  const float* skb = sk + (size_t)b * kC;
  #pragma unroll
  for (int q = 0; q < 8; ++q) sklds[q * 256 + t] = skb[q * 256 + t];
  const unsigned* bitrow = bits + ((size_t)b * kC + i0) * 64;
  #pragma unroll
  for (int q = 0; q < 8; ++q) bitlds[q * 256 + t] = bitrow[q * 256 + t];

  // P-build thread constants: thread t builds half-fragment (f = t/2, h = t&1)
  int f = t >> 1, h = t & 1;
  int mt_b = f >> 6;
  int lb = f & 63;
  int irow_l = mt_b * 16 + (lb & 15);
  int quad_b = lb >> 4;
  int i_g = i0 + irow_l;
  float sqi = sq[(size_t)b * kC + i_g];
  float mri = Mrow[(size_t)b * kC + i_g];
  int joff = quad_b * 8 + h * 4;
  bool irow_ok = (i_g < kN);
  const unsigned char* bitb = (const unsigned char*)bitlds + irow_l * 256;

  __syncthreads();

  auto buildP = [&](int k0, int buf) {
    float4 skv = *(const float4*)(sklds + k0 + joff);
    unsigned byte;
    if (irow_ok) {
      byte = bitb[(k0 >> 3) + quad_b];
    } else {
      int d0 = i_g - (k0 + quad_b * 8);
      byte = ((unsigned)d0 < 8u) ? (1u << d0) : 0u;
    }
    unsigned nib = byte >> (h * 4);
    unsigned short us[4];
    float sv[4] = {skv.x, skv.y, skv.z, skv.w};
    #pragma unroll
    for (int dj = 0; dj < 4; ++dj) {
      float s = sqi + sv[dj];
      float lr = fmaxf(s, 0.01f * s);
      float val = ((nib >> dj) & 1u) ? lr : 0.f;
      us[dj] = f2bf_fast(__expf(val - mri));
    }
    uint2 pk;
    pk.x = us[0] | ((unsigned)us[1] << 16);
    pk.y = us[2] | ((unsigned)us[3] << 16);
    *(uint2*)(&pshare[buf][f * 8 + h * 4]) = pk;
  };

  // accumulators + B pointers
  f32x4 acc00 = {0.f, 0.f, 0.f, 0.f}, acc01 = acc00, acc10 = acc00, acc11 = acc00;
  int m = lane & 15, quad = lane >> 4;
  int nbase = w * 32;
  const unsigned short* vtb = Vt + (size_t)b * kD * kC;
  const unsigned short* bptr0 = vtb + (size_t)(nbase + m) * kC + quad * 8;
  const unsigned short* bptr1 = vtb + (size_t)(nbase + 16 + m) * kC + quad * 8;

  buildP(0, 0);
  bfrag8 b0n = *(const bfrag8*)bptr0;
  bfrag8 b1n = *(const bfrag8*)bptr1;
  __syncthreads();

  for (int k0 = 0; k0 < kC; k0 += 32) {
    int cur = (k0 >> 5) & 1;
    bfrag8 bf0 = b0n, bf1 = b1n;
    if (k0 + 32 < kC) {
      b0n = *(const bfrag8*)(bptr0 + k0 + 32);
      b1n = *(const bfrag8*)(bptr1 + k0 + 32);
    }
    bfrag8 a0 = *(const bfrag8*)(&pshare[cur][(0 * 64 + lane) * 8]);
    bfrag8 a1 = *(const bfrag8*)(&pshare[cur][(1 * 64 + lane) * 8]);
    acc00 = mfma16(a0, bf0, acc00);
    acc01 = mfma16(a0, bf1, acc01);
    acc10 = mfma16(a1, bf0, acc10);
    acc11 = mfma16(a1, bf1, acc11);
    if (k0 + 32 < kC) buildP(k0 + 32, cur ^ 1);
    __syncthreads();
  }

  // epilogue: out = acc * Zinv[i]; C/D layout col=lane&15, row=quad*4+reg
  #pragma unroll
  for (int reg = 0; reg < 4; ++reg) {
    int i_a = i0 + quad * 4 + reg;
    int i_b = i_a + 16;
    float za = Zinv[(size_t)b * kC + i_a];
    float zb = Zinv[(size_t)b * kC + i_b];
    float* oa = outw + ((size_t)b * kC + i_a) * kD + nbase + m;
    float* ob = outw + ((size_t)b * kC + i_b) * kD + nbase + m;
    oa[0]  = acc00[reg] * za;
    oa[16] = acc01[reg] * za;
    ob[0]  = acc10[reg] * zb;
    ob[16] = acc11[reg] * zb;
  }
}

// ---------- K8: row-GEMM (attn_out projection, in-place safe per block) ----------
__global__ __launch_bounds__(128) void k_gemm_rows(
    const float* __restrict__ x, const float* __restrict__ w, int wstride,
    const float* __restrict__ bias, float* __restrict__ out)
{
  int row0 = blockIdx.x * 8;
  int d = threadIdx.x;
  __shared__ float xs[8][kD];
  #pragma unroll
  for (int r = 0; r < 8; ++r) xs[r][d] = x[(size_t)(row0 + r) * kD + d];
  __syncthreads();
  float bv = bias[d];
  float acc[8];
  #pragma unroll
  for (int r = 0; r < 8; ++r) acc[r] = bv;
  for (int k = 0; k < kD; k += 4) {
    float w0 = w[(size_t)(k + 0) * wstride + d];
    float w1 = w[(size_t)(k + 1) * wstride + d];
    float w2 = w[(size_t)(k + 2) * wstride + d];
    float w3 = w[(size_t)(k + 3) * wstride + d];
    #pragma unroll
    for (int r = 0; r < 8; ++r) {
      float4 xv = *(const float4*)(&xs[r][k]);
      acc[r] += xv.x * w0 + xv.y * w1 + xv.z * w2 + xv.w * w3;
    }
  }
  #pragma unroll
  for (int r = 0; r < 8; ++r) out[(size_t)(row0 + r) * kD + d] = acc[r];
}

// ---------- K9: mix ----------
__global__ __launch_bounds__(128) void k_mix(
    const float* __restrict__ seq, const float* __restrict__ attn2,
    const float* __restrict__ w, const float* __restrict__ bias, float* __restrict__ feats)
{
  int row0 = blockIdx.x * 8;
  int d = threadIdx.x;
  __shared__ float xs[8][2 * kD];
  #pragma unroll
  for (int r = 0; r < 8; ++r) {
    xs[r][d]      = seq[(size_t)(row0 + r) * kD + d];
    xs[r][kD + d] = attn2[(size_t)(row0 + r) * kD + d];
  }
  __syncthreads();
  float bv = bias[d];
  float acc[8];
  #pragma unroll
  for (int r = 0; r < 8; ++r) acc[r] = bv;
  for (int k = 0; k < 2 * kD; k += 4) {
    float w0 = w[(size_t)(k + 0) * kD + d];
    float w1 = w[(size_t)(k + 1) * kD + d];
    float w2 = w[(size_t)(k + 2) * kD + d];
    float w3 = w[(size_t)(k + 3) * kD + d];
    #pragma unroll
    for (int r = 0; r < 8; ++r) {
      float4 xv = *(const float4*)(&xs[r][k]);
      acc[r] += xv.x * w0 + xv.y * w1 + xv.z * w2 + xv.w * w3;
    }
  }
  #pragma unroll
  for (int r = 0; r < 8; ++r) feats[(size_t)(row0 + r) * kD + d] = acc[r];
}

// ---------- K10: outputs ----------
__global__ __launch_bounds__(128) void k_part(const float* __restrict__ feats, float* __restrict__ part) {
  int b = blockIdx.x >> 4, g = blockIdx.x & 15, d = threadIdx.x;
  float s = 0.f;
  for (int c = g * 128; c < g * 128 + 128; ++c) s += feats[((size_t)b * kC + c) * kD + d];
  part[(size_t)blockIdx.x * kD + d] = s;
}
__global__ __launch_bounds__(128) void k_mean(const float* __restrict__ part, void* __restrict__ out,
                                              const int* __restrict__ flag) {
  int b = blockIdx.x, d = threadIdx.x;
  float s = 0.f;
  for (int g = 0; g < 16; ++g) s += part[((size_t)b * 16 + g) * kD + d];
  float r = s * (1.0f / kC);
  if (*flag) ((unsigned short*)out)[b * kD + d] = f2bf(r);
  else       ((float*)out)[b * kD + d] = r;
}
__global__ __launch_bounds__(256) void k_cast_out(const float* __restrict__ feats, void* __restrict__ out,
                                                  const int* __restrict__ flag) {
  int idx = blockIdx.x * 256 + threadIdx.x;
  float2 f = *(const float2*)(feats + (size_t)idx * 2);
  if (*flag) {
    unsigned* o = (unsigned*)((unsigned short*)out + kB * kD);
    o[idx] = (unsigned)f2bf(f.x) | ((unsigned)f2bf(f.y) << 16);
  } else {
    float2* o = (float2*)((float*)out + kB * kD);
    o[idx] = f;
  }
}

extern "C" void kernel_launch(void* const* d_in, const int* in_sizes, int n_in,
                              void* d_out, int out_size, void* d_ws, size_t ws_size,
                              hipStream_t stream) {
  const int* relations = (const int*)d_in[2];
  const int* begins    = (const int*)d_in[3];
  const int* ends      = (const int*)d_in[4];

  float* ws    = (float*)d_ws;
  float* feats = ws + OF_FEATS;
  float* seq   = ws + OF_SEQ;
  float* attnw = ws + OF_ATTN;
  float* sq    = ws + OF_SQ;
  float* sk    = ws + OF_SK;
  float* Mrow  = ws + OF_M;
  float* Zinv  = ws + OF_ZI;
  float* u     = ws + OF_U;
  float* part  = ws + OF_PART;
  float* prm   = ws + OF_PARAMS;
  int*   flag  = (int*)(ws + OF_FLAG);
  // V arena reuse: Vt bf16 (4 MB) then bitmask (4 MB)
  unsigned short*     Vt   = (unsigned short*)(ws + OF_V);
  unsigned long long* bits = (unsigned long long*)(ws + OF_V + (size_t)kB * kC * kD / 2);

  k_detect<<<1, 256, 0, stream>>>((const unsigned*)d_in[0], flag);
  ConvPtrs cp;
  for (int i = 0; i < 18; ++i) cp.p[i] = d_in[5 + i];
  k_conv<<<(PA_TOTAL + 255) / 256, 256, 0, stream>>>(cp, prm, flag);

  k_cast_ops<<<4092, 256, 0, stream>>>(d_in[0], feats, flag);
  k_maskbits<<<4092, 256, 0, stream>>>(d_in[1], bits, flag);
  k_begin_end<<<dim3(kB, 2), 128, 0, stream>>>(feats, begins, ends,
      prm + PA_INIT_BP_W, prm + PA_INIT_BP_B, prm + PA_INIT_EP_W, prm + PA_INIT_EP_B, feats);

  for (int l = 0; l < kL; ++l) {
    const float* aw = prm + PA_ATTN_W + (size_t)l * kD * 3 * kD;
    const float* ab = prm + PA_ATTN_B + (size_t)l * 3 * kD;

    k_begin_end<<<dim3(kB, 2), 128, 0, stream>>>(feats, begins, ends,
        prm + PA_BE_BP_W + (size_t)l * kD * kD, prm + PA_BE_BP_B + (size_t)l * kD,
        prm + PA_BE_EP_W + (size_t)l * kD * kD, prm + PA_BE_EP_B + (size_t)l * kD, seq);
    k_seq_mix<<<dim3(256, kB), 128, 0, stream>>>(feats, relations,
        prm + PA_SEQ_W + (size_t)l * 3 * kD * kD, prm + PA_SEQ_B + (size_t)l * kD, seq);

    k_uvec<<<1, 128, 0, stream>>>(aw, ab,
        prm + PA_SCORE_W + (size_t)l * 2 * kD, prm + PA_SCORE_B + l, u);
    k_sqsk<<<4096, 256, 0, stream>>>(feats, u, sq, sk);
    k_vproj<<<2048, 128, 0, stream>>>(feats, aw + 2 * kD, ab + 2 * kD, Vt);
    k_stats<<<4096, 256, 0, stream>>>(bits, sq, sk, Mrow, Zinv);
    k_attn_pv_mfma<<<dim3(64, kB), 256, 0, stream>>>((const unsigned*)bits,
        sq, sk, Mrow, Zinv, Vt, attnw);
    k_gemm_rows<<<2048, 128, 0, stream>>>(attnw,
        prm + PA_AO_W + (size_t)l * kD * kD, kD, prm + PA_AO_B + (size_t)l * kD, attnw);
    k_mix<<<2048, 128, 0, stream>>>(seq, attnw,
        prm + PA_MIX_W + (size_t)l * 2 * kD * kD, prm + PA_MIX_B + (size_t)l * kD, feats);
  }

  k_part<<<128, 128, 0, stream>>>(feats, part);
  k_mean<<<kB, 128, 0, stream>>>(part, d_out, flag);
  k_cast_out<<<4096, 256, 0, stream>>>(feats, d_out, flag);
}

// Round 4
// 566.492 us; speedup vs baseline: 2.5452x; 1.2027x over previous
//
#include <hip/hip_runtime.h>

// Problem constants
constexpr int kB = 8;
constexpr int kN = 2046;
constexpr int kC = 2048;   // kN + 2
constexpr int kD = 128;
constexpr int kJ = 128;
constexpr int kL = 2;

typedef short bfrag8 __attribute__((ext_vector_type(8)));
typedef float f32x4 __attribute__((ext_vector_type(4)));

// ---------- bf16 helpers ----------
__device__ __forceinline__ float bf2f(unsigned short h) {
  union { unsigned u; float f; } x; x.u = ((unsigned)h) << 16; return x.f;
}
__device__ __forceinline__ unsigned short f2bf(float f) {
  union { float f; unsigned u; } x; x.f = f;
  unsigned u = x.u;
  if ((u & 0x7fffffffu) > 0x7f800000u) return (unsigned short)((u >> 16) | 0x40);
  return (unsigned short)((u + 0x7fffu + ((u >> 16) & 1u)) >> 16);
}
__device__ __forceinline__ unsigned short f2bf_fast(float f) {  // finite inputs
  union { float f; unsigned u; } x; x.f = f;
  return (unsigned short)((x.u + 0x7fffu + ((x.u >> 16) & 1u)) >> 16);
}
// split x into hi+lo bf16 (16 mantissa bits total)
__device__ __forceinline__ void split2(float x, unsigned short& h, unsigned short& l) {
  unsigned short hh = f2bf_fast(x);
  h = hh;
  l = f2bf_fast(x - bf2f(hh));
}

// ---------- workspace layout (float offsets) ----------
constexpr size_t OF_FEATS  = 0;
constexpr size_t OF_SEQ    = OF_FEATS + (size_t)kB * kC * kD;
constexpr size_t OF_ATTN   = OF_SEQ   + (size_t)kB * kC * kD;
constexpr size_t OF_V      = OF_ATTN  + (size_t)kB * kC * kD;  // Vt bf16 (4MB) + bits (4MB)
constexpr size_t OF_SQ     = OF_V     + (size_t)kB * kC * kD;
constexpr size_t OF_SK     = OF_SQ    + (size_t)kB * kC;
constexpr size_t OF_M      = OF_SK    + (size_t)kB * kC;
constexpr size_t OF_ZI     = OF_M     + (size_t)kB * kC;
constexpr size_t OF_U      = OF_ZI    + (size_t)kB * kC;   // uq[128], uk[128], cc
constexpr size_t OF_PART   = OF_U     + 384;               // 16*kB*kD
constexpr size_t OF_PARAMS = OF_PART  + 2048;
constexpr int    PA_TOTAL  = 396048;
constexpr size_t OF_FLAG   = OF_PARAMS + PA_TOTAL;
constexpr size_t OF_BMIX   = OF_FLAG + 4;                  // fused mix bias, 2*128 f32
constexpr size_t OF_WT     = OF_BMIX + 256;                // bf16 Wt arena (ushort), 16B aligned

// param arena offsets (floats)
constexpr int PA_INIT_BP_W = 0;
constexpr int PA_INIT_BP_B = 16384;
constexpr int PA_INIT_EP_W = 16512;
constexpr int PA_INIT_EP_B = 32896;
constexpr int PA_BE_BP_W   = 33024;
constexpr int PA_BE_BP_B   = 65792;
constexpr int PA_BE_EP_W   = 66048;
constexpr int PA_BE_EP_B   = 98816;
constexpr int PA_SEQ_W     = 99072;
constexpr int PA_SEQ_B     = 197376;
constexpr int PA_ATTN_W    = 197632;
constexpr int PA_ATTN_B    = 295936;
constexpr int PA_SCORE_W   = 296704;
constexpr int PA_SCORE_B   = 297216;
constexpr int PA_AO_W      = 297224;
constexpr int PA_AO_B      = 329992;
constexpr int PA_MIX_W     = 330248;
constexpr int PA_MIX_B     = 395784;

// Wt arena (ushort offsets), per-layer stride
constexpr int WT_SEQH = 0;        // [128][384]
constexpr int WT_SEQL = 49152;
constexpr int WT_VH   = 98304;    // [128][128]
constexpr int WT_VL   = 114688;
constexpr int WT_MIXH = 131072;   // [128][256] (k<128: mix top; k>=128: fused ao@mixbot)
constexpr int WT_MIXL = 163840;
constexpr int WT_LS   = 196608;   // per-layer ushorts

// ---------- K0: dtype sniff ----------
__global__ __launch_bounds__(256) void k_detect(const unsigned* __restrict__ x, int* __restrict__ flag) {
  int t = threadIdx.x;
  int hits = 0;
  #pragma unroll
  for (int q = 0; q < 4; ++q) {
    unsigned w = x[t * 4 + q];
    unsigned e0 = (w >> 7) & 0xFFu;
    hits += (e0 == 0u || (e0 >= 96u && e0 <= 134u)) ? 1 : 0;
  }
  __shared__ int s[256];
  s[t] = hits; __syncthreads();
  for (int off = 128; off > 0; off >>= 1) { if (t < off) s[t] += s[t + off]; __syncthreads(); }
  if (t == 0) *flag = (s[0] >= 512) ? 1 : 0;
}

// ---------- K0b: params -> f32 arena ----------
struct ConvPtrs { const void* p[18]; };

__global__ __launch_bounds__(256) void k_conv(ConvPtrs cp, float* __restrict__ dst,
                                              const int* __restrict__ flag) {
  constexpr int off[18] = {PA_INIT_BP_W, PA_INIT_BP_B, PA_INIT_EP_W, PA_INIT_EP_B,
                           PA_BE_BP_W, PA_BE_BP_B, PA_BE_EP_W, PA_BE_EP_B,
                           PA_SEQ_W, PA_SEQ_B, PA_ATTN_W, PA_ATTN_B,
                           PA_SCORE_W, PA_SCORE_B, PA_AO_W, PA_AO_B, PA_MIX_W, PA_MIX_B};
  constexpr int cnt[18] = {16384, 128, 16384, 128, 32768, 256, 32768, 256,
                           98304, 256, 98304, 768, 512, 2, 32768, 256, 65536, 256};
  int idx = blockIdx.x * 256 + threadIdx.x;
  if (idx >= PA_TOTAL) return;
  int t = 0;
  #pragma unroll
  for (int i = 1; i < 18; ++i) if (idx >= off[i]) t = i;
  int rel = idx - off[t];
  if (rel >= cnt[t]) return;
  const void* src = cp.p[t];
  float v = (*flag) ? bf2f(((const unsigned short*)src)[rel]) : ((const float*)src)[rel];
  dst[idx] = v;
}

// ---------- K0c: transpose+split weights -> Wt bf16 arena ----------
__global__ __launch_bounds__(256) void k_wtprep(const float* __restrict__ prm,
                                                unsigned short* __restrict__ wt) {
  int idx = blockIdx.x * 256 + threadIdx.x;   // < 163840
  if (idx >= 163840) return;
  int l = idx / 81920;
  int r = idx - l * 81920;
  int k, n, srcOff, srcStride, srcCol, dH, dL, dStride;
  if (r < 49152) {
    k = r >> 7; n = r & 127;
    srcOff = PA_SEQ_W + l * 49152; srcStride = 128; srcCol = 0;
    dH = l * WT_LS + WT_SEQH; dL = l * WT_LS + WT_SEQL; dStride = 384;
  } else if (r < 65536) {
    int e = r - 49152; k = e >> 7; n = e & 127;
    srcOff = PA_ATTN_W + l * 49152; srcStride = 384; srcCol = 256;
    dH = l * WT_LS + WT_VH; dL = l * WT_LS + WT_VL; dStride = 128;
  } else {
    int e = r - 65536; k = e >> 7; n = e & 127;
    srcOff = PA_MIX_W + l * 32768; srcStride = 128; srcCol = 0;
    dH = l * WT_LS + WT_MIXH; dL = l * WT_LS + WT_MIXL; dStride = 256;
  }
  float v = prm[srcOff + (size_t)k * srcStride + srcCol + n];
  unsigned short h, lo;
  split2(v, h, lo);
  wt[dH + (size_t)n * dStride + k] = h;
  wt[dL + (size_t)n * dStride + k] = lo;
}

// ---------- K0d: fuse ao_w @ mix_w_bot into Wt_mix[k>=128], and fused bias ----------
__global__ __launch_bounds__(128) void k_wfuse(const float* __restrict__ prm,
                                               unsigned short* __restrict__ wt,
                                               float* __restrict__ bmix) {
  int l = blockIdx.y, d1 = blockIdx.x, d = threadIdx.x;
  const float* mixbot = prm + PA_MIX_W + (size_t)l * 2 * kD * kD + (size_t)kD * kD;
  if (d1 < 128) {
    const float* aow = prm + PA_AO_W + (size_t)l * kD * kD + (size_t)d1 * kD;
    float acc = 0.f;
    for (int d2 = 0; d2 < kD; ++d2) acc += aow[d2] * mixbot[(size_t)d2 * kD + d];
    unsigned short h, lo;
    split2(acc, h, lo);
    wt[l * WT_LS + WT_MIXH + (size_t)d * 256 + 128 + d1] = h;
    wt[l * WT_LS + WT_MIXL + (size_t)d * 256 + 128 + d1] = lo;
  } else {
    const float* aob = prm + PA_AO_B + (size_t)l * kD;
    float acc = prm[PA_MIX_B + (size_t)l * kD + d];
    for (int d2 = 0; d2 < kD; ++d2) acc += aob[d2] * mixbot[(size_t)d2 * kD + d];
    bmix[(size_t)l * kD + d] = acc;
  }
}

// ---------- K1: ops -> feats rows 0..N-1 ----------
__global__ __launch_bounds__(256) void k_cast_ops(const void* __restrict__ ops,
                                                  float* __restrict__ feats,
                                                  const int* __restrict__ flag) {
  int idx = blockIdx.x * 256 + threadIdx.x;
  int elem = idx * 2;
  int b = elem / (kN * kD);
  int r = elem - b * (kN * kD);
  float2 f;
  if (*flag) {
    unsigned u = ((const unsigned*)ops)[idx];
    f.x = bf2f((unsigned short)(u & 0xffffu));
    f.y = bf2f((unsigned short)(u >> 16));
  } else {
    f = ((const float2*)ops)[idx];
  }
  *(float2*)(feats + (size_t)b * kC * kD + r) = f;
}

// ---------- K1b: mask -> bit array ----------
__global__ __launch_bounds__(256) void k_maskbits(const void* __restrict__ mask,
                                                  unsigned long long* __restrict__ bits,
                                                  const int* __restrict__ flag) {
  int wave = threadIdx.x >> 6, lane = threadIdx.x & 63;
  int r = blockIdx.x * 4 + wave;            // 0..B*kN-1
  int b = r / kN;
  int i = r - b * kN;
  bool isbf = (*flag != 0);
  const unsigned short* mh = (const unsigned short*)mask + (size_t)r * kN;
  const unsigned*       mw = (const unsigned*)mask + (size_t)r * kN;
  unsigned long long* brow = bits + ((size_t)b * kC + i) * 32;
  for (int t = 0; t < 32; ++t) {
    int j = t * 64 + lane;
    bool nz = false;
    if (j < kN) nz = isbf ? (mh[j] != 0) : (mw[j] != 0);
    unsigned long long bm = __ballot(nz);
    if (lane == 0) brow[t] = bm;
  }
}

// ---------- K2: begin/end pooling ----------
__global__ __launch_bounds__(128) void k_begin_end(
    const float* __restrict__ src, const int* __restrict__ bidx, const int* __restrict__ eidx,
    const float* __restrict__ bp_w, const float* __restrict__ bp_b,
    const float* __restrict__ ep_w, const float* __restrict__ ep_b,
    float* __restrict__ dst)
{
  int b = blockIdx.x, sel = blockIdx.y;
  int d = threadIdx.x;
  const int* idx = sel ? (eidx + b * kJ) : (bidx + b * kJ);
  const float* w    = sel ? ep_w : bp_w;
  const float* bias = sel ? ep_b : bp_b;
  __shared__ float m[kD];
  float acc = 0.f;
  const float* sb = src + (size_t)b * kC * kD;
  for (int j = 0; j < kJ; ++j) acc += sb[(size_t)idx[j] * kD + d];
  m[d] = acc * (1.0f / kJ);
  __syncthreads();
  float o = bias[d];
  for (int k = 0; k < kD; k += 4) {
    float4 xv = *(const float4*)(&m[k]);
    o += xv.x * w[(k + 0) * kD + d] + xv.y * w[(k + 1) * kD + d]
       + xv.z * w[(k + 2) * kD + d] + xv.w * w[(k + 3) * kD + d];
  }
  dst[(size_t)b * kC * kD + (size_t)(kN + sel) * kD + d] = o;
}

// ---------- K5a: u-vectors ----------
__global__ __launch_bounds__(128) void k_uvec(
    const float* __restrict__ attn_w, const float* __restrict__ attn_b,
    const float* __restrict__ score_w, const float* __restrict__ score_b, float* __restrict__ u)
{
  int k = threadIdx.x;
  __shared__ float sw[2 * kD];
  sw[k] = score_w[k]; sw[kD + k] = score_w[kD + k];
  __syncthreads();
  const float* wr = attn_w + (size_t)k * (3 * kD);
  float uq = 0.f, uk = 0.f;
  #pragma unroll 4
  for (int d2 = 0; d2 < kD; ++d2) {
    uq += wr[d2] * sw[d2];
    uk += wr[kD + d2] * sw[kD + d2];
  }
  u[k] = uq; u[kD + k] = uk;
  __shared__ float red[kD];
  red[k] = attn_b[k] * sw[k] + attn_b[kD + k] * sw[kD + k];
  __syncthreads();
  if (k == 0) {
    float s = score_b[0];
    for (int i = 0; i < kD; ++i) s += red[i];
    u[2 * kD] = s;
  }
}

// ---------- K5b: sq/sk row scalars ----------
__global__ __launch_bounds__(256) void k_sqsk(const float* __restrict__ feats,
                                              const float* __restrict__ u,
                                              float* __restrict__ sq, float* __restrict__ sk) {
  int wave = threadIdx.x >> 6, lane = threadIdx.x & 63;
  int row = blockIdx.x * 4 + wave;
  const float* x = feats + (size_t)row * kD;
  float2 xv  = *(const float2*)(x + 2 * lane);
  float2 uqv = *(const float2*)(u + 2 * lane);
  float2 ukv = *(const float2*)(u + kD + 2 * lane);
  float a  = xv.x * uqv.x + xv.y * uqv.y;
  float b2 = xv.x * ukv.x + xv.y * ukv.y;
  for (int off = 32; off > 0; off >>= 1) { a += __shfl_down(a, off); b2 += __shfl_down(b2, off); }
  if (lane == 0) { sq[row] = a + u[2 * kD]; sk[row] = b2; }
}

// ---------- MFMA helper ----------
__device__ __forceinline__ f32x4 mfma16(bfrag8 a, bfrag8 b, f32x4 c) {
  return __builtin_amdgcn_mfma_f32_16x16x32_bf16(a, b, c, 0, 0, 0);
}

// ---------- K4: seq_mix GEMM (K=384, gathered A) ----------
__global__ __launch_bounds__(256) void k_mm_seq(
    const float* __restrict__ feats, const int* __restrict__ relations,
    const unsigned short* __restrict__ wth, const unsigned short* __restrict__ wtl,
    const float* __restrict__ bias, float* __restrict__ seq)
{
  constexpr int K = 384;
  int gr0 = blockIdx.x * 32;
  int b = gr0 >> 11, r0 = gr0 & 2047;
  int t = threadIdx.x;
  int lane = t & 63, w = t >> 6;
  int m = lane & 15, quad = lane >> 4;
  __shared__ unsigned short Ah[32 * 40], Al[32 * 40];
  int br = t >> 3, kq = (t & 7) * 4;
  int nl = r0 + br; if (nl > kN - 1) nl = kN - 1;
  const int* rel = relations + ((size_t)b * kN + nl) * 2;
  int rp = rel[0], rs = rel[1];
  int p = (rp < 0) ? kN : rp;
  int s = (rs < 0) ? (kN + 1) : rs;
  const float* fb = feats + (size_t)b * kC * kD;
  const float* s0 = fb + (size_t)nl * kD;
  const float* s1 = fb + (size_t)p * kD;
  const float* s2 = fb + (size_t)s * kD;
  const unsigned short* wh0 = wth + (size_t)(w * 32 + m) * K + quad * 8;
  const unsigned short* wh1 = wth + (size_t)(w * 32 + 16 + m) * K + quad * 8;
  const unsigned short* wl0 = wtl + (size_t)(w * 32 + m) * K + quad * 8;
  const unsigned short* wl1 = wtl + (size_t)(w * 32 + 16 + m) * K + quad * 8;
  f32x4 acc00 = {0.f, 0.f, 0.f, 0.f}, acc01 = acc00, acc10 = acc00, acc11 = acc00;
  for (int kb = 0; kb < K; kb += 32) {
    int kg = kb + kq;
    const float* sp = (kg < 128) ? (s0 + kg) : (kg < 256) ? (s1 + kg - 128) : (s2 + kg - 256);
    float4 x = *(const float4*)sp;
    unsigned short h0, h1, h2, h3, l0, l1, l2, l3;
    split2(x.x, h0, l0); split2(x.y, h1, l1); split2(x.z, h2, l2); split2(x.w, h3, l3);
    uint2 ph, pl;
    ph.x = h0 | ((unsigned)h1 << 16); ph.y = h2 | ((unsigned)h3 << 16);
    pl.x = l0 | ((unsigned)l1 << 16); pl.y = l2 | ((unsigned)l3 << 16);
    *(uint2*)(&Ah[br * 40 + kq]) = ph;
    *(uint2*)(&Al[br * 40 + kq]) = pl;
    __syncthreads();
    bfrag8 a0h = *(const bfrag8*)(&Ah[m * 40 + quad * 8]);
    bfrag8 a1h = *(const bfrag8*)(&Ah[(m + 16) * 40 + quad * 8]);
    bfrag8 a0l = *(const bfrag8*)(&Al[m * 40 + quad * 8]);
    bfrag8 a1l = *(const bfrag8*)(&Al[(m + 16) * 40 + quad * 8]);
    bfrag8 b0h = *(const bfrag8*)(wh0 + kb);
    bfrag8 b1h = *(const bfrag8*)(wh1 + kb);
    bfrag8 b0l = *(const bfrag8*)(wl0 + kb);
    bfrag8 b1l = *(const bfrag8*)(wl1 + kb);
    acc00 = mfma16(a0h, b0h, acc00); acc00 = mfma16(a0l, b0h, acc00); acc00 = mfma16(a0h, b0l, acc00);
    acc01 = mfma16(a0h, b1h, acc01); acc01 = mfma16(a0l, b1h, acc01); acc01 = mfma16(a0h, b1l, acc01);
    acc10 = mfma16(a1h, b0h, acc10); acc10 = mfma16(a1l, b0h, acc10); acc10 = mfma16(a1h, b0l, acc10);
    acc11 = mfma16(a1h, b1h, acc11); acc11 = mfma16(a1l, b1h, acc11); acc11 = mfma16(a1h, b1l, acc11);
    __syncthreads();
  }
  int n0 = w * 32 + m;
  float bv0 = bias[n0], bv1 = bias[n0 + 16];
  #pragma unroll
  for (int reg = 0; reg < 4; ++reg) {
    int ra = r0 + quad * 4 + reg;
    int rb = ra + 16;
    if (ra < kN) {
      seq[((size_t)b * kC + ra) * kD + n0]      = acc00[reg] + bv0;
      seq[((size_t)b * kC + ra) * kD + n0 + 16] = acc01[reg] + bv1;
    }
    if (rb < kN) {
      seq[((size_t)b * kC + rb) * kD + n0]      = acc10[reg] + bv0;
      seq[((size_t)b * kC + rb) * kD + n0 + 16] = acc11[reg] + bv1;
    }
  }
}

// ---------- K5c: v-projection GEMM (K=128) -> Vt bf16 [B][D][C] ----------
__global__ __launch_bounds__(256) void k_mm_vproj(
    const float* __restrict__ feats,
    const unsigned short* __restrict__ wth, const unsigned short* __restrict__ wtl,
    const float* __restrict__ bias, unsigned short* __restrict__ Vt)
{
  constexpr int K = 128;
  int gr0 = blockIdx.x * 32;
  int b = gr0 >> 11, r0 = gr0 & 2047;
  int t = threadIdx.x;
  int lane = t & 63, w = t >> 6;
  int m = lane & 15, quad = lane >> 4;
  __shared__ unsigned short Ah[32 * 40], Al[32 * 40];
  int br = t >> 3, kq = (t & 7) * 4;
  const float* s0 = feats + ((size_t)gr0 + br) * kD;
  const unsigned short* wh0 = wth + (size_t)(w * 32 + m) * K + quad * 8;
  const unsigned short* wh1 = wth + (size_t)(w * 32 + 16 + m) * K + quad * 8;
  const unsigned short* wl0 = wtl + (size_t)(w * 32 + m) * K + quad * 8;
  const unsigned short* wl1 = wtl + (size_t)(w * 32 + 16 + m) * K + quad * 8;
  f32x4 acc00 = {0.f, 0.f, 0.f, 0.f}, acc01 = acc00, acc10 = acc00, acc11 = acc00;
  for (int kb = 0; kb < K; kb += 32) {
    float4 x = *(const float4*)(s0 + kb + kq);
    unsigned short h0, h1, h2, h3, l0, l1, l2, l3;
    split2(x.x, h0, l0); split2(x.y, h1, l1); split2(x.z, h2, l2); split2(x.w, h3, l3);
    uint2 ph, pl;
    ph.x = h0 | ((unsigned)h1 << 16); ph.y = h2 | ((unsigned)h3 << 16);
    pl.x = l0 | ((unsigned)l1 << 16); pl.y = l2 | ((unsigned)l3 << 16);
    *(uint2*)(&Ah[br * 40 + kq]) = ph;
    *(uint2*)(&Al[br * 40 + kq]) = pl;
    __syncthreads();
    bfrag8 a0h = *(const bfrag8*)(&Ah[m * 40 + quad * 8]);
    bfrag8 a1h = *(const bfrag8*)(&Ah[(m + 16) * 40 + quad * 8]);
    bfrag8 a0l = *(const bfrag8*)(&Al[m * 40 + quad * 8]);
    bfrag8 a1l = *(const bfrag8*)(&Al[(m + 16) * 40 + quad * 8]);
    bfrag8 b0h = *(const bfrag8*)(wh0 + kb);
    bfrag8 b1h = *(const bfrag8*)(wh1 + kb);
    bfrag8 b0l = *(const bfrag8*)(wl0 + kb);
    bfrag8 b1l = *(const bfrag8*)(wl1 + kb);
    acc00 = mfma16(a0h, b0h, acc00); acc00 = mfma16(a0l, b0h, acc00); acc00 = mfma16(a0h, b0l, acc00);
    acc01 = mfma16(a0h, b1h, acc01); acc01 = mfma16(a0l, b1h, acc01); acc01 = mfma16(a0h, b1l, acc01);
    acc10 = mfma16(a1h, b0h, acc10); acc10 = mfma16(a1l, b0h, acc10); acc10 = mfma16(a1h, b0l, acc10);
    acc11 = mfma16(a1h, b1h, acc11); acc11 = mfma16(a1l, b1h, acc11); acc11 = mfma16(a1h, b1l, acc11);
    __syncthreads();
  }
  int n0 = w * 32 + m;
  float bv0 = bias[n0], bv1 = bias[n0 + 16];
  unsigned short* vtb = Vt + (size_t)b * kD * kC;
  #pragma unroll
  for (int reg = 0; reg < 4; ++reg) {
    int ca = r0 + quad * 4 + reg;
    int cb = ca + 16;
    vtb[(size_t)n0 * kC + ca]        = f2bf_fast(acc00[reg] + bv0);
    vtb[(size_t)(n0 + 16) * kC + ca] = f2bf_fast(acc01[reg] + bv1);
    vtb[(size_t)n0 * kC + cb]        = f2bf_fast(acc10[reg] + bv0);
    vtb[(size_t)(n0 + 16) * kC + cb] = f2bf_fast(acc11[reg] + bv1);
  }
}

// ---------- K9: fused mix GEMM (K=256: seq | attnw), ao projection folded into Wt ----------
__global__ __launch_bounds__(256) void k_mm_mix(
    const float* __restrict__ seq, const float* __restrict__ attnw,
    const unsigned short* __restrict__ wth, const unsigned short* __restrict__ wtl,
    const float* __restrict__ bias, float* __restrict__ outf)
{
  constexpr int K = 256;
  int gr0 = blockIdx.x * 32;
  int t = threadIdx.x;
  int lane = t & 63, w = t >> 6;
  int m = lane & 15, quad = lane >> 4;
  __shared__ unsigned short Ah[32 * 40], Al[32 * 40];
  int br = t >> 3, kq = (t & 7) * 4;
  const float* s0 = seq   + ((size_t)gr0 + br) * kD;
  const float* s1 = attnw + ((size_t)gr0 + br) * kD;
  const unsigned short* wh0 = wth + (size_t)(w * 32 + m) * K + quad * 8;
  const unsigned short* wh1 = wth + (size_t)(w * 32 + 16 + m) * K + quad * 8;
  const unsigned short* wl0 = wtl + (size_t)(w * 32 + m) * K + quad * 8;
  const unsigned short* wl1 = wtl + (size_t)(w * 32 + 16 + m) * K + quad * 8;
  f32x4 acc00 = {0.f, 0.f, 0.f, 0.f}, acc01 = acc00, acc10 = acc00, acc11 = acc00;
  for (int kb = 0; kb < K; kb += 32) {
    int kg = kb + kq;
    float4 x = (kg < kD) ? *(const float4*)(s0 + kg) : *(const float4*)(s1 + kg - kD);
    unsigned short h0, h1, h2, h3, l0, l1, l2, l3;
    split2(x.x, h0, l0); split2(x.y, h1, l1); split2(x.z, h2, l2); split2(x.w, h3, l3);
    uint2 ph, pl;
    ph.x = h0 | ((unsigned)h1 << 16); ph.y = h2 | ((unsigned)h3 << 16);
    pl.x = l0 | ((unsigned)l1 << 16); pl.y = l2 | ((unsigned)l3 << 16);
    *(uint2*)(&Ah[br * 40 + kq]) = ph;
    *(uint2*)(&Al[br * 40 + kq]) = pl;
    __syncthreads();
    bfrag8 a0h = *(const bfrag8*)(&Ah[m * 40 + quad * 8]);
    bfrag8 a1h = *(const bfrag8*)(&Ah[(m + 16) * 40 + quad * 8]);
    bfrag8 a0l = *(const bfrag8*)(&Al[m * 40 + quad * 8]);
    bfrag8 a1l = *(const bfrag8*)(&Al[(m + 16) * 40 + quad * 8]);
    bfrag8 b0h = *(const bfrag8*)(wh0 + kb);
    bfrag8 b1h = *(const bfrag8*)(wh1 + kb);
    bfrag8 b0l = *(const bfrag8*)(wl0 + kb);
    bfrag8 b1l = *(const bfrag8*)(wl1 + kb);
    acc00 = mfma16(a0h, b0h, acc00); acc00 = mfma16(a0l, b0h, acc00); acc00 = mfma16(a0h, b0l, acc00);
    acc01 = mfma16(a0h, b1h, acc01); acc01 = mfma16(a0l, b1h, acc01); acc01 = mfma16(a0h, b1l, acc01);
    acc10 = mfma16(a1h, b0h, acc10); acc10 = mfma16(a1l, b0h, acc10); acc10 = mfma16(a1h, b0l, acc10);
    acc11 = mfma16(a1h, b1h, acc11); acc11 = mfma16(a1l, b1h, acc11); acc11 = mfma16(a1h, b1l, acc11);
    __syncthreads();
  }
  int n0 = w * 32 + m;
  float bv0 = bias[n0], bv1 = bias[n0 + 16];
  #pragma unroll
  for (int reg = 0; reg < 4; ++reg) {
    int ra = gr0 + quad * 4 + reg;
    int rb = ra + 16;
    outf[(size_t)ra * kD + n0]      = acc00[reg] + bv0;
    outf[(size_t)ra * kD + n0 + 16] = acc01[reg] + bv1;
    outf[(size_t)rb * kD + n0]      = acc10[reg] + bv0;
    outf[(size_t)rb * kD + n0 + 16] = acc11[reg] + bv1;
  }
}

// ---------- K6: softmax row stats from bitmask ----------
__global__ __launch_bounds__(256) void k_stats(const unsigned long long* __restrict__ bits,
                                               const float* __restrict__ sq,
                                               const float* __restrict__ sk,
                                               float* __restrict__ Mrow, float* __restrict__ Zinv) {
  int wave = (int)threadIdx.x >> 6, lane = (int)threadIdx.x & 63;
  int row = blockIdx.x * 4 + wave;
  int b = row >> 11;
  int i = row & (kC - 1);
  float a = sq[row];
  const float* skb = sk + (size_t)b * kC;
  float vals[32];
  float mx = 0.f;
  if (i < kN) {
    const unsigned long long* brow = bits + ((size_t)b * kC + i) * 32;
    #pragma unroll
    for (int t = 0; t < 32; ++t) {
      unsigned long long bm = brow[t];
      int j = t * 64 + lane;
      float val = 0.f;
      if ((bm >> lane) & 1ull) {
        float s = a + skb[j];
        val = fmaxf(s, 0.01f * s);
      }
      vals[t] = val;
      mx = fmaxf(mx, val);
    }
  } else {
    #pragma unroll
    for (int t = 0; t < 32; ++t) {
      int j = t * 64 + lane;
      float val = 0.f;
      if (j == i) {
        float s = a + skb[j];
        val = fmaxf(s, 0.01f * s);
      }
      vals[t] = val;
      mx = fmaxf(mx, val);
    }
  }
  for (int off = 32; off > 0; off >>= 1) mx = fmaxf(mx, __shfl_down(mx, off));
  mx = __shfl(mx, 0);
  float zs = 0.f;
  #pragma unroll
  for (int t = 0; t < 32; ++t) zs += __expf(vals[t] - mx);
  for (int off = 32; off > 0; off >>= 1) zs += __shfl_down(zs, off);
  if (lane == 0) { Mrow[row] = mx; Zinv[row] = 1.0f / zs; }
}

// ---------- K7: MFMA PV ----------
__global__ __launch_bounds__(256) void k_attn_pv_mfma(
    const unsigned* __restrict__ bits,         // u32 view, row stride 64 u32
    const float* __restrict__ sq, const float* __restrict__ sk,
    const float* __restrict__ Mrow, const float* __restrict__ Zinv,
    const unsigned short* __restrict__ Vt,     // [B][D][C] bf16
    float* __restrict__ outw)                  // [B][C][D] f32
{
  int b = blockIdx.y;
  int i0 = blockIdx.x * 32;
  int t = threadIdx.x;
  int lane = t & 63;
  int w = t >> 6;

  __shared__ unsigned short pshare[2][1024];
  __shared__ float sklds[kC];
  __shared__ unsigned bitlds[2048];

  const float* skb = sk + (size_t)b * kC;
  #pragma unroll
  for (int q = 0; q < 8; ++q) sklds[q * 256 + t] = skb[q * 256 + t];
  const unsigned* bitrow = bits + ((size_t)b * kC + i0) * 64;
  #pragma unroll
  for (int q = 0; q < 8; ++q) bitlds[q * 256 + t] = bitrow[q * 256 + t];

  int f = t >> 1, h = t & 1;
  int mt_b = f >> 6;
  int lb = f & 63;
  int irow_l = mt_b * 16 + (lb & 15);
  int quad_b = lb >> 4;
  int i_g = i0 + irow_l;
  float sqi = sq[(size_t)b * kC + i_g];
  float mri = Mrow[(size_t)b * kC + i_g];
  int joff = quad_b * 8 + h * 4;
  bool irow_ok = (i_g < kN);
  const unsigned char* bitb = (const unsigned char*)bitlds + irow_l * 256;

  __syncthreads();

  auto buildP = [&](int k0, int buf) {
    float4 skv = *(const float4*)(sklds + k0 + joff);
    unsigned byte;
    if (irow_ok) {
      byte = bitb[(k0 >> 3) + quad_b];
    } else {
      int d0 = i_g - (k0 + quad_b * 8);
      byte = ((unsigned)d0 < 8u) ? (1u << d0) : 0u;
    }
    unsigned nib = byte >> (h * 4);
    unsigned short us[4];
    float sv[4] = {skv.x, skv.y, skv.z, skv.w};
    #pragma unroll
    for (int dj = 0; dj < 4; ++dj) {
      float s = sqi + sv[dj];
      float lr = fmaxf(s, 0.01f * s);
      float val = ((nib >> dj) & 1u) ? lr : 0.f;
      us[dj] = f2bf_fast(__expf(val - mri));
    }
    uint2 pk;
    pk.x = us[0] | ((unsigned)us[1] << 16);
    pk.y = us[2] | ((unsigned)us[3] << 16);
    *(uint2*)(&pshare[buf][f * 8 + h * 4]) = pk;
  };

  f32x4 acc00 = {0.f, 0.f, 0.f, 0.f}, acc01 = acc00, acc10 = acc00, acc11 = acc00;
  int m = lane & 15, quad = lane >> 4;
  int nbase = w * 32;
  const unsigned short* vtb = Vt + (size_t)b * kD * kC;
  const unsigned short* bptr0 = vtb + (size_t)(nbase + m) * kC + quad * 8;
  const unsigned short* bptr1 = vtb + (size_t)(nbase + 16 + m) * kC + quad * 8;

  buildP(0, 0);
  bfrag8 b0n = *(const bfrag8*)bptr0;
  bfrag8 b1n = *(const bfrag8*)bptr1;
  __syncthreads();

  for (int k0 = 0; k0 < kC; k0 += 32) {
    int cur = (k0 >> 5) & 1;
    bfrag8 bf0 = b0n, bf1 = b1n;
    if (k0 + 32 < kC) {
      b0n = *(const bfrag8*)(bptr0 + k0 + 32);
      b1n = *(const bfrag8*)(bptr1 + k0 + 32);
    }
    bfrag8 a0 = *(const bfrag8*)(&pshare[cur][(0 * 64 + lane) * 8]);
    bfrag8 a1 = *(const bfrag8*)(&pshare[cur][(1 * 64 + lane) * 8]);
    acc00 = mfma16(a0, bf0, acc00);
    acc01 = mfma16(a0, bf1, acc01);
    acc10 = mfma16(a1, bf0, acc10);
    acc11 = mfma16(a1, bf1, acc11);
    if (k0 + 32 < kC) buildP(k0 + 32, cur ^ 1);
    __syncthreads();
  }

  #pragma unroll
  for (int reg = 0; reg < 4; ++reg) {
    int i_a = i0 + quad * 4 + reg;
    int i_b = i_a + 16;
    float za = Zinv[(size_t)b * kC + i_a];
    float zb = Zinv[(size_t)b * kC + i_b];
    float* oa = outw + ((size_t)b * kC + i_a) * kD + nbase + m;
    float* ob = outw + ((size_t)b * kC + i_b) * kD + nbase + m;
    oa[0]  = acc00[reg] * za;
    oa[16] = acc01[reg] * za;
    ob[0]  = acc10[reg] * zb;
    ob[16] = acc11[reg] * zb;
  }
}

// ---------- K10: outputs ----------
__global__ __launch_bounds__(128) void k_part(const float* __restrict__ feats, float* __restrict__ part) {
  int b = blockIdx.x >> 4, g = blockIdx.x & 15, d = threadIdx.x;
  float s = 0.f;
  for (int c = g * 128; c < g * 128 + 128; ++c) s += feats[((size_t)b * kC + c) * kD + d];
  part[(size_t)blockIdx.x * kD + d] = s;
}
__global__ __launch_bounds__(128) void k_mean(const float* __restrict__ part, void* __restrict__ out,
                                              const int* __restrict__ flag) {
  int b = blockIdx.x, d = threadIdx.x;
  float s = 0.f;
  for (int g = 0; g < 16; ++g) s += part[((size_t)b * 16 + g) * kD + d];
  float r = s * (1.0f / kC);
  if (*flag) ((unsigned short*)out)[b * kD + d] = f2bf(r);
  else       ((float*)out)[b * kD + d] = r;
}
__global__ __launch_bounds__(256) void k_cast_out(const float* __restrict__ feats, void* __restrict__ out,
                                                  const int* __restrict__ flag) {
  int idx = blockIdx.x * 256 + threadIdx.x;
  float2 f = *(const float2*)(feats + (size_t)idx * 2);
  if (*flag) {
    unsigned* o = (unsigned*)((unsigned short*)out + kB * kD);
    o[idx] = (unsigned)f2bf(f.x) | ((unsigned)f2bf(f.y) << 16);
  } else {
    float2* o = (float2*)((float*)out + kB * kD);
    o[idx] = f;
  }
}

extern "C" void kernel_launch(void* const* d_in, const int* in_sizes, int n_in,
                              void* d_out, int out_size, void* d_ws, size_t ws_size,
                              hipStream_t stream) {
  const int* relations = (const int*)d_in[2];
  const int* begins    = (const int*)d_in[3];
  const int* ends      = (const int*)d_in[4];

  float* ws    = (float*)d_ws;
  float* feats = ws + OF_FEATS;
  float* seq   = ws + OF_SEQ;
  float* attnw = ws + OF_ATTN;
  float* sq    = ws + OF_SQ;
  float* sk    = ws + OF_SK;
  float* Mrow  = ws + OF_M;
  float* Zinv  = ws + OF_ZI;
  float* u     = ws + OF_U;
  float* part  = ws + OF_PART;
  float* prm   = ws + OF_PARAMS;
  int*   flag  = (int*)(ws + OF_FLAG);
  float* bmix  = ws + OF_BMIX;
  unsigned short* wt = (unsigned short*)(ws + OF_WT);
  unsigned short*     Vt   = (unsigned short*)(ws + OF_V);
  unsigned long long* bits = (unsigned long long*)(ws + OF_V + (size_t)kB * kC * kD / 2);

  k_detect<<<1, 256, 0, stream>>>((const unsigned*)d_in[0], flag);
  ConvPtrs cp;
  for (int i = 0; i < 18; ++i) cp.p[i] = d_in[5 + i];
  k_conv<<<(PA_TOTAL + 255) / 256, 256, 0, stream>>>(cp, prm, flag);
  k_wtprep<<<640, 256, 0, stream>>>(prm, wt);
  k_wfuse<<<dim3(129, 2), 128, 0, stream>>>(prm, wt, bmix);

  k_cast_ops<<<4092, 256, 0, stream>>>(d_in[0], feats, flag);
  k_maskbits<<<4092, 256, 0, stream>>>(d_in[1], bits, flag);
  k_begin_end<<<dim3(kB, 2), 128, 0, stream>>>(feats, begins, ends,
      prm + PA_INIT_BP_W, prm + PA_INIT_BP_B, prm + PA_INIT_EP_W, prm + PA_INIT_EP_B, feats);

  for (int l = 0; l < kL; ++l) {
    const float* aw = prm + PA_ATTN_W + (size_t)l * kD * 3 * kD;
    const float* ab = prm + PA_ATTN_B + (size_t)l * 3 * kD;
    const unsigned short* wl_base = wt + (size_t)l * WT_LS;

    k_begin_end<<<dim3(kB, 2), 128, 0, stream>>>(feats, begins, ends,
        prm + PA_BE_BP_W + (size_t)l * kD * kD, prm + PA_BE_BP_B + (size_t)l * kD,
        prm + PA_BE_EP_W + (size_t)l * kD * kD, prm + PA_BE_EP_B + (size_t)l * kD, seq);
    k_mm_seq<<<512, 256, 0, stream>>>(feats, relations,
        wl_base + WT_SEQH, wl_base + WT_SEQL, prm + PA_SEQ_B + (size_t)l * kD, seq);

    k_uvec<<<1, 128, 0, stream>>>(aw, ab,
        prm + PA_SCORE_W + (size_t)l * 2 * kD, prm + PA_SCORE_B + l, u);
    k_sqsk<<<4096, 256, 0, stream>>>(feats, u, sq, sk);
    k_mm_vproj<<<512, 256, 0, stream>>>(feats,
        wl_base + WT_VH, wl_base + WT_VL, ab + 2 * kD, Vt);
    k_stats<<<4096, 256, 0, stream>>>(bits, sq, sk, Mrow, Zinv);
    k_attn_pv_mfma<<<dim3(64, kB), 256, 0, stream>>>((const unsigned*)bits,
        sq, sk, Mrow, Zinv, Vt, attnw);
    k_mm_mix<<<512, 256, 0, stream>>>(seq, attnw,
        wl_base + WT_MIXH, wl_base + WT_MIXL, bmix + (size_t)l * kD, feats);
  }

  k_part<<<128, 128, 0, stream>>>(feats, part);
  k_mean<<<kB, 128, 0, stream>>>(part, d_out, flag);
  k_cast_out<<<4096, 256, 0, stream>>>(feats, d_out, flag);
}

// Round 5
// 554.043 us; speedup vs baseline: 2.6024x; 1.0225x over previous
//
#include <hip/hip_runtime.h>

// Problem constants
constexpr int kB = 8;
constexpr int kN = 2046;
constexpr int kC = 2048;   // kN + 2
constexpr int kD = 128;
constexpr int kJ = 128;
constexpr int kL = 2;

typedef short bfrag8 __attribute__((ext_vector_type(8)));
typedef float f32x4 __attribute__((ext_vector_type(4)));

// ---------- bf16 helpers ----------
__device__ __forceinline__ float bf2f(unsigned short h) {
  union { unsigned u; float f; } x; x.u = ((unsigned)h) << 16; return x.f;
}
__device__ __forceinline__ unsigned short f2bf(float f) {
  union { float f; unsigned u; } x; x.f = f;
  unsigned u = x.u;
  if ((u & 0x7fffffffu) > 0x7f800000u) return (unsigned short)((u >> 16) | 0x40);
  return (unsigned short)((u + 0x7fffu + ((u >> 16) & 1u)) >> 16);
}
__device__ __forceinline__ unsigned short f2bf_fast(float f) {  // finite inputs
  union { float f; unsigned u; } x; x.f = f;
  return (unsigned short)((x.u + 0x7fffu + ((x.u >> 16) & 1u)) >> 16);
}
__device__ __forceinline__ void split2(float x, unsigned short& h, unsigned short& l) {
  unsigned short hh = f2bf_fast(x);
  h = hh;
  l = f2bf_fast(x - bf2f(hh));
}

// ---------- workspace layout (float offsets) ----------
constexpr size_t OF_FEATS  = 0;
constexpr size_t OF_SEQ    = OF_FEATS + (size_t)kB * kC * kD;
constexpr size_t OF_ATTN   = OF_SEQ   + (size_t)kB * kC * kD;
constexpr size_t OF_V      = OF_ATTN  + (size_t)kB * kC * kD;  // Vt bf16 (4MB) + bits (4MB)
constexpr size_t OF_SQ     = OF_V     + (size_t)kB * kC * kD;
constexpr size_t OF_SK     = OF_SQ    + (size_t)kB * kC;
constexpr size_t OF_U      = OF_SK    + (size_t)kB * kC;   // 2 layers x 272 (uq,uk,cc)
constexpr size_t OF_PART   = OF_U     + 1024;              // kB*kD mean accumulators
constexpr size_t OF_PARAMS = OF_PART  + 2048;
constexpr int    PA_TOTAL  = 396048;
constexpr size_t OF_FLAG   = OF_PARAMS + PA_TOTAL;
constexpr size_t OF_BMIX   = OF_FLAG + 4;
constexpr size_t OF_WT     = OF_BMIX + 256;                // bf16 Wt arena (ushort)

// param arena offsets (floats)
constexpr int PA_INIT_BP_W = 0;
constexpr int PA_INIT_BP_B = 16384;
constexpr int PA_INIT_EP_W = 16512;
constexpr int PA_INIT_EP_B = 32896;
constexpr int PA_BE_BP_W   = 33024;
constexpr int PA_BE_BP_B   = 65792;
constexpr int PA_BE_EP_W   = 66048;
constexpr int PA_BE_EP_B   = 98816;
constexpr int PA_SEQ_W     = 99072;
constexpr int PA_SEQ_B     = 197376;
constexpr int PA_ATTN_W    = 197632;
constexpr int PA_ATTN_B    = 295936;
constexpr int PA_SCORE_W   = 296704;
constexpr int PA_SCORE_B   = 297216;
constexpr int PA_AO_W      = 297224;
constexpr int PA_AO_B      = 329992;
constexpr int PA_MIX_W     = 330248;
constexpr int PA_MIX_B     = 395784;

// Wt arena (ushort offsets), per-layer stride
constexpr int WT_SEQH = 0;        // [128][384]
constexpr int WT_SEQL = 49152;
constexpr int WT_VH   = 98304;    // [128][128]
constexpr int WT_VL   = 114688;
constexpr int WT_MIXH = 131072;   // [128][256] (k<128: mix top; k>=128: fused ao@mixbot)
constexpr int WT_MIXL = 163840;
constexpr int WT_LS   = 196608;

// ---------- K0: dtype sniff + zero mean accumulators ----------
__global__ __launch_bounds__(256) void k_detect(const unsigned* __restrict__ x, int* __restrict__ flag,
                                                float* __restrict__ part) {
  int t = threadIdx.x;
  #pragma unroll
  for (int q = 0; q < 4; ++q) part[q * 256 + t] = 0.f;
  int hits = 0;
  #pragma unroll
  for (int q = 0; q < 4; ++q) {
    unsigned w = x[t * 4 + q];
    unsigned e0 = (w >> 7) & 0xFFu;
    hits += (e0 == 0u || (e0 >= 96u && e0 <= 134u)) ? 1 : 0;
  }
  __shared__ int s[256];
  s[t] = hits; __syncthreads();
  for (int off = 128; off > 0; off >>= 1) { if (t < off) s[t] += s[t + off]; __syncthreads(); }
  if (t == 0) *flag = (s[0] >= 512) ? 1 : 0;
}

// ---------- K0b: params -> f32 arena ----------
struct ConvPtrs { const void* p[18]; };

__global__ __launch_bounds__(256) void k_conv(ConvPtrs cp, float* __restrict__ dst,
                                              const int* __restrict__ flag) {
  constexpr int off[18] = {PA_INIT_BP_W, PA_INIT_BP_B, PA_INIT_EP_W, PA_INIT_EP_B,
                           PA_BE_BP_W, PA_BE_BP_B, PA_BE_EP_W, PA_BE_EP_B,
                           PA_SEQ_W, PA_SEQ_B, PA_ATTN_W, PA_ATTN_B,
                           PA_SCORE_W, PA_SCORE_B, PA_AO_W, PA_AO_B, PA_MIX_W, PA_MIX_B};
  constexpr int cnt[18] = {16384, 128, 16384, 128, 32768, 256, 32768, 256,
                           98304, 256, 98304, 768, 512, 2, 32768, 256, 65536, 256};
  int idx = blockIdx.x * 256 + threadIdx.x;
  if (idx >= PA_TOTAL) return;
  int t = 0;
  #pragma unroll
  for (int i = 1; i < 18; ++i) if (idx >= off[i]) t = i;
  int rel = idx - off[t];
  if (rel >= cnt[t]) return;
  const void* src = cp.p[t];
  float v = (*flag) ? bf2f(((const unsigned short*)src)[rel]) : ((const float*)src)[rel];
  dst[idx] = v;
}

// ---------- K0c: transpose+split weights -> Wt bf16 arena ----------
__global__ __launch_bounds__(256) void k_wtprep(const float* __restrict__ prm,
                                                unsigned short* __restrict__ wt) {
  int idx = blockIdx.x * 256 + threadIdx.x;   // < 163840
  if (idx >= 163840) return;
  int l = idx / 81920;
  int r = idx - l * 81920;
  int k, n, srcOff, srcStride, srcCol, dH, dL, dStride;
  if (r < 49152) {
    k = r >> 7; n = r & 127;
    srcOff = PA_SEQ_W + l * 49152; srcStride = 128; srcCol = 0;
    dH = l * WT_LS + WT_SEQH; dL = l * WT_LS + WT_SEQL; dStride = 384;
  } else if (r < 65536) {
    int e = r - 49152; k = e >> 7; n = e & 127;
    srcOff = PA_ATTN_W + l * 49152; srcStride = 384; srcCol = 256;
    dH = l * WT_LS + WT_VH; dL = l * WT_LS + WT_VL; dStride = 128;
  } else {
    int e = r - 65536; k = e >> 7; n = e & 127;
    srcOff = PA_MIX_W + l * 32768; srcStride = 128; srcCol = 0;
    dH = l * WT_LS + WT_MIXH; dL = l * WT_LS + WT_MIXL; dStride = 256;
  }
  float v = prm[srcOff + (size_t)k * srcStride + srcCol + n];
  unsigned short h, lo;
  split2(v, h, lo);
  wt[dH + (size_t)n * dStride + k] = h;
  wt[dL + (size_t)n * dStride + k] = lo;
}

// ---------- K0d: fuse ao_w @ mix_w_bot into Wt_mix[k>=128], fused bias ----------
__global__ __launch_bounds__(128) void k_wfuse(const float* __restrict__ prm,
                                               unsigned short* __restrict__ wt,
                                               float* __restrict__ bmix) {
  int l = blockIdx.y, d1 = blockIdx.x, d = threadIdx.x;
  const float* mixbot = prm + PA_MIX_W + (size_t)l * 2 * kD * kD + (size_t)kD * kD;
  if (d1 < 128) {
    const float* aow = prm + PA_AO_W + (size_t)l * kD * kD + (size_t)d1 * kD;
    float acc = 0.f;
    for (int d2 = 0; d2 < kD; ++d2) acc += aow[d2] * mixbot[(size_t)d2 * kD + d];
    unsigned short h, lo;
    split2(acc, h, lo);
    wt[l * WT_LS + WT_MIXH + (size_t)d * 256 + 128 + d1] = h;
    wt[l * WT_LS + WT_MIXL + (size_t)d * 256 + 128 + d1] = lo;
  } else {
    const float* aob = prm + PA_AO_B + (size_t)l * kD;
    float acc = prm[PA_MIX_B + (size_t)l * kD + d];
    for (int d2 = 0; d2 < kD; ++d2) acc += aob[d2] * mixbot[(size_t)d2 * kD + d];
    bmix[(size_t)l * kD + d] = acc;
  }
}

// ---------- K0e: u-vectors for both layers ----------
__global__ __launch_bounds__(128) void k_uvec2(const float* __restrict__ prm, float* __restrict__ u2) {
  int l = blockIdx.x;
  const float* attn_w  = prm + PA_ATTN_W + (size_t)l * kD * 3 * kD;
  const float* attn_b  = prm + PA_ATTN_B + (size_t)l * 3 * kD;
  const float* score_w = prm + PA_SCORE_W + (size_t)l * 2 * kD;
  const float* score_b = prm + PA_SCORE_B + l;
  float* u = u2 + (size_t)l * 272;
  int k = threadIdx.x;
  __shared__ float sw[2 * kD];
  sw[k] = score_w[k]; sw[kD + k] = score_w[kD + k];
  __syncthreads();
  const float* wr = attn_w + (size_t)k * (3 * kD);
  float uq = 0.f, uk = 0.f;
  #pragma unroll 4
  for (int d2 = 0; d2 < kD; ++d2) {
    uq += wr[d2] * sw[d2];
    uk += wr[kD + d2] * sw[kD + d2];
  }
  u[k] = uq; u[kD + k] = uk;
  __shared__ float red[kD];
  red[k] = attn_b[k] * sw[k] + attn_b[kD + k] * sw[kD + k];
  __syncthreads();
  if (k == 0) {
    float s = score_b[0];
    for (int i = 0; i < kD; ++i) s += red[i];
    u[2 * kD] = s;
  }
}

// ---------- K1: ops -> feats rows 0..N-1 ----------
__global__ __launch_bounds__(256) void k_cast_ops(const void* __restrict__ ops,
                                                  float* __restrict__ feats,
                                                  const int* __restrict__ flag) {
  int idx = blockIdx.x * 256 + threadIdx.x;
  int elem = idx * 2;
  int b = elem / (kN * kD);
  int r = elem - b * (kN * kD);
  float2 f;
  if (*flag) {
    unsigned u = ((const unsigned*)ops)[idx];
    f.x = bf2f((unsigned short)(u & 0xffffu));
    f.y = bf2f((unsigned short)(u >> 16));
  } else {
    f = ((const float2*)ops)[idx];
  }
  *(float2*)(feats + (size_t)b * kC * kD + r) = f;
}

// ---------- K1b: mask -> bit array ----------
__global__ __launch_bounds__(256) void k_maskbits(const void* __restrict__ mask,
                                                  unsigned long long* __restrict__ bits,
                                                  const int* __restrict__ flag) {
  int wave = threadIdx.x >> 6, lane = threadIdx.x & 63;
  int r = blockIdx.x * 4 + wave;            // 0..B*kN-1
  int b = r / kN;
  int i = r - b * kN;
  bool isbf = (*flag != 0);
  const unsigned short* mh = (const unsigned short*)mask + (size_t)r * kN;
  const unsigned*       mw = (const unsigned*)mask + (size_t)r * kN;
  unsigned long long* brow = bits + ((size_t)b * kC + i) * 32;
  for (int t = 0; t < 32; ++t) {
    int j = t * 64 + lane;
    bool nz = false;
    if (j < kN) nz = isbf ? (mh[j] != 0) : (mw[j] != 0);
    unsigned long long bm = __ballot(nz);
    if (lane == 0) brow[t] = bm;
  }
}

// ---------- K2: begin/end pooling ----------
__global__ __launch_bounds__(128) void k_begin_end(
    const float* __restrict__ src, const int* __restrict__ bidx, const int* __restrict__ eidx,
    const float* __restrict__ bp_w, const float* __restrict__ bp_b,
    const float* __restrict__ ep_w, const float* __restrict__ ep_b,
    float* __restrict__ dst)
{
  int b = blockIdx.x, sel = blockIdx.y;
  int d = threadIdx.x;
  const int* idx = sel ? (eidx + b * kJ) : (bidx + b * kJ);
  const float* w    = sel ? ep_w : bp_w;
  const float* bias = sel ? ep_b : bp_b;
  __shared__ float m[kD];
  float acc = 0.f;
  const float* sb = src + (size_t)b * kC * kD;
  for (int j = 0; j < kJ; ++j) acc += sb[(size_t)idx[j] * kD + d];
  m[d] = acc * (1.0f / kJ);
  __syncthreads();
  float o = bias[d];
  for (int k = 0; k < kD; k += 4) {
    float4 xv = *(const float4*)(&m[k]);
    o += xv.x * w[(k + 0) * kD + d] + xv.y * w[(k + 1) * kD + d]
       + xv.z * w[(k + 2) * kD + d] + xv.w * w[(k + 3) * kD + d];
  }
  dst[(size_t)b * kC * kD + (size_t)(kN + sel) * kD + d] = o;
}

// ---------- MFMA helper ----------
__device__ __forceinline__ f32x4 mfma16(bfrag8 a, bfrag8 b, f32x4 c) {
  return __builtin_amdgcn_mfma_f32_16x16x32_bf16(a, b, c, 0, 0, 0);
}

// ---------- K4: seq_mix GEMM (K=384, gathered A, 16-row blocks) ----------
__global__ __launch_bounds__(256) void k_mm_seq(
    const float* __restrict__ feats, const int* __restrict__ relations,
    const unsigned short* __restrict__ wth, const unsigned short* __restrict__ wtl,
    const float* __restrict__ bias, float* __restrict__ seq)
{
  constexpr int K = 384;
  int gr0 = blockIdx.x * 16;
  int b = gr0 >> 11, r0 = gr0 & 2047;
  int t = threadIdx.x, lane = t & 63, w = t >> 6;
  int m = lane & 15, quad = lane >> 4;
  __shared__ unsigned short Ah[2][16 * 40], Al[2][16 * 40];
  int arow = t >> 4, kk = (t & 15) * 2;
  int nl = r0 + arow;
  int nr = (nl < kN) ? nl : (kN - 1);
  const int* rel = relations + ((size_t)b * kN + nr) * 2;
  int rp = rel[0], rs = rel[1];
  int p = (rp < 0) ? kN : rp;
  int s = (rs < 0) ? (kN + 1) : rs;
  const float* fb = feats + (size_t)b * kC * kD;
  const float* s0 = fb + (size_t)nl * kD;
  const float* s1 = fb + (size_t)p * kD;
  const float* s2 = fb + (size_t)s * kD;
  const unsigned short* bh0 = wth + (size_t)(w * 32 + m) * K + quad * 8;
  const unsigned short* bh1 = wth + (size_t)(w * 32 + 16 + m) * K + quad * 8;
  const unsigned short* bl0 = wtl + (size_t)(w * 32 + m) * K + quad * 8;
  const unsigned short* bl1 = wtl + (size_t)(w * 32 + 16 + m) * K + quad * 8;
  auto build = [&](int kb, int buf) {
    int kg = kb + kk;
    const float* sp = (kg < 128) ? (s0 + kg) : (kg < 256) ? (s1 + kg - 128) : (s2 + kg - 256);
    float2 x = *(const float2*)sp;
    unsigned short h0, l0, h1, l1;
    split2(x.x, h0, l0); split2(x.y, h1, l1);
    *(unsigned*)(&Ah[buf][arow * 40 + kk]) = (unsigned)h0 | ((unsigned)h1 << 16);
    *(unsigned*)(&Al[buf][arow * 40 + kk]) = (unsigned)l0 | ((unsigned)l1 << 16);
  };
  f32x4 acc0 = {0.f, 0.f, 0.f, 0.f}, acc1 = acc0;
  build(0, 0);
  __syncthreads();
  for (int kb = 0; kb < K; kb += 32) {
    int cur = (kb >> 5) & 1;
    bfrag8 ah = *(const bfrag8*)(&Ah[cur][m * 40 + quad * 8]);
    bfrag8 al = *(const bfrag8*)(&Al[cur][m * 40 + quad * 8]);
    bfrag8 f0h = *(const bfrag8*)(bh0 + kb);
    bfrag8 f1h = *(const bfrag8*)(bh1 + kb);
    bfrag8 f0l = *(const bfrag8*)(bl0 + kb);
    bfrag8 f1l = *(const bfrag8*)(bl1 + kb);
    if (kb + 32 < K) build(kb + 32, cur ^ 1);
    acc0 = mfma16(ah, f0h, acc0); acc0 = mfma16(al, f0h, acc0); acc0 = mfma16(ah, f0l, acc0);
    acc1 = mfma16(ah, f1h, acc1); acc1 = mfma16(al, f1h, acc1); acc1 = mfma16(ah, f1l, acc1);
    __syncthreads();
  }
  int n0 = w * 32 + m;
  float bv0 = bias[n0], bv1 = bias[n0 + 16];
  #pragma unroll
  for (int reg = 0; reg < 4; ++reg) {
    int ra = r0 + quad * 4 + reg;
    if (ra < kN) {
      seq[((size_t)b * kC + ra) * kD + n0]      = acc0[reg] + bv0;
      seq[((size_t)b * kC + ra) * kD + n0 + 16] = acc1[reg] + bv1;
    }
  }
}

// ---------- K5: v-projection GEMM (K=128) -> Vt bf16 [B][D][C], + fused sq/sk ----------
__global__ __launch_bounds__(256) void k_mm_vproj(
    const float* __restrict__ feats,
    const unsigned short* __restrict__ wth, const unsigned short* __restrict__ wtl,
    const float* __restrict__ bias, const float* __restrict__ uvec,
    unsigned short* __restrict__ Vt, float* __restrict__ sq, float* __restrict__ sk)
{
  constexpr int K = 128;
  int gr0 = blockIdx.x * 16;
  int b = gr0 >> 11, r0 = gr0 & 2047;
  int t = threadIdx.x, lane = t & 63, w = t >> 6;
  int m = lane & 15, quad = lane >> 4;
  __shared__ unsigned short Ah[2][16 * 40], Al[2][16 * 40];
  __shared__ float su[256];
  su[t] = uvec[t];
  int arow = t >> 4, kk = (t & 15) * 2;
  const float* s0 = feats + (size_t)(gr0 + arow) * kD;
  const unsigned short* bh0 = wth + (size_t)(w * 32 + m) * K + quad * 8;
  const unsigned short* bh1 = wth + (size_t)(w * 32 + 16 + m) * K + quad * 8;
  const unsigned short* bl0 = wtl + (size_t)(w * 32 + m) * K + quad * 8;
  const unsigned short* bl1 = wtl + (size_t)(w * 32 + 16 + m) * K + quad * 8;
  float pq = 0.f, pk2 = 0.f;
  auto build = [&](int kb, int buf) {
    int kg = kb + kk;
    float2 x = *(const float2*)(s0 + kg);
    pq  += x.x * su[kg]       + x.y * su[kg + 1];
    pk2 += x.x * su[128 + kg] + x.y * su[128 + kg + 1];
    unsigned short h0, l0, h1, l1;
    split2(x.x, h0, l0); split2(x.y, h1, l1);
    *(unsigned*)(&Ah[buf][arow * 40 + kk]) = (unsigned)h0 | ((unsigned)h1 << 16);
    *(unsigned*)(&Al[buf][arow * 40 + kk]) = (unsigned)l0 | ((unsigned)l1 << 16);
  };
  f32x4 acc0 = {0.f, 0.f, 0.f, 0.f}, acc1 = acc0;
  __syncthreads();          // su ready
  build(0, 0);
  __syncthreads();
  for (int kb = 0; kb < K; kb += 32) {
    int cur = (kb >> 5) & 1;
    bfrag8 ah = *(const bfrag8*)(&Ah[cur][m * 40 + quad * 8]);
    bfrag8 al = *(const bfrag8*)(&Al[cur][m * 40 + quad * 8]);
    bfrag8 f0h = *(const bfrag8*)(bh0 + kb);
    bfrag8 f1h = *(const bfrag8*)(bh1 + kb);
    bfrag8 f0l = *(const bfrag8*)(bl0 + kb);
    bfrag8 f1l = *(const bfrag8*)(bl1 + kb);
    if (kb + 32 < K) build(kb + 32, cur ^ 1);
    acc0 = mfma16(ah, f0h, acc0); acc0 = mfma16(al, f0h, acc0); acc0 = mfma16(ah, f0l, acc0);
    acc1 = mfma16(ah, f1h, acc1); acc1 = mfma16(al, f1h, acc1); acc1 = mfma16(ah, f1l, acc1);
    __syncthreads();
  }
  int n0 = w * 32 + m;
  float bv0 = bias[n0], bv1 = bias[n0 + 16];
  unsigned short* vtb = Vt + (size_t)b * kD * kC;
  #pragma unroll
  for (int reg = 0; reg < 4; ++reg) {
    int ca = r0 + quad * 4 + reg;
    vtb[(size_t)n0 * kC + ca]        = f2bf_fast(acc0[reg] + bv0);
    vtb[(size_t)(n0 + 16) * kC + ca] = f2bf_fast(acc1[reg] + bv1);
  }
  #pragma unroll
  for (int d2 = 1; d2 < 16; d2 <<= 1) {
    pq  += __shfl_xor(pq, d2);
    pk2 += __shfl_xor(pk2, d2);
  }
  if ((t & 15) == 0) {
    sq[(size_t)b * kC + r0 + arow] = pq + uvec[256];
    sk[(size_t)b * kC + r0 + arow] = pk2;
  }
}

// ---------- K7: MFMA PV with fused softmax stats ----------
__global__ __launch_bounds__(256) void k_attn_pv_mfma(
    const unsigned* __restrict__ bits,         // u32 view, row stride 64 u32
    const float* __restrict__ sq, const float* __restrict__ sk,
    const unsigned short* __restrict__ Vt,     // [B][D][C] bf16
    float* __restrict__ outw)                  // [B][C][D] f32
{
  int b = blockIdx.y;
  int i0 = blockIdx.x * 32;
  int t = threadIdx.x, lane = t & 63, w = t >> 6;

  __shared__ unsigned short pshare[2][1024];
  __shared__ float sklds[kC];
  __shared__ unsigned bitlds[2048];
  __shared__ float ssq[32], smx[32], szv[32];

  const float* skb = sk + (size_t)b * kC;
  #pragma unroll
  for (int q = 0; q < 8; ++q) sklds[q * 256 + t] = skb[q * 256 + t];
  const unsigned* bitrow = bits + ((size_t)b * kC + i0) * 64;
  #pragma unroll
  for (int q = 0; q < 8; ++q) bitlds[q * 256 + t] = bitrow[q * 256 + t];
  if (t < 32) ssq[t] = sq[(size_t)b * kC + i0 + t];
  __syncthreads();

  // ---- stats phase: 8 threads per row ----
  {
    int r = t >> 3, seg = t & 7;
    int ig = i0 + r;
    bool ok = (ig < kN);
    float sqi2 = ssq[r];
    const unsigned* bw = bitlds + r * 64 + seg * 8;
    const float* sks = sklds + seg * 256;
    float mx;
    if (ok) {
      float msk = -3e38f;
      #pragma unroll 1
      for (int w8 = 0; w8 < 8; ++w8) {
        unsigned bb = bw[w8];
        #pragma unroll
        for (int q4 = 0; q4 < 8; ++q4) {
          float4 skv = *(const float4*)(sks + w8 * 32 + q4 * 4);
          unsigned nib = bb >> (q4 * 4);
          msk = (nib & 1u) ? fmaxf(msk, skv.x) : msk;
          msk = (nib & 2u) ? fmaxf(msk, skv.y) : msk;
          msk = (nib & 4u) ? fmaxf(msk, skv.z) : msk;
          msk = (nib & 8u) ? fmaxf(msk, skv.w) : msk;
        }
      }
      #pragma unroll
      for (int d2 = 1; d2 < 8; d2 <<= 1) msk = fmaxf(msk, __shfl_xor(msk, d2));
      float s = sqi2 + msk;
      mx = fmaxf(0.f, fmaxf(s, 0.01f * s));
    } else {
      float s = sqi2 + sklds[ig & (kC - 1)];
      mx = fmaxf(0.f, fmaxf(s, 0.01f * s));
    }
    float emx = __expf(-mx);
    float zs = 0.f;
    if (ok) {
      #pragma unroll 1
      for (int w8 = 0; w8 < 8; ++w8) {
        unsigned bb = bw[w8];
        #pragma unroll
        for (int q4 = 0; q4 < 8; ++q4) {
          float4 skv = *(const float4*)(sks + w8 * 32 + q4 * 4);
          unsigned nib = bb >> (q4 * 4);
          float s1 = sqi2 + skv.x, l1 = fmaxf(s1, 0.01f * s1);
          float s2 = sqi2 + skv.y, l2 = fmaxf(s2, 0.01f * s2);
          float s3 = sqi2 + skv.z, l3 = fmaxf(s3, 0.01f * s3);
          float s4 = sqi2 + skv.w, l4 = fmaxf(s4, 0.01f * s4);
          zs += (nib & 1u) ? __expf(l1 - mx) : emx;
          zs += (nib & 2u) ? __expf(l2 - mx) : emx;
          zs += (nib & 4u) ? __expf(l3 - mx) : emx;
          zs += (nib & 8u) ? __expf(l4 - mx) : emx;
        }
      }
    } else {
      zs = 256.f * emx;
      if ((ig >> 8) == seg) {
        float s = sqi2 + sklds[ig & (kC - 1)];
        float lr = fmaxf(s, 0.01f * s);
        zs += __expf(lr - mx) - emx;
      }
    }
    #pragma unroll
    for (int d2 = 1; d2 < 8; d2 <<= 1) zs += __shfl_xor(zs, d2);
    if (seg == 0) { smx[r] = mx; szv[r] = 1.0f / zs; }
  }
  __syncthreads();

  // ---- PV phase ----
  int f = t >> 1, h = t & 1;
  int mt_b = f >> 6;
  int lb = f & 63;
  int irow_l = mt_b * 16 + (lb & 15);
  int quad_b = lb >> 4;
  int i_g = i0 + irow_l;
  float sqi = ssq[irow_l];
  float mri = smx[irow_l];
  int joff = quad_b * 8 + h * 4;
  bool irow_ok = (i_g < kN);
  const unsigned char* bitb = (const unsigned char*)bitlds + irow_l * 256;

  auto buildP = [&](int k0, int buf) {
    float4 skv = *(const float4*)(sklds + k0 + joff);
    unsigned byte;
    if (irow_ok) {
      byte = bitb[(k0 >> 3) + quad_b];
    } else {
      int d0 = i_g - (k0 + quad_b * 8);
      byte = ((unsigned)d0 < 8u) ? (1u << d0) : 0u;
    }
    unsigned nib = byte >> (h * 4);
    unsigned short us[4];
    float sv[4] = {skv.x, skv.y, skv.z, skv.w};
    #pragma unroll
    for (int dj = 0; dj < 4; ++dj) {
      float s = sqi + sv[dj];
      float lr = fmaxf(s, 0.01f * s);
      float val = ((nib >> dj) & 1u) ? lr : 0.f;
      us[dj] = f2bf_fast(__expf(val - mri));
    }
    uint2 pk;
    pk.x = us[0] | ((unsigned)us[1] << 16);
    pk.y = us[2] | ((unsigned)us[3] << 16);
    *(uint2*)(&pshare[buf][f * 8 + h * 4]) = pk;
  };

  f32x4 acc00 = {0.f, 0.f, 0.f, 0.f}, acc01 = acc00, acc10 = acc00, acc11 = acc00;
  int m = lane & 15, quad = lane >> 4;
  int nbase = w * 32;
  const unsigned short* vtb = Vt + (size_t)b * kD * kC;
  const unsigned short* bptr0 = vtb + (size_t)(nbase + m) * kC + quad * 8;
  const unsigned short* bptr1 = vtb + (size_t)(nbase + 16 + m) * kC + quad * 8;

  buildP(0, 0);
  bfrag8 b0n = *(const bfrag8*)bptr0;
  bfrag8 b1n = *(const bfrag8*)bptr1;
  __syncthreads();

  for (int k0 = 0; k0 < kC; k0 += 32) {
    int cur = (k0 >> 5) & 1;
    bfrag8 bf0 = b0n, bf1 = b1n;
    if (k0 + 32 < kC) {
      b0n = *(const bfrag8*)(bptr0 + k0 + 32);
      b1n = *(const bfrag8*)(bptr1 + k0 + 32);
    }
    bfrag8 a0 = *(const bfrag8*)(&pshare[cur][(0 * 64 + lane) * 8]);
    bfrag8 a1 = *(const bfrag8*)(&pshare[cur][(1 * 64 + lane) * 8]);
    acc00 = mfma16(a0, bf0, acc00);
    acc01 = mfma16(a0, bf1, acc01);
    acc10 = mfma16(a1, bf0, acc10);
    acc11 = mfma16(a1, bf1, acc11);
    if (k0 + 32 < kC) buildP(k0 + 32, cur ^ 1);
    __syncthreads();
  }

  #pragma unroll
  for (int reg = 0; reg < 4; ++reg) {
    int il_a = quad * 4 + reg;
    int i_a = i0 + il_a;
    int i_b = i_a + 16;
    float za = szv[il_a];
    float zb = szv[il_a + 16];
    float* oa = outw + ((size_t)b * kC + i_a) * kD + nbase + m;
    float* ob = outw + ((size_t)b * kC + i_b) * kD + nbase + m;
    oa[0]  = acc00[reg] * za;
    oa[16] = acc01[reg] * za;
    ob[0]  = acc10[reg] * zb;
    ob[16] = acc11[reg] * zb;
  }
}

// ---------- K9: fused mix GEMM (K=256: seq | attnw); mode1 writes outputs ----------
__global__ __launch_bounds__(256) void k_mm_mix(
    const float* __restrict__ seq, const float* __restrict__ attnw,
    const unsigned short* __restrict__ wth, const unsigned short* __restrict__ wtl,
    const float* __restrict__ bias, float* __restrict__ outf,
    void* __restrict__ outx, float* __restrict__ part, const int* __restrict__ flag,
    int mode)
{
  constexpr int K = 256;
  int gr0 = blockIdx.x * 16;
  int b = gr0 >> 11;
  int t = threadIdx.x, lane = t & 63, w = t >> 6;
  int m = lane & 15, quad = lane >> 4;
  __shared__ unsigned short Ah[2][16 * 40], Al[2][16 * 40];
  int arow = t >> 4, kk = (t & 15) * 2;
  const float* s0 = seq   + (size_t)(gr0 + arow) * kD;
  const float* s1 = attnw + (size_t)(gr0 + arow) * kD;
  const unsigned short* bh0 = wth + (size_t)(w * 32 + m) * K + quad * 8;
  const unsigned short* bh1 = wth + (size_t)(w * 32 + 16 + m) * K + quad * 8;
  const unsigned short* bl0 = wtl + (size_t)(w * 32 + m) * K + quad * 8;
  const unsigned short* bl1 = wtl + (size_t)(w * 32 + 16 + m) * K + quad * 8;
  auto build = [&](int kb, int buf) {
    int kg = kb + kk;
    float2 x = (kg < kD) ? *(const float2*)(s0 + kg) : *(const float2*)(s1 + kg - kD);
    unsigned short h0, l0, h1, l1;
    split2(x.x, h0, l0); split2(x.y, h1, l1);
    *(unsigned*)(&Ah[buf][arow * 40 + kk]) = (unsigned)h0 | ((unsigned)h1 << 16);
    *(unsigned*)(&Al[buf][arow * 40 + kk]) = (unsigned)l0 | ((unsigned)l1 << 16);
  };
  f32x4 acc0 = {0.f, 0.f, 0.f, 0.f}, acc1 = acc0;
  build(0, 0);
  __syncthreads();
  for (int kb = 0; kb < K; kb += 32) {
    int cur = (kb >> 5) & 1;
    bfrag8 ah = *(const bfrag8*)(&Ah[cur][m * 40 + quad * 8]);
    bfrag8 al = *(const bfrag8*)(&Al[cur][m * 40 + quad * 8]);
    bfrag8 f0h = *(const bfrag8*)(bh0 + kb);
    bfrag8 f1h = *(const bfrag8*)(bh1 + kb);
    bfrag8 f0l = *(const bfrag8*)(bl0 + kb);
    bfrag8 f1l = *(const bfrag8*)(bl1 + kb);
    if (kb + 32 < K) build(kb + 32, cur ^ 1);
    acc0 = mfma16(ah, f0h, acc0); acc0 = mfma16(al, f0h, acc0); acc0 = mfma16(ah, f0l, acc0);
    acc1 = mfma16(ah, f1h, acc1); acc1 = mfma16(al, f1h, acc1); acc1 = mfma16(ah, f1l, acc1);
    __syncthreads();
  }
  int n0 = w * 32 + m;
  float bv0 = bias[n0], bv1 = bias[n0 + 16];
  if (mode == 0) {
    #pragma unroll
    for (int reg = 0; reg < 4; ++reg) {
      size_t row = (size_t)gr0 + quad * 4 + reg;
      outf[row * kD + n0]      = acc0[reg] + bv0;
      outf[row * kD + n0 + 16] = acc1[reg] + bv1;
    }
  } else {
    float sum0 = 0.f, sum1 = 0.f;
    bool isbf = (*flag != 0);
    #pragma unroll
    for (int reg = 0; reg < 4; ++reg) {
      size_t row = (size_t)gr0 + quad * 4 + reg;
      float v0 = acc0[reg] + bv0;
      float v1 = acc1[reg] + bv1;
      if (isbf) {
        unsigned short* o = (unsigned short*)outx + 1024;
        o[row * kD + n0]      = f2bf(v0);
        o[row * kD + n0 + 16] = f2bf(v1);
      } else {
        float* o = (float*)outx + 1024;
        o[row * kD + n0]      = v0;
        o[row * kD + n0 + 16] = v1;
      }
      sum0 += v0; sum1 += v1;
    }
    sum0 += __shfl_xor(sum0, 16); sum0 += __shfl_xor(sum0, 32);
    sum1 += __shfl_xor(sum1, 16); sum1 += __shfl_xor(sum1, 32);
    if (quad == 0) {
      atomicAdd(&part[(size_t)b * kD + n0],      sum0);
      atomicAdd(&part[(size_t)b * kD + n0 + 16], sum1);
    }
  }
}

// ---------- K10: final mean ----------
__global__ __launch_bounds__(128) void k_mean(const float* __restrict__ part, void* __restrict__ out,
                                              const int* __restrict__ flag) {
  int b = blockIdx.x, d = threadIdx.x;
  float r = part[(size_t)b * kD + d] * (1.0f / kC);
  if (*flag) ((unsigned short*)out)[b * kD + d] = f2bf(r);
  else       ((float*)out)[b * kD + d] = r;
}

extern "C" void kernel_launch(void* const* d_in, const int* in_sizes, int n_in,
                              void* d_out, int out_size, void* d_ws, size_t ws_size,
                              hipStream_t stream) {
  const int* relations = (const int*)d_in[2];
  const int* begins    = (const int*)d_in[3];
  const int* ends      = (const int*)d_in[4];

  float* ws    = (float*)d_ws;
  float* feats = ws + OF_FEATS;
  float* seq   = ws + OF_SEQ;
  float* attnw = ws + OF_ATTN;
  float* sq    = ws + OF_SQ;
  float* sk    = ws + OF_SK;
  float* u2    = ws + OF_U;
  float* part  = ws + OF_PART;
  float* prm   = ws + OF_PARAMS;
  int*   flag  = (int*)(ws + OF_FLAG);
  float* bmix  = ws + OF_BMIX;
  unsigned short* wt = (unsigned short*)(ws + OF_WT);
  unsigned short*     Vt   = (unsigned short*)(ws + OF_V);
  unsigned long long* bits = (unsigned long long*)(ws + OF_V + (size_t)kB * kC * kD / 2);

  k_detect<<<1, 256, 0, stream>>>((const unsigned*)d_in[0], flag, part);
  ConvPtrs cp;
  for (int i = 0; i < 18; ++i) cp.p[i] = d_in[5 + i];
  k_conv<<<(PA_TOTAL + 255) / 256, 256, 0, stream>>>(cp, prm, flag);
  k_wtprep<<<640, 256, 0, stream>>>(prm, wt);
  k_wfuse<<<dim3(129, 2), 128, 0, stream>>>(prm, wt, bmix);
  k_uvec2<<<2, 128, 0, stream>>>(prm, u2);

  k_cast_ops<<<4092, 256, 0, stream>>>(d_in[0], feats, flag);
  k_maskbits<<<4092, 256, 0, stream>>>(d_in[1], bits, flag);
  k_begin_end<<<dim3(kB, 2), 128, 0, stream>>>(feats, begins, ends,
      prm + PA_INIT_BP_W, prm + PA_INIT_BP_B, prm + PA_INIT_EP_W, prm + PA_INIT_EP_B, feats);

  for (int l = 0; l < kL; ++l) {
    const unsigned short* wl_base = wt + (size_t)l * WT_LS;
    const float* ab = prm + PA_ATTN_B + (size_t)l * 3 * kD;

    k_begin_end<<<dim3(kB, 2), 128, 0, stream>>>(feats, begins, ends,
        prm + PA_BE_BP_W + (size_t)l * kD * kD, prm + PA_BE_BP_B + (size_t)l * kD,
        prm + PA_BE_EP_W + (size_t)l * kD * kD, prm + PA_BE_EP_B + (size_t)l * kD, seq);
    k_mm_seq<<<1024, 256, 0, stream>>>(feats, relations,
        wl_base + WT_SEQH, wl_base + WT_SEQL, prm + PA_SEQ_B + (size_t)l * kD, seq);
    k_mm_vproj<<<1024, 256, 0, stream>>>(feats,
        wl_base + WT_VH, wl_base + WT_VL, ab + 2 * kD, u2 + (size_t)l * 272, Vt, sq, sk);
    k_attn_pv_mfma<<<dim3(64, kB), 256, 0, stream>>>((const unsigned*)bits,
        sq, sk, Vt, attnw);
    k_mm_mix<<<1024, 256, 0, stream>>>(seq, attnw,
        wl_base + WT_MIXH, wl_base + WT_MIXL, bmix + (size_t)l * kD,
        feats, d_out, part, flag, (l == kL - 1) ? 1 : 0);
  }

  k_mean<<<kB, 128, 0, stream>>>(part, d_out, flag);
}

// Round 6
// 501.580 us; speedup vs baseline: 2.8745x; 1.1046x over previous
//
#include <hip/hip_runtime.h>

// Problem constants
constexpr int kB = 8;
constexpr int kN = 2046;
constexpr int kC = 2048;   // kN + 2
constexpr int kD = 128;
constexpr int kJ = 128;
constexpr int kL = 2;

typedef short bfrag8 __attribute__((ext_vector_type(8)));
typedef float f32x4 __attribute__((ext_vector_type(4)));

// ---------- bf16 helpers ----------
__device__ __forceinline__ float bf2f(unsigned short h) {
  union { unsigned u; float f; } x; x.u = ((unsigned)h) << 16; return x.f;
}
__device__ __forceinline__ unsigned short f2bf(float f) {
  union { float f; unsigned u; } x; x.f = f;
  unsigned u = x.u;
  if ((u & 0x7fffffffu) > 0x7f800000u) return (unsigned short)((u >> 16) | 0x40);
  return (unsigned short)((u + 0x7fffu + ((u >> 16) & 1u)) >> 16);
}
__device__ __forceinline__ unsigned short f2bf_fast(float f) {  // finite inputs
  union { float f; unsigned u; } x; x.f = f;
  return (unsigned short)((x.u + 0x7fffu + ((x.u >> 16) & 1u)) >> 16);
}
__device__ __forceinline__ void split2(float x, unsigned short& h, unsigned short& l) {
  unsigned short hh = f2bf_fast(x);
  h = hh;
  l = f2bf_fast(x - bf2f(hh));
}

// ---------- raw input pointers ----------
struct Raw {
  const void *ops, *mask;
  const int *rel, *bidx, *eidx;
  const void *ibw, *ibb, *iew, *ieb;       // init begin/end proj
  const void *bbw, *bbb, *bew, *beb;       // per-layer begin/end proj
  const void *sw, *sb;                     // seq_mix
  const void *aw, *ab;                     // attn_w
  const void *scw, *scb;                   // score
  const void *aow, *aob;                   // attn_out
  const void *mw, *mb;                     // mix
};

// read param: bf16 or f32
__device__ __forceinline__ float rp(const void* p, size_t i, bool bf) {
  return bf ? bf2f(((const unsigned short*)p)[i]) : ((const float*)p)[i];
}

// per-wave dtype sniff over first 1024 words of operation_features
__device__ __forceinline__ bool sniff(const Raw& r) {
  const unsigned* x = (const unsigned*)r.ops;
  int lane = (int)(threadIdx.x & 63);
  int hits = 0;
  #pragma unroll
  for (int q = 0; q < 16; ++q) {
    unsigned w = x[q * 64 + lane];
    unsigned e0 = (w >> 7) & 0xFFu;
    hits += (e0 == 0u || (e0 >= 96u && e0 <= 134u)) ? 1 : 0;
  }
  #pragma unroll
  for (int o = 1; o < 64; o <<= 1) hits += __shfl_xor(hits, o);
  return hits >= 512;
}

// ---------- workspace layout (float offsets) ----------
constexpr size_t OF_FEATS = 0;                       // 2097152
constexpr size_t OF_SEQ   = 2097152;
constexpr size_t OF_ATTN  = 4194304;
constexpr size_t OF_V     = 6291456;                 // Vt (1M floats) + bits (1M floats)
constexpr size_t OF_SQ    = 8388608;                 // 16384
constexpr size_t OF_SK    = 8404992;                 // 16384
constexpr size_t OF_U     = 8421376;                 // 2 x 272, padded 1024
constexpr size_t OF_PART  = 8422400;                 // 1024
constexpr size_t OF_BMIX  = 8423424;                 // 256
constexpr size_t OF_WT    = 8423680;                 // ushort arena

// Wt arena (ushort offsets), per-layer stride
constexpr int WT_SEQH = 0;        // [128][384]
constexpr int WT_SEQL = 49152;
constexpr int WT_VH   = 98304;    // [128][128]
constexpr int WT_VL   = 114688;
constexpr int WT_MIXH = 131072;   // [128][256]
constexpr int WT_MIXL = 163840;
constexpr int WT_LS   = 196608;

// prep role boundaries
constexpr int RP_CAST = 4092;
constexpr int RP_MASK = 8184;
constexpr int RP_WT   = 8824;
constexpr int RP_WF   = 9082;
constexpr int RP_UV   = 9084;
constexpr int RP_BE   = 9100;
constexpr int RP_TOT  = 9101;

// ---------- MFMA helpers ----------
__device__ __forceinline__ f32x4 mfma16(bfrag8 a, bfrag8 b, f32x4 c) {
  return __builtin_amdgcn_mfma_f32_16x16x32_bf16(a, b, c, 0, 0, 0);
}

// ---------- K0: mega-prep (all roles read raw inputs only) ----------
__global__ __launch_bounds__(256) void k_prep(Raw r, float* __restrict__ feats,
                                              unsigned long long* __restrict__ bits,
                                              unsigned short* __restrict__ wt,
                                              float* __restrict__ bmix,
                                              float* __restrict__ u2,
                                              float* __restrict__ part) {
  __shared__ __align__(16) char smem[4096];
  int bid = blockIdx.x, t = threadIdx.x;
  bool bf = sniff(r);

  if (bid < RP_CAST) {
    // cast ops -> feats rows 0..N-1
    int idx = bid * 256 + t;
    int elem = idx * 2;
    int b = elem / (kN * kD);
    int rr = elem - b * (kN * kD);
    float2 f;
    if (bf) {
      unsigned u = ((const unsigned*)r.ops)[idx];
      f.x = bf2f((unsigned short)(u & 0xffffu));
      f.y = bf2f((unsigned short)(u >> 16));
    } else {
      f = ((const float2*)r.ops)[idx];
    }
    *(float2*)(feats + (size_t)b * kC * kD + rr) = f;
  } else if (bid < RP_MASK) {
    // mask -> bit array
    int wave = t >> 6, lane = t & 63;
    int rr = (bid - RP_CAST) * 4 + wave;
    int b = rr / kN, i = rr - b * kN;
    const unsigned short* mh = (const unsigned short*)r.mask + (size_t)rr * kN;
    const unsigned*       mw = (const unsigned*)r.mask + (size_t)rr * kN;
    unsigned long long* brow = bits + ((size_t)b * kC + i) * 32;
    for (int tt = 0; tt < 32; ++tt) {
      int j = tt * 64 + lane;
      bool nz = false;
      if (j < kN) nz = bf ? (mh[j] != 0) : (mw[j] != 0);
      unsigned long long bm = __ballot(nz);
      if (lane == 0) brow[tt] = bm;
    }
  } else if (bid < RP_WT) {
    // transpose+split weights
    int idx = (bid - RP_MASK) * 256 + t;   // < 163840
    int l = idx / 81920;
    int rr = idx - l * 81920;
    const void* src; size_t si; int dH, dL, dS, k, n;
    if (rr < 49152) {
      k = rr >> 7; n = rr & 127;
      src = r.sw; si = (size_t)l * 49152 + (size_t)k * 128 + n;
      dH = l * WT_LS + WT_SEQH; dL = l * WT_LS + WT_SEQL; dS = 384;
    } else if (rr < 65536) {
      int e = rr - 49152; k = e >> 7; n = e & 127;
      src = r.aw; si = (size_t)l * 49152 + (size_t)k * 384 + 256 + n;
      dH = l * WT_LS + WT_VH; dL = l * WT_LS + WT_VL; dS = 128;
    } else {
      int e = rr - 65536; k = e >> 7; n = e & 127;
      src = r.mw; si = (size_t)l * 32768 + (size_t)k * 128 + n;
      dH = l * WT_LS + WT_MIXH; dL = l * WT_LS + WT_MIXL; dS = 256;
    }
    float v = rp(src, si, bf);
    unsigned short h, lo;
    split2(v, h, lo);
    wt[dH + (size_t)n * dS + k] = h;
    wt[dL + (size_t)n * dS + k] = lo;
  } else if (bid < RP_WF) {
    // fuse ao_w @ mix_bot
    int rb = bid - RP_WT;
    int l = rb / 129, d1 = rb - l * 129;
    if (t < 128) {
      int d = t;
      size_t mixbot = (size_t)l * 32768 + 16384;
      if (d1 < 128) {
        float acc = 0.f;
        for (int d2 = 0; d2 < kD; ++d2)
          acc += rp(r.aow, (size_t)l * 16384 + (size_t)d1 * 128 + d2, bf)
               * rp(r.mw, mixbot + (size_t)d2 * 128 + d, bf);
        unsigned short h, lo;
        split2(acc, h, lo);
        wt[l * WT_LS + WT_MIXH + (size_t)d * 256 + 128 + d1] = h;
        wt[l * WT_LS + WT_MIXL + (size_t)d * 256 + 128 + d1] = lo;
      } else {
        float acc = rp(r.mb, (size_t)l * 128 + d, bf);
        for (int d2 = 0; d2 < kD; ++d2)
          acc += rp(r.aob, (size_t)l * 128 + d2, bf)
               * rp(r.mw, mixbot + (size_t)d2 * 128 + d, bf);
        bmix[(size_t)l * kD + d] = acc;
      }
    }
  } else if (bid < RP_UV) {
    // u-vectors
    int l = bid - RP_WF;
    float* swm = (float*)smem;          // 256 floats
    float* red = (float*)smem + 256;    // 128 floats
    if (t < 128) {
      swm[t]       = rp(r.scw, (size_t)l * 256 + t, bf);
      swm[128 + t] = rp(r.scw, (size_t)l * 256 + 128 + t, bf);
    }
    __syncthreads();
    if (t < 128) {
      int k = t;
      size_t base = (size_t)l * 49152 + (size_t)k * 384;
      float uq = 0.f, uk = 0.f;
      for (int d2 = 0; d2 < kD; ++d2) {
        uq += rp(r.aw, base + d2, bf) * swm[d2];
        uk += rp(r.aw, base + 128 + d2, bf) * swm[128 + d2];
      }
      float* u = u2 + (size_t)l * 272;
      u[k] = uq; u[128 + k] = uk;
      red[k] = rp(r.ab, (size_t)l * 384 + k, bf) * swm[k]
             + rp(r.ab, (size_t)l * 384 + 128 + k, bf) * swm[128 + k];
    }
    __syncthreads();
    if (t == 0) {
      float s = rp(r.scb, l, bf);
      for (int i = 0; i < 128; ++i) s += red[i];
      u2[(size_t)l * 272 + 256] = s;
    }
  } else if (bid < RP_BE) {
    // init begin/end (gathers raw ops)
    int rb = bid - RP_UV;
    int b = rb >> 1, sel = rb & 1;
    float* msh = (float*)smem;
    const int* idx = (sel ? r.eidx : r.bidx) + b * kJ;
    const void* wv = sel ? r.iew : r.ibw;
    const void* bb = sel ? r.ieb : r.ibb;
    if (t < 128) {
      int d = t;
      float acc = 0.f;
      for (int j = 0; j < kJ; ++j)
        acc += rp(r.ops, ((size_t)b * kN + idx[j]) * kD + d, bf);
      msh[d] = acc * (1.0f / kJ);
    }
    __syncthreads();
    if (t < 128) {
      int d = t;
      float o = rp(bb, d, bf);
      for (int k = 0; k < kD; ++k) o += msh[k] * rp(wv, (size_t)k * kD + d, bf);
      feats[(size_t)b * kC * kD + (size_t)(kN + sel) * kD + d] = o;
    }
  } else {
    // zero mean accumulators
    #pragma unroll
    for (int q = 0; q < 4; ++q) part[q * 256 + t] = 0.f;
  }
}

// ---------- K1: stage1 — seq GEMM + vproj GEMM + layer begin/end ----------
__global__ __launch_bounds__(256) void k_stage1(Raw r, int l,
    const float* __restrict__ feats, const unsigned short* __restrict__ wt,
    const float* __restrict__ u2, float* __restrict__ seq,
    unsigned short* __restrict__ Vt, float* __restrict__ sq, float* __restrict__ sk)
{
  __shared__ __align__(16) char smem[21504];
  unsigned short (*Ah)[64 * 40] = (unsigned short(*)[64 * 40])smem;
  unsigned short (*Al)[64 * 40] = (unsigned short(*)[64 * 40])(smem + 10240);
  float* su = (float*)(smem + 20480);
  int bid = blockIdx.x, t = threadIdx.x;
  int lane = t & 63, w = t >> 6, m = lane & 15, quad = lane >> 4;
  bool bf = sniff(r);
  const unsigned short* wl = wt + (size_t)l * WT_LS;

  if (bid < 512) {
    bool isv = bid >= 256;
    int rb = isv ? bid - 256 : bid;
    int gr0 = rb * 64;
    int b = gr0 >> 11, r0 = gr0 & 2047;
    int arow = t >> 2, kq = (t & 3) * 8;
    int nl = r0 + arow;
    const float* fb = feats + (size_t)b * kC * kD;
    const float *s0, *s1, *s2;
    if (!isv) {
      int nr = (nl <= kN - 1) ? nl : (kN - 1);
      const int* rel = r.rel + ((size_t)b * kN + nr) * 2;
      int rpd = rel[0], rsc = rel[1];
      int p = (rpd < 0) ? kN : rpd;
      int s = (rsc < 0) ? (kN + 1) : rsc;
      s0 = fb + (size_t)nl * kD;
      s1 = fb + (size_t)p * kD;
      s2 = fb + (size_t)s * kD;
    } else {
      s0 = fb + (size_t)nl * kD; s1 = s0; s2 = s0;
      su[t] = u2[(size_t)l * 272 + t];
    }
    const int K = isv ? 128 : 384;
    const unsigned short* wth = isv ? (wl + WT_VH) : (wl + WT_SEQH);
    const unsigned short* wtl = isv ? (wl + WT_VL) : (wl + WT_SEQL);
    const unsigned short* bh0p = wth + (size_t)(w * 32 + m) * K + quad * 8;
    const unsigned short* bh1p = wth + (size_t)(w * 32 + 16 + m) * K + quad * 8;
    const unsigned short* bl0p = wtl + (size_t)(w * 32 + m) * K + quad * 8;
    const unsigned short* bl1p = wtl + (size_t)(w * 32 + 16 + m) * K + quad * 8;
    float pq = 0.f, pk2 = 0.f;

    auto build = [&](int kb, int buf) {
      int kg = kb + kq;
      const float* sp;
      if (!isv) sp = (kg < 128) ? (s0 + kg) : (kg < 256) ? (s1 + kg - 128) : (s2 + kg - 256);
      else      sp = s0 + kg;
      float4 xa = *(const float4*)sp;
      float4 xb = *(const float4*)(sp + 4);
      if (isv) {
        pq  += xa.x * su[kg]     + xa.y * su[kg + 1] + xa.z * su[kg + 2] + xa.w * su[kg + 3]
             + xb.x * su[kg + 4] + xb.y * su[kg + 5] + xb.z * su[kg + 6] + xb.w * su[kg + 7];
        pk2 += xa.x * su[128 + kg]     + xa.y * su[128 + kg + 1] + xa.z * su[128 + kg + 2] + xa.w * su[128 + kg + 3]
             + xb.x * su[128 + kg + 4] + xb.y * su[128 + kg + 5] + xb.z * su[128 + kg + 6] + xb.w * su[128 + kg + 7];
      }
      unsigned short h[8], lo[8];
      split2(xa.x, h[0], lo[0]); split2(xa.y, h[1], lo[1]);
      split2(xa.z, h[2], lo[2]); split2(xa.w, h[3], lo[3]);
      split2(xb.x, h[4], lo[4]); split2(xb.y, h[5], lo[5]);
      split2(xb.z, h[6], lo[6]); split2(xb.w, h[7], lo[7]);
      uint4 ph, pl;
      ph.x = h[0] | ((unsigned)h[1] << 16);  ph.y = h[2] | ((unsigned)h[3] << 16);
      ph.z = h[4] | ((unsigned)h[5] << 16);  ph.w = h[6] | ((unsigned)h[7] << 16);
      pl.x = lo[0] | ((unsigned)lo[1] << 16); pl.y = lo[2] | ((unsigned)lo[3] << 16);
      pl.z = lo[4] | ((unsigned)lo[5] << 16); pl.w = lo[6] | ((unsigned)lo[7] << 16);
      *(uint4*)&Ah[buf][arow * 40 + kq] = ph;
      *(uint4*)&Al[buf][arow * 40 + kq] = pl;
    };

    f32x4 acc[4][2];
    #pragma unroll
    for (int mi = 0; mi < 4; ++mi) { acc[mi][0] = {0.f,0.f,0.f,0.f}; acc[mi][1] = {0.f,0.f,0.f,0.f}; }

    __syncthreads();   // su visible (vproj role)
    build(0, 0);
    __syncthreads();
    for (int kb = 0; kb < K; kb += 32) {
      int cur = (kb >> 5) & 1;
      bfrag8 bh0 = *(const bfrag8*)(bh0p + kb);
      bfrag8 bh1 = *(const bfrag8*)(bh1p + kb);
      bfrag8 bl0 = *(const bfrag8*)(bl0p + kb);
      bfrag8 bl1 = *(const bfrag8*)(bl1p + kb);
      if (kb + 32 < K) build(kb + 32, cur ^ 1);
      #pragma unroll
      for (int mi = 0; mi < 4; ++mi) {
        bfrag8 ah = *(const bfrag8*)&Ah[cur][(mi * 16 + m) * 40 + quad * 8];
        bfrag8 al = *(const bfrag8*)&Al[cur][(mi * 16 + m) * 40 + quad * 8];
        acc[mi][0] = mfma16(ah, bh0, acc[mi][0]);
        acc[mi][0] = mfma16(al, bh0, acc[mi][0]);
        acc[mi][0] = mfma16(ah, bl0, acc[mi][0]);
        acc[mi][1] = mfma16(ah, bh1, acc[mi][1]);
        acc[mi][1] = mfma16(al, bh1, acc[mi][1]);
        acc[mi][1] = mfma16(ah, bl1, acc[mi][1]);
      }
      __syncthreads();
    }

    int n0 = w * 32 + m;
    if (!isv) {
      float bv0 = rp(r.sb, (size_t)l * 128 + n0, bf);
      float bv1 = rp(r.sb, (size_t)l * 128 + n0 + 16, bf);
      #pragma unroll
      for (int mi = 0; mi < 4; ++mi)
        #pragma unroll
        for (int reg = 0; reg < 4; ++reg) {
          int ra = r0 + mi * 16 + quad * 4 + reg;
          if (ra < kN) {
            seq[((size_t)b * kC + ra) * kD + n0]      = acc[mi][0][reg] + bv0;
            seq[((size_t)b * kC + ra) * kD + n0 + 16] = acc[mi][1][reg] + bv1;
          }
        }
    } else {
      float bv0 = rp(r.ab, (size_t)l * 384 + 256 + n0, bf);
      float bv1 = rp(r.ab, (size_t)l * 384 + 256 + n0 + 16, bf);
      unsigned short* vtb = Vt + (size_t)b * kD * kC;
      #pragma unroll
      for (int mi = 0; mi < 4; ++mi)
        #pragma unroll
        for (int reg = 0; reg < 4; ++reg) {
          int ca = r0 + mi * 16 + quad * 4 + reg;
          vtb[(size_t)n0 * kC + ca]        = f2bf_fast(acc[mi][0][reg] + bv0);
          vtb[(size_t)(n0 + 16) * kC + ca] = f2bf_fast(acc[mi][1][reg] + bv1);
        }
      pq  += __shfl_xor(pq, 1);  pq  += __shfl_xor(pq, 2);
      pk2 += __shfl_xor(pk2, 1); pk2 += __shfl_xor(pk2, 2);
      if ((t & 3) == 0) {
        sq[(size_t)b * kC + nl] = pq + u2[(size_t)l * 272 + 256];
        sk[(size_t)b * kC + nl] = pk2;
      }
    }
  } else {
    // layer begin/end: reads feats, writes seq rows N, N+1
    int rb = bid - 512;
    int b = rb >> 1, sel = rb & 1;
    float* msh = (float*)smem;
    const int* idx = (sel ? r.eidx : r.bidx) + b * kJ;
    const void* wv = sel ? r.bew : r.bbw;
    const void* bb = sel ? r.beb : r.bbb;
    size_t wbase = (size_t)l * kD * kD, bbase = (size_t)l * kD;
    if (t < 128) {
      int d = t;
      const float* fb2 = feats + (size_t)b * kC * kD;
      float acc = 0.f;
      for (int j = 0; j < kJ; ++j) acc += fb2[(size_t)idx[j] * kD + d];
      msh[d] = acc * (1.0f / kJ);
    }
    __syncthreads();
    if (t < 128) {
      int d = t;
      float o = rp(bb, bbase + d, bf);
      for (int k = 0; k < kD; ++k) o += msh[k] * rp(wv, wbase + (size_t)k * kD + d, bf);
      seq[(size_t)b * kC * kD + (size_t)(kN + sel) * kD + d] = o;
    }
  }
}

// ---------- K2: MFMA PV with fused softmax stats (unchanged from R5 — proven) ----------
__global__ __launch_bounds__(256) void k_attn_pv_mfma(
    const unsigned* __restrict__ bits,
    const float* __restrict__ sq, const float* __restrict__ sk,
    const unsigned short* __restrict__ Vt,
    float* __restrict__ outw)
{
  int b = blockIdx.y;
  int i0 = blockIdx.x * 32;
  int t = threadIdx.x, lane = t & 63, w = t >> 6;

  __shared__ unsigned short pshare[2][1024];
  __shared__ float sklds[kC];
  __shared__ unsigned bitlds[2048];
  __shared__ float ssq[32], smx[32], szv[32];

  const float* skb = sk + (size_t)b * kC;
  #pragma unroll
  for (int q = 0; q < 8; ++q) sklds[q * 256 + t] = skb[q * 256 + t];
  const unsigned* bitrow = bits + ((size_t)b * kC + i0) * 64;
  #pragma unroll
  for (int q = 0; q < 8; ++q) bitlds[q * 256 + t] = bitrow[q * 256 + t];
  if (t < 32) ssq[t] = sq[(size_t)b * kC + i0 + t];
  __syncthreads();

  {
    int rr = t >> 3, seg = t & 7;
    int ig = i0 + rr;
    bool ok = (ig < kN);
    float sqi2 = ssq[rr];
    const unsigned* bw = bitlds + rr * 64 + seg * 8;
    const float* sks = sklds + seg * 256;
    float mx;
    if (ok) {
      float msk = -3e38f;
      #pragma unroll 1
      for (int w8 = 0; w8 < 8; ++w8) {
        unsigned bb = bw[w8];
        #pragma unroll
        for (int q4 = 0; q4 < 8; ++q4) {
          float4 skv = *(const float4*)(sks + w8 * 32 + q4 * 4);
          unsigned nib = bb >> (q4 * 4);
          msk = (nib & 1u) ? fmaxf(msk, skv.x) : msk;
          msk = (nib & 2u) ? fmaxf(msk, skv.y) : msk;
          msk = (nib & 4u) ? fmaxf(msk, skv.z) : msk;
          msk = (nib & 8u) ? fmaxf(msk, skv.w) : msk;
        }
      }
      #pragma unroll
      for (int d2 = 1; d2 < 8; d2 <<= 1) msk = fmaxf(msk, __shfl_xor(msk, d2));
      float s = sqi2 + msk;
      mx = fmaxf(0.f, fmaxf(s, 0.01f * s));
    } else {
      float s = sqi2 + sklds[ig & (kC - 1)];
      mx = fmaxf(0.f, fmaxf(s, 0.01f * s));
    }
    float emx = __expf(-mx);
    float zs = 0.f;
    if (ok) {
      #pragma unroll 1
      for (int w8 = 0; w8 < 8; ++w8) {
        unsigned bb = bw[w8];
        #pragma unroll
        for (int q4 = 0; q4 < 8; ++q4) {
          float4 skv = *(const float4*)(sks + w8 * 32 + q4 * 4);
          unsigned nib = bb >> (q4 * 4);
          float s1 = sqi2 + skv.x, l1 = fmaxf(s1, 0.01f * s1);
          float s2 = sqi2 + skv.y, l2 = fmaxf(s2, 0.01f * s2);
          float s3 = sqi2 + skv.z, l3 = fmaxf(s3, 0.01f * s3);
          float s4 = sqi2 + skv.w, l4 = fmaxf(s4, 0.01f * s4);
          zs += (nib & 1u) ? __expf(l1 - mx) : emx;
          zs += (nib & 2u) ? __expf(l2 - mx) : emx;
          zs += (nib & 4u) ? __expf(l3 - mx) : emx;
          zs += (nib & 8u) ? __expf(l4 - mx) : emx;
        }
      }
    } else {
      zs = 256.f * emx;
      if ((ig >> 8) == seg) {
        float s = sqi2 + sklds[ig & (kC - 1)];
        float lr = fmaxf(s, 0.01f * s);
        zs += __expf(lr - mx) - emx;
      }
    }
    #pragma unroll
    for (int d2 = 1; d2 < 8; d2 <<= 1) zs += __shfl_xor(zs, d2);
    if (seg == 0) { smx[rr] = mx; szv[rr] = 1.0f / zs; }
  }
  __syncthreads();

  int f = t >> 1, h = t & 1;
  int mt_b = f >> 6;
  int lb = f & 63;
  int irow_l = mt_b * 16 + (lb & 15);
  int quad_b = lb >> 4;
  int i_g = i0 + irow_l;
  float sqi = ssq[irow_l];
  float mri = smx[irow_l];
  int joff = quad_b * 8 + h * 4;
  bool irow_ok = (i_g < kN);
  const unsigned char* bitb = (const unsigned char*)bitlds + irow_l * 256;

  auto buildP = [&](int k0, int buf) {
    float4 skv = *(const float4*)(sklds + k0 + joff);
    unsigned byte;
    if (irow_ok) {
      byte = bitb[(k0 >> 3) + quad_b];
    } else {
      int d0 = i_g - (k0 + quad_b * 8);
      byte = ((unsigned)d0 < 8u) ? (1u << d0) : 0u;
    }
    unsigned nib = byte >> (h * 4);
    unsigned short us[4];
    float sv[4] = {skv.x, skv.y, skv.z, skv.w};
    #pragma unroll
    for (int dj = 0; dj < 4; ++dj) {
      float s = sqi + sv[dj];
      float lr = fmaxf(s, 0.01f * s);
      float val = ((nib >> dj) & 1u) ? lr : 0.f;
      us[dj] = f2bf_fast(__expf(val - mri));
    }
    uint2 pk;
    pk.x = us[0] | ((unsigned)us[1] << 16);
    pk.y = us[2] | ((unsigned)us[3] << 16);
    *(uint2*)(&pshare[buf][f * 8 + h * 4]) = pk;
  };

  f32x4 acc00 = {0.f, 0.f, 0.f, 0.f}, acc01 = acc00, acc10 = acc00, acc11 = acc00;
  int m = lane & 15, quad = lane >> 4;
  int nbase = w * 32;
  const unsigned short* vtb = Vt + (size_t)b * kD * kC;
  const unsigned short* bptr0 = vtb + (size_t)(nbase + m) * kC + quad * 8;
  const unsigned short* bptr1 = vtb + (size_t)(nbase + 16 + m) * kC + quad * 8;

  buildP(0, 0);
  bfrag8 b0n = *(const bfrag8*)bptr0;
  bfrag8 b1n = *(const bfrag8*)bptr1;
  __syncthreads();

  for (int k0 = 0; k0 < kC; k0 += 32) {
    int cur = (k0 >> 5) & 1;
    bfrag8 bf0 = b0n, bf1 = b1n;
    if (k0 + 32 < kC) {
      b0n = *(const bfrag8*)(bptr0 + k0 + 32);
      b1n = *(const bfrag8*)(bptr1 + k0 + 32);
    }
    bfrag8 a0 = *(const bfrag8*)(&pshare[cur][(0 * 64 + lane) * 8]);
    bfrag8 a1 = *(const bfrag8*)(&pshare[cur][(1 * 64 + lane) * 8]);
    acc00 = mfma16(a0, bf0, acc00);
    acc01 = mfma16(a0, bf1, acc01);
    acc10 = mfma16(a1, bf0, acc10);
    acc11 = mfma16(a1, bf1, acc11);
    if (k0 + 32 < kC) buildP(k0 + 32, cur ^ 1);
    __syncthreads();
  }

  #pragma unroll
  for (int reg = 0; reg < 4; ++reg) {
    int il_a = quad * 4 + reg;
    int i_a = i0 + il_a;
    int i_b = i_a + 16;
    float za = szv[il_a];
    float zb = szv[il_a + 16];
    float* oa = outw + ((size_t)b * kC + i_a) * kD + nbase + m;
    float* ob = outw + ((size_t)b * kC + i_b) * kD + nbase + m;
    oa[0]  = acc00[reg] * za;
    oa[16] = acc01[reg] * za;
    ob[0]  = acc10[reg] * zb;
    ob[16] = acc11[reg] * zb;
  }
}

// ---------- K3: mix GEMM (K=256, 64-row tiles); mode1 writes outputs ----------
__global__ __launch_bounds__(256) void k_mix64(Raw r, int l,
    const float* __restrict__ seqb, const float* __restrict__ attnw,
    const unsigned short* __restrict__ wt, const float* __restrict__ bmix,
    float* __restrict__ featsOut, void* __restrict__ outx, float* __restrict__ part,
    int mode)
{
  __shared__ __align__(16) char smem[20480];
  unsigned short (*Ah)[64 * 40] = (unsigned short(*)[64 * 40])smem;
  unsigned short (*Al)[64 * 40] = (unsigned short(*)[64 * 40])(smem + 10240);
  constexpr int K = 256;
  int bid = blockIdx.x, t = threadIdx.x;
  int lane = t & 63, w = t >> 6, m = lane & 15, quad = lane >> 4;
  int gr0 = bid * 64;
  int b = gr0 >> 11;
  int arow = t >> 2, kq = (t & 3) * 8;
  const float* s0 = seqb  + (size_t)(gr0 + arow) * kD;
  const float* s1 = attnw + (size_t)(gr0 + arow) * kD;
  const unsigned short* wth = wt + (size_t)l * WT_LS + WT_MIXH;
  const unsigned short* wtl = wt + (size_t)l * WT_LS + WT_MIXL;
  const unsigned short* bh0p = wth + (size_t)(w * 32 + m) * K + quad * 8;
  const unsigned short* bh1p = wth + (size_t)(w * 32 + 16 + m) * K + quad * 8;
  const unsigned short* bl0p = wtl + (size_t)(w * 32 + m) * K + quad * 8;
  const unsigned short* bl1p = wtl + (size_t)(w * 32 + 16 + m) * K + quad * 8;

  auto build = [&](int kb, int buf) {
    int kg = kb + kq;
    const float* sp = (kg < kD) ? (s0 + kg) : (s1 + kg - kD);
    float4 xa = *(const float4*)sp;
    float4 xb = *(const float4*)(sp + 4);
    unsigned short h[8], lo[8];
    split2(xa.x, h[0], lo[0]); split2(xa.y, h[1], lo[1]);
    split2(xa.z, h[2], lo[2]); split2(xa.w, h[3], lo[3]);
    split2(xb.x, h[4], lo[4]); split2(xb.y, h[5], lo[5]);
    split2(xb.z, h[6], lo[6]); split2(xb.w, h[7], lo[7]);
    uint4 ph, pl;
    ph.x = h[0] | ((unsigned)h[1] << 16);  ph.y = h[2] | ((unsigned)h[3] << 16);
    ph.z = h[4] | ((unsigned)h[5] << 16);  ph.w = h[6] | ((unsigned)h[7] << 16);
    pl.x = lo[0] | ((unsigned)lo[1] << 16); pl.y = lo[2] | ((unsigned)lo[3] << 16);
    pl.z = lo[4] | ((unsigned)lo[5] << 16); pl.w = lo[6] | ((unsigned)lo[7] << 16);
    *(uint4*)&Ah[buf][arow * 40 + kq] = ph;
    *(uint4*)&Al[buf][arow * 40 + kq] = pl;
  };

  f32x4 acc[4][2];
  #pragma unroll
  for (int mi = 0; mi < 4; ++mi) { acc[mi][0] = {0.f,0.f,0.f,0.f}; acc[mi][1] = {0.f,0.f,0.f,0.f}; }

  build(0, 0);
  __syncthreads();
  for (int kb = 0; kb < K; kb += 32) {
    int cur = (kb >> 5) & 1;
    bfrag8 bh0 = *(const bfrag8*)(bh0p + kb);
    bfrag8 bh1 = *(const bfrag8*)(bh1p + kb);
    bfrag8 bl0 = *(const bfrag8*)(bl0p + kb);
    bfrag8 bl1 = *(const bfrag8*)(bl1p + kb);
    if (kb + 32 < K) build(kb + 32, cur ^ 1);
    #pragma unroll
    for (int mi = 0; mi < 4; ++mi) {
      bfrag8 ah = *(const bfrag8*)&Ah[cur][(mi * 16 + m) * 40 + quad * 8];
      bfrag8 al = *(const bfrag8*)&Al[cur][(mi * 16 + m) * 40 + quad * 8];
      acc[mi][0] = mfma16(ah, bh0, acc[mi][0]);
      acc[mi][0] = mfma16(al, bh0, acc[mi][0]);
      acc[mi][0] = mfma16(ah, bl0, acc[mi][0]);
      acc[mi][1] = mfma16(ah, bh1, acc[mi][1]);
      acc[mi][1] = mfma16(al, bh1, acc[mi][1]);
      acc[mi][1] = mfma16(ah, bl1, acc[mi][1]);
    }
    __syncthreads();
  }

  int n0 = w * 32 + m;
  float bv0 = bmix[(size_t)l * kD + n0];
  float bv1 = bmix[(size_t)l * kD + n0 + 16];
  if (mode == 0) {
    #pragma unroll
    for (int mi = 0; mi < 4; ++mi)
      #pragma unroll
      for (int reg = 0; reg < 4; ++reg) {
        size_t row = (size_t)gr0 + mi * 16 + quad * 4 + reg;
        featsOut[row * kD + n0]      = acc[mi][0][reg] + bv0;
        featsOut[row * kD + n0 + 16] = acc[mi][1][reg] + bv1;
      }
  } else {
    bool bf = sniff(r);
    float sum0 = 0.f, sum1 = 0.f;
    #pragma unroll
    for (int mi = 0; mi < 4; ++mi)
      #pragma unroll
      for (int reg = 0; reg < 4; ++reg) {
        size_t row = (size_t)gr0 + mi * 16 + quad * 4 + reg;
        float v0 = acc[mi][0][reg] + bv0;
        float v1 = acc[mi][1][reg] + bv1;
        if (bf) {
          unsigned short* o = (unsigned short*)outx + 1024;
          o[row * kD + n0]      = f2bf(v0);
          o[row * kD + n0 + 16] = f2bf(v1);
        } else {
          float* o = (float*)outx + 1024;
          o[row * kD + n0]      = v0;
          o[row * kD + n0 + 16] = v1;
        }
        sum0 += v0; sum1 += v1;
      }
    sum0 += __shfl_xor(sum0, 16); sum0 += __shfl_xor(sum0, 32);
    sum1 += __shfl_xor(sum1, 16); sum1 += __shfl_xor(sum1, 32);
    if (quad == 0) {
      atomicAdd(&part[(size_t)b * kD + n0],      sum0);
      atomicAdd(&part[(size_t)b * kD + n0 + 16], sum1);
    }
  }
}

// ---------- K4: final mean ----------
__global__ __launch_bounds__(128) void k_mean(Raw r, const float* __restrict__ part,
                                              void* __restrict__ out) {
  bool bf = sniff(r);
  int b = blockIdx.x, d = threadIdx.x;
  float v = part[(size_t)b * kD + d] * (1.0f / kC);
  if (bf) ((unsigned short*)out)[b * kD + d] = f2bf(v);
  else    ((float*)out)[b * kD + d] = v;
}

extern "C" void kernel_launch(void* const* d_in, const int* in_sizes, int n_in,
                              void* d_out, int out_size, void* d_ws, size_t ws_size,
                              hipStream_t stream) {
  Raw r;
  r.ops = d_in[0];  r.mask = d_in[1];
  r.rel = (const int*)d_in[2]; r.bidx = (const int*)d_in[3]; r.eidx = (const int*)d_in[4];
  r.ibw = d_in[5];  r.ibb = d_in[6];  r.iew = d_in[7];  r.ieb = d_in[8];
  r.bbw = d_in[9];  r.bbb = d_in[10]; r.bew = d_in[11]; r.beb = d_in[12];
  r.sw  = d_in[13]; r.sb  = d_in[14]; r.aw  = d_in[15]; r.ab  = d_in[16];
  r.scw = d_in[17]; r.scb = d_in[18]; r.aow = d_in[19]; r.aob = d_in[20];
  r.mw  = d_in[21]; r.mb  = d_in[22];

  float* ws    = (float*)d_ws;
  float* feats = ws + OF_FEATS;
  float* seq   = ws + OF_SEQ;
  float* attnw = ws + OF_ATTN;
  float* sq    = ws + OF_SQ;
  float* sk    = ws + OF_SK;
  float* u2    = ws + OF_U;
  float* part  = ws + OF_PART;
  float* bmix  = ws + OF_BMIX;
  unsigned short* wt = (unsigned short*)(ws + OF_WT);
  unsigned short*     Vt   = (unsigned short*)(ws + OF_V);
  unsigned long long* bits = (unsigned long long*)(ws + OF_V + 1048576);

  k_prep<<<RP_TOT, 256, 0, stream>>>(r, feats, bits, wt, bmix, u2, part);

  for (int l = 0; l < kL; ++l) {
    k_stage1<<<528, 256, 0, stream>>>(r, l, feats, wt, u2, seq, Vt, sq, sk);
    k_attn_pv_mfma<<<dim3(64, kB), 256, 0, stream>>>((const unsigned*)bits, sq, sk, Vt, attnw);
    k_mix64<<<256, 256, 0, stream>>>(r, l, seq, attnw, wt, bmix, feats, d_out, part,
                                     (l == kL - 1) ? 1 : 0);
  }

  k_mean<<<kB, 128, 0, stream>>>(r, part, d_out);
}

// Round 7
// 459.732 us; speedup vs baseline: 3.1362x; 1.0910x over previous
//
#include <hip/hip_runtime.h>

// Problem constants
constexpr int kB = 8;
constexpr int kN = 2046;
constexpr int kC = 2048;   // kN + 2
constexpr int kD = 128;
constexpr int kJ = 128;
constexpr int kL = 2;

typedef short bfrag8 __attribute__((ext_vector_type(8)));
typedef float f32x4 __attribute__((ext_vector_type(4)));

// ---------- bf16 helpers ----------
__device__ __forceinline__ float bf2f(unsigned short h) {
  union { unsigned u; float f; } x; x.u = ((unsigned)h) << 16; return x.f;
}
__device__ __forceinline__ unsigned short f2bf(float f) {
  union { float f; unsigned u; } x; x.f = f;
  unsigned u = x.u;
  if ((u & 0x7fffffffu) > 0x7f800000u) return (unsigned short)((u >> 16) | 0x40);
  return (unsigned short)((u + 0x7fffu + ((u >> 16) & 1u)) >> 16);
}
__device__ __forceinline__ unsigned short f2bf_fast(float f) {  // finite inputs
  union { float f; unsigned u; } x; x.f = f;
  return (unsigned short)((x.u + 0x7fffu + ((x.u >> 16) & 1u)) >> 16);
}
__device__ __forceinline__ void split2(float x, unsigned short& h, unsigned short& l) {
  unsigned short hh = f2bf_fast(x);
  h = hh;
  l = f2bf_fast(x - bf2f(hh));
}

// ---------- raw input pointers ----------
struct Raw {
  const void *ops, *mask;
  const int *rel, *bidx, *eidx;
  const void *ibw, *ibb, *iew, *ieb;       // init begin/end proj
  const void *bbw, *bbb, *bew, *beb;       // per-layer begin/end proj
  const void *sw, *sb;                     // seq_mix
  const void *aw, *ab;                     // attn_w
  const void *scw, *scb;                   // score
  const void *aow, *aob;                   // attn_out
  const void *mw, *mb;                     // mix
};

__device__ __forceinline__ float rp(const void* p, size_t i, bool bf) {
  return bf ? bf2f(((const unsigned short*)p)[i]) : ((const float*)p)[i];
}

// per-wave dtype sniff over first 1024 words of operation_features
__device__ __forceinline__ bool sniff(const Raw& r) {
  const unsigned* x = (const unsigned*)r.ops;
  int lane = (int)(threadIdx.x & 63);
  int hits = 0;
  #pragma unroll
  for (int q = 0; q < 16; ++q) {
    unsigned w = x[q * 64 + lane];
    unsigned e0 = (w >> 7) & 0xFFu;
    hits += (e0 == 0u || (e0 >= 96u && e0 <= 134u)) ? 1 : 0;
  }
  #pragma unroll
  for (int o = 1; o < 64; o <<= 1) hits += __shfl_xor(hits, o);
  return hits >= 512;
}

// ---------- workspace layout (float offsets) ----------
constexpr size_t OF_FEATS = 0;                       // 2097152
constexpr size_t OF_SEQ   = 2097152;
constexpr size_t OF_ATTN  = 4194304;
constexpr size_t OF_V     = 6291456;                 // VtF (1M floats) + bits (1M floats)
constexpr size_t OF_SQ    = 8388608;                 // 16384
constexpr size_t OF_SK    = 8404992;                 // 16384
constexpr size_t OF_U     = 8421376;                 // 2 x 272, padded 1024
constexpr size_t OF_PART  = 8422400;                 // 1024
constexpr size_t OF_BMIX  = 8423424;                 // 256
constexpr size_t OF_WT    = 8423680;                 // ushort arena

// Wt arena (ushort offsets), per-layer stride. Fragment layout:
// frag(kc, nt, lane, e): element (n = nt*16 + (lane&15), k = kc*32 + (lane>>4)*8 + e)
// addr = base + ((kc*8 + nt)*64 + lane)*8 + e        (NT = 8 for all; per-kc stride 4096)
constexpr int WT_SEQH = 0;        // K=384 (KC=12): 49152
constexpr int WT_SEQL = 49152;
constexpr int WT_VH   = 98304;    // K=128 (KC=4): 16384
constexpr int WT_VL   = 114688;
constexpr int WT_MIXH = 131072;   // K=256 (KC=8): 32768
constexpr int WT_MIXL = 163840;
constexpr int WT_LS   = 196608;

// prep role boundaries
constexpr int RP_CAST = 4092;
constexpr int RP_MASK = 8184;
constexpr int RP_WT   = 8824;
constexpr int RP_WF   = 9082;
constexpr int RP_UV   = 9084;
constexpr int RP_BE   = 9100;
constexpr int RP_TOT  = 9101;

// ---------- MFMA helper ----------
__device__ __forceinline__ f32x4 mfma16(bfrag8 a, bfrag8 b, f32x4 c) {
  return __builtin_amdgcn_mfma_f32_16x16x32_bf16(a, b, c, 0, 0, 0);
}

// ---------- K0: mega-prep ----------
__global__ __launch_bounds__(256) void k_prep(Raw r, float* __restrict__ feats,
                                              unsigned* __restrict__ bits32,
                                              unsigned short* __restrict__ wt,
                                              float* __restrict__ bmix,
                                              float* __restrict__ u2,
                                              float* __restrict__ part) {
  __shared__ __align__(16) char smem[4096];
  int bid = blockIdx.x, t = threadIdx.x;
  bool bf = sniff(r);

  if (bid < RP_CAST) {
    // cast ops -> feats rows 0..N-1
    int idx = bid * 256 + t;
    int elem = idx * 2;
    int b = elem / (kN * kD);
    int rr = elem - b * (kN * kD);
    float2 f;
    if (bf) {
      unsigned u = ((const unsigned*)r.ops)[idx];
      f.x = bf2f((unsigned short)(u & 0xffffu));
      f.y = bf2f((unsigned short)(u >> 16));
    } else {
      f = ((const float2*)r.ops)[idx];
    }
    *(float2*)(feats + (size_t)b * kC * kD + rr) = f;
  } else if (bid < RP_MASK) {
    // mask -> bit array: one wave per row, lane L owns elements L*32..L*32+31
    int wave = t >> 6, lane = t & 63;
    int rr = (bid - RP_CAST) * 4 + wave;      // 0..B*kN-1
    int b = rr / kN, i = rr - b * kN;
    unsigned chunk = 0;
    int je0 = lane * 32;
    if (bf) {
      const unsigned short* mrow = (const unsigned short*)r.mask + (size_t)rr * kN;
      if (je0 + 32 <= kN) {
        const unsigned* p32 = (const unsigned*)mrow;  // row base is 4B-aligned (kN*2 = 4092)
        #pragma unroll
        for (int g = 0; g < 16; ++g) {
          unsigned v = p32[lane * 16 + g];
          if (v & 0xFFFFu) chunk |= 1u << (g * 2);
          if (v >> 16)     chunk |= 1u << (g * 2 + 1);
        }
      } else {
        for (int jj = je0; jj < kN; ++jj)
          if (mrow[jj] != 0) chunk |= 1u << (jj - je0);
      }
    } else {
      const unsigned* mrow = (const unsigned*)r.mask + (size_t)rr * kN;
      if (je0 + 32 <= kN) {
        const uint2* p64 = (const uint2*)mrow;  // row base 8B-aligned (kN*4 = 8184)
        #pragma unroll
        for (int g = 0; g < 16; ++g) {
          uint2 v = p64[lane * 16 + g];
          if (v.x) chunk |= 1u << (g * 2);
          if (v.y) chunk |= 1u << (g * 2 + 1);
        }
      } else {
        for (int jj = je0; jj < kN; ++jj)
          if (mrow[jj] != 0) chunk |= 1u << (jj - je0);
      }
    }
    bits32[((size_t)b * kC + i) * 64 + lane] = chunk;
  } else if (bid < RP_WT) {
    // transpose+split weights into fragment layout
    int idx = (bid - RP_MASK) * 256 + t;   // < 163840
    int l = idx / 81920;
    int rr = idx - l * 81920;
    const void* src; size_t si; int dH, dL, k, n;
    if (rr < 49152) {
      k = rr >> 7; n = rr & 127;
      src = r.sw; si = (size_t)l * 49152 + (size_t)k * 128 + n;
      dH = l * WT_LS + WT_SEQH; dL = l * WT_LS + WT_SEQL;
    } else if (rr < 65536) {
      int e = rr - 49152; k = e >> 7; n = e & 127;
      src = r.aw; si = (size_t)l * 49152 + (size_t)k * 384 + 256 + n;
      dH = l * WT_LS + WT_VH; dL = l * WT_LS + WT_VL;
    } else {
      int e = rr - 65536; k = e >> 7; n = e & 127;
      src = r.mw; si = (size_t)l * 32768 + (size_t)k * 128 + n;
      dH = l * WT_LS + WT_MIXH; dL = l * WT_LS + WT_MIXL;
    }
    float v = rp(src, si, bf);
    unsigned short h, lo;
    split2(v, h, lo);
    int kc = k >> 5, q = (k >> 3) & 3, e8 = k & 7;
    int fa = ((kc * 8 + (n >> 4)) * 64 + (q * 16 + (n & 15))) * 8 + e8;
    wt[dH + fa] = h;
    wt[dL + fa] = lo;
  } else if (bid < RP_WF) {
    // fuse ao_w @ mix_bot -> mix fragments k in [128,256)
    int rb = bid - RP_WT;
    int l = rb / 129, d1 = rb - l * 129;
    if (t < 128) {
      int d = t;
      size_t mixbot = (size_t)l * 32768 + 16384;
      if (d1 < 128) {
        float acc = 0.f;
        for (int d2 = 0; d2 < kD; ++d2)
          acc += rp(r.aow, (size_t)l * 16384 + (size_t)d1 * 128 + d2, bf)
               * rp(r.mw, mixbot + (size_t)d2 * 128 + d, bf);
        unsigned short h, lo;
        split2(acc, h, lo);
        int k = 128 + d1;
        int kc = k >> 5, q = (k >> 3) & 3, e8 = k & 7;
        int fa = ((kc * 8 + (d >> 4)) * 64 + (q * 16 + (d & 15))) * 8 + e8;
        wt[l * WT_LS + WT_MIXH + fa] = h;
        wt[l * WT_LS + WT_MIXL + fa] = lo;
      } else {
        float acc = rp(r.mb, (size_t)l * 128 + d, bf);
        for (int d2 = 0; d2 < kD; ++d2)
          acc += rp(r.aob, (size_t)l * 128 + d2, bf)
               * rp(r.mw, mixbot + (size_t)d2 * 128 + d, bf);
        bmix[(size_t)l * kD + d] = acc;
      }
    }
  } else if (bid < RP_UV) {
    // u-vectors
    int l = bid - RP_WF;
    float* swm = (float*)smem;
    float* red = (float*)smem + 256;
    if (t < 128) {
      swm[t]       = rp(r.scw, (size_t)l * 256 + t, bf);
      swm[128 + t] = rp(r.scw, (size_t)l * 256 + 128 + t, bf);
    }
    __syncthreads();
    if (t < 128) {
      int k = t;
      size_t base = (size_t)l * 49152 + (size_t)k * 384;
      float uq = 0.f, uk = 0.f;
      for (int d2 = 0; d2 < kD; ++d2) {
        uq += rp(r.aw, base + d2, bf) * swm[d2];
        uk += rp(r.aw, base + 128 + d2, bf) * swm[128 + d2];
      }
      float* u = u2 + (size_t)l * 272;
      u[k] = uq; u[128 + k] = uk;
      red[k] = rp(r.ab, (size_t)l * 384 + k, bf) * swm[k]
             + rp(r.ab, (size_t)l * 384 + 128 + k, bf) * swm[128 + k];
    }
    __syncthreads();
    if (t == 0) {
      float s = rp(r.scb, l, bf);
      for (int i = 0; i < 128; ++i) s += red[i];
      u2[(size_t)l * 272 + 256] = s;
    }
  } else if (bid < RP_BE) {
    // init begin/end
    int rb = bid - RP_UV;
    int b = rb >> 1, sel = rb & 1;
    float* msh = (float*)smem;
    const int* idx = (sel ? r.eidx : r.bidx) + b * kJ;
    const void* wv = sel ? r.iew : r.ibw;
    const void* bb = sel ? r.ieb : r.ibb;
    if (t < 128) {
      int d = t;
      float acc = 0.f;
      for (int j = 0; j < kJ; ++j)
        acc += rp(r.ops, ((size_t)b * kN + idx[j]) * kD + d, bf);
      msh[d] = acc * (1.0f / kJ);
    }
    __syncthreads();
    if (t < 128) {
      int d = t;
      float o = rp(bb, d, bf);
      for (int k = 0; k < kD; ++k) o += msh[k] * rp(wv, (size_t)k * kD + d, bf);
      feats[(size_t)b * kC * kD + (size_t)(kN + sel) * kD + d] = o;
    }
  } else {
    #pragma unroll
    for (int q = 0; q < 4; ++q) part[q * 256 + t] = 0.f;
  }
}

// ---------- K1: stage1 — seq GEMM + vproj GEMM + layer begin/end ----------
__global__ __launch_bounds__(256) void k_stage1(Raw r, int l,
    const float* __restrict__ feats, const unsigned short* __restrict__ wt,
    const float* __restrict__ u2, float* __restrict__ seq,
    unsigned short* __restrict__ Vt, float* __restrict__ sq, float* __restrict__ sk)
{
  __shared__ __align__(16) char smem[21504];
  unsigned short (*Ah)[64 * 40] = (unsigned short(*)[64 * 40])smem;
  unsigned short (*Al)[64 * 40] = (unsigned short(*)[64 * 40])(smem + 10240);
  float* su = (float*)(smem + 20480);
  int bid = blockIdx.x, t = threadIdx.x;
  int lane = t & 63, w = t >> 6, m = lane & 15, quad = lane >> 4;
  bool bf = sniff(r);
  const unsigned short* wl = wt + (size_t)l * WT_LS;

  if (bid < 512) {
    bool isv = bid >= 256;
    int rb = isv ? bid - 256 : bid;
    int gr0 = rb * 64;
    int b = gr0 >> 11, r0 = gr0 & 2047;
    int arow = t >> 2, kq = (t & 3) * 8;
    int nl = r0 + arow;
    const float* fb = feats + (size_t)b * kC * kD;
    const float *s0, *s1, *s2;
    if (!isv) {
      int nr = (nl <= kN - 1) ? nl : (kN - 1);
      const int* rel = r.rel + ((size_t)b * kN + nr) * 2;
      int rpd = rel[0], rsc = rel[1];
      int p = (rpd < 0) ? kN : rpd;
      int s = (rsc < 0) ? (kN + 1) : rsc;
      s0 = fb + (size_t)nl * kD;
      s1 = fb + (size_t)p * kD;
      s2 = fb + (size_t)s * kD;
    } else {
      s0 = fb + (size_t)nl * kD; s1 = s0; s2 = s0;
      su[t] = u2[(size_t)l * 272 + t];
    }
    const int K = isv ? 128 : 384;
    const unsigned short* wth = isv ? (wl + WT_VH) : (wl + WT_SEQH);
    const unsigned short* wtl = isv ? (wl + WT_VL) : (wl + WT_SEQL);
    const unsigned short* pbh = wth + (size_t)(w * 2) * 512 + lane * 8;
    const unsigned short* pbl = wtl + (size_t)(w * 2) * 512 + lane * 8;
    float pq = 0.f, pk2 = 0.f;

    auto build = [&](int kb, int buf) {
      int kg = kb + kq;
      const float* sp;
      if (!isv) sp = (kg < 128) ? (s0 + kg) : (kg < 256) ? (s1 + kg - 128) : (s2 + kg - 256);
      else      sp = s0 + kg;
      float4 xa = *(const float4*)sp;
      float4 xb = *(const float4*)(sp + 4);
      if (isv) {
        pq  += xa.x * su[kg]     + xa.y * su[kg + 1] + xa.z * su[kg + 2] + xa.w * su[kg + 3]
             + xb.x * su[kg + 4] + xb.y * su[kg + 5] + xb.z * su[kg + 6] + xb.w * su[kg + 7];
        pk2 += xa.x * su[128 + kg]     + xa.y * su[128 + kg + 1] + xa.z * su[128 + kg + 2] + xa.w * su[128 + kg + 3]
             + xb.x * su[128 + kg + 4] + xb.y * su[128 + kg + 5] + xb.z * su[128 + kg + 6] + xb.w * su[128 + kg + 7];
      }
      unsigned short h[8], lo[8];
      split2(xa.x, h[0], lo[0]); split2(xa.y, h[1], lo[1]);
      split2(xa.z, h[2], lo[2]); split2(xa.w, h[3], lo[3]);
      split2(xb.x, h[4], lo[4]); split2(xb.y, h[5], lo[5]);
      split2(xb.z, h[6], lo[6]); split2(xb.w, h[7], lo[7]);
      uint4 ph, pl;
      ph.x = h[0] | ((unsigned)h[1] << 16);  ph.y = h[2] | ((unsigned)h[3] << 16);
      ph.z = h[4] | ((unsigned)h[5] << 16);  ph.w = h[6] | ((unsigned)h[7] << 16);
      pl.x = lo[0] | ((unsigned)lo[1] << 16); pl.y = lo[2] | ((unsigned)lo[3] << 16);
      pl.z = lo[4] | ((unsigned)lo[5] << 16); pl.w = lo[6] | ((unsigned)lo[7] << 16);
      *(uint4*)&Ah[buf][arow * 40 + kq] = ph;
      *(uint4*)&Al[buf][arow * 40 + kq] = pl;
    };

    f32x4 acc[4][2];
    #pragma unroll
    for (int mi = 0; mi < 4; ++mi) { acc[mi][0] = {0.f,0.f,0.f,0.f}; acc[mi][1] = {0.f,0.f,0.f,0.f}; }

    __syncthreads();   // su visible
    build(0, 0);
    __syncthreads();
    for (int kb = 0; kb < K; kb += 32) {
      int cur = (kb >> 5) & 1;
      int kc = kb >> 5;
      bfrag8 bh0 = *(const bfrag8*)(pbh + (size_t)kc * 4096);
      bfrag8 bh1 = *(const bfrag8*)(pbh + (size_t)kc * 4096 + 512);
      bfrag8 bl0 = {}, bl1 = {};
      if (!bf) {
        bl0 = *(const bfrag8*)(pbl + (size_t)kc * 4096);
        bl1 = *(const bfrag8*)(pbl + (size_t)kc * 4096 + 512);
      }
      if (kb + 32 < K) build(kb + 32, cur ^ 1);
      #pragma unroll
      for (int mi = 0; mi < 4; ++mi) {
        bfrag8 ah = *(const bfrag8*)&Ah[cur][(mi * 16 + m) * 40 + quad * 8];
        bfrag8 al = *(const bfrag8*)&Al[cur][(mi * 16 + m) * 40 + quad * 8];
        acc[mi][0] = mfma16(ah, bh0, acc[mi][0]);
        acc[mi][0] = mfma16(al, bh0, acc[mi][0]);
        acc[mi][1] = mfma16(ah, bh1, acc[mi][1]);
        acc[mi][1] = mfma16(al, bh1, acc[mi][1]);
        if (!bf) {
          acc[mi][0] = mfma16(ah, bl0, acc[mi][0]);
          acc[mi][1] = mfma16(ah, bl1, acc[mi][1]);
        }
      }
      __syncthreads();
    }

    int n0 = w * 32 + m;
    if (!isv) {
      float bv0 = rp(r.sb, (size_t)l * 128 + n0, bf);
      float bv1 = rp(r.sb, (size_t)l * 128 + n0 + 16, bf);
      #pragma unroll
      for (int mi = 0; mi < 4; ++mi)
        #pragma unroll
        for (int reg = 0; reg < 4; ++reg) {
          int ra = r0 + mi * 16 + quad * 4 + reg;
          if (ra < kN) {
            seq[((size_t)b * kC + ra) * kD + n0]      = acc[mi][0][reg] + bv0;
            seq[((size_t)b * kC + ra) * kD + n0 + 16] = acc[mi][1][reg] + bv1;
          }
        }
    } else {
      float bv0 = rp(r.ab, (size_t)l * 384 + 256 + n0, bf);
      float bv1 = rp(r.ab, (size_t)l * 384 + 256 + n0 + 16, bf);
      // write VtF fragment layout: frag(kc,nt,lane,e); n-tiles nt0=w*2, nt1=w*2+1
      unsigned short* vtb = Vt + (size_t)b * 262144;
      #pragma unroll
      for (int mi = 0; mi < 4; ++mi)
        #pragma unroll
        for (int reg = 0; reg < 4; ++reg) {
          int c = r0 + mi * 16 + quad * 4 + reg;
          int kc = c >> 5, cq = (c >> 3) & 3, e8 = c & 7;
          int lp = cq * 16 + m;
          vtb[((kc * 8 + w * 2) * 64 + lp) * 8 + e8]       = f2bf_fast(acc[mi][0][reg] + bv0);
          vtb[((kc * 8 + w * 2 + 1) * 64 + lp) * 8 + e8]   = f2bf_fast(acc[mi][1][reg] + bv1);
        }
      pq  += __shfl_xor(pq, 1);  pq  += __shfl_xor(pq, 2);
      pk2 += __shfl_xor(pk2, 1); pk2 += __shfl_xor(pk2, 2);
      if ((t & 3) == 0) {
        sq[(size_t)b * kC + nl] = pq + u2[(size_t)l * 272 + 256];
        sk[(size_t)b * kC + nl] = pk2;
      }
    }
  } else {
    // layer begin/end: reads feats, writes seq rows N, N+1
    int rb = bid - 512;
    int b = rb >> 1, sel = rb & 1;
    float* msh = (float*)smem;
    const int* idx = (sel ? r.eidx : r.bidx) + b * kJ;
    const void* wv = sel ? r.bew : r.bbw;
    const void* bb = sel ? r.beb : r.bbb;
    size_t wbase = (size_t)l * kD * kD, bbase = (size_t)l * kD;
    if (t < 128) {
      int d = t;
      const float* fb2 = feats + (size_t)b * kC * kD;
      float acc = 0.f;
      for (int j = 0; j < kJ; ++j) acc += fb2[(size_t)idx[j] * kD + d];
      msh[d] = acc * (1.0f / kJ);
    }
    __syncthreads();
    if (t < 128) {
      int d = t;
      float o = rp(bb, bbase + d, bf);
      for (int k = 0; k < kD; ++k) o += msh[k] * rp(wv, wbase + (size_t)k * kD + d, bf);
      seq[(size_t)b * kC * kD + (size_t)(kN + sel) * kD + d] = o;
    }
  }
}

// ---------- K2: MFMA PV with fused softmax stats ----------
__global__ __launch_bounds__(256) void k_attn_pv_mfma(
    const unsigned* __restrict__ bits,
    const float* __restrict__ sq, const float* __restrict__ sk,
    const unsigned short* __restrict__ Vt,     // fragment layout per batch (262144 ushorts)
    float* __restrict__ outw)
{
  int b = blockIdx.y;
  int i0 = blockIdx.x * 32;
  int t = threadIdx.x, lane = t & 63, w = t >> 6;

  __shared__ unsigned short pshare[2][1024];
  __shared__ float sklds[kC];
  __shared__ unsigned bitlds[2048];
  __shared__ float ssq[32], smx[32], szv[32];

  const float* skb = sk + (size_t)b * kC;
  #pragma unroll
  for (int q = 0; q < 8; ++q) sklds[q * 256 + t] = skb[q * 256 + t];
  const unsigned* bitrow = bits + ((size_t)b * kC + i0) * 64;
  #pragma unroll
  for (int q = 0; q < 8; ++q) bitlds[q * 256 + t] = bitrow[q * 256 + t];
  if (t < 32) ssq[t] = sq[(size_t)b * kC + i0 + t];
  __syncthreads();

  {
    int rr = t >> 3, seg = t & 7;
    int ig = i0 + rr;
    bool ok = (ig < kN);
    float sqi2 = ssq[rr];
    const unsigned* bw = bitlds + rr * 64 + seg * 8;
    const float* sks = sklds + seg * 256;
    float mx;
    if (ok) {
      float msk = -3e38f;
      #pragma unroll 1
      for (int w8 = 0; w8 < 8; ++w8) {
        unsigned bb = bw[w8];
        #pragma unroll
        for (int q4 = 0; q4 < 8; ++q4) {
          float4 skv = *(const float4*)(sks + w8 * 32 + q4 * 4);
          unsigned nib = bb >> (q4 * 4);
          msk = (nib & 1u) ? fmaxf(msk, skv.x) : msk;
          msk = (nib & 2u) ? fmaxf(msk, skv.y) : msk;
          msk = (nib & 4u) ? fmaxf(msk, skv.z) : msk;
          msk = (nib & 8u) ? fmaxf(msk, skv.w) : msk;
        }
      }
      #pragma unroll
      for (int d2 = 1; d2 < 8; d2 <<= 1) msk = fmaxf(msk, __shfl_xor(msk, d2));
      float s = sqi2 + msk;
      mx = fmaxf(0.f, fmaxf(s, 0.01f * s));
    } else {
      float s = sqi2 + sklds[ig & (kC - 1)];
      mx = fmaxf(0.f, fmaxf(s, 0.01f * s));
    }
    float emx = __expf(-mx);
    float zs = 0.f;
    if (ok) {
      #pragma unroll 1
      for (int w8 = 0; w8 < 8; ++w8) {
        unsigned bb = bw[w8];
        #pragma unroll
        for (int q4 = 0; q4 < 8; ++q4) {
          float4 skv = *(const float4*)(sks + w8 * 32 + q4 * 4);
          unsigned nib = bb >> (q4 * 4);
          float s1 = sqi2 + skv.x, l1 = fmaxf(s1, 0.01f * s1);
          float s2 = sqi2 + skv.y, l2 = fmaxf(s2, 0.01f * s2);
          float s3 = sqi2 + skv.z, l3 = fmaxf(s3, 0.01f * s3);
          float s4 = sqi2 + skv.w, l4 = fmaxf(s4, 0.01f * s4);
          zs += (nib & 1u) ? __expf(l1 - mx) : emx;
          zs += (nib & 2u) ? __expf(l2 - mx) : emx;
          zs += (nib & 4u) ? __expf(l3 - mx) : emx;
          zs += (nib & 8u) ? __expf(l4 - mx) : emx;
        }
      }
    } else {
      zs = 256.f * emx;
      if ((ig >> 8) == seg) {
        float s = sqi2 + sklds[ig & (kC - 1)];
        float lr = fmaxf(s, 0.01f * s);
        zs += __expf(lr - mx) - emx;
      }
    }
    #pragma unroll
    for (int d2 = 1; d2 < 8; d2 <<= 1) zs += __shfl_xor(zs, d2);
    if (seg == 0) { smx[rr] = mx; szv[rr] = 1.0f / zs; }
  }
  __syncthreads();

  int f = t >> 1, h = t & 1;
  int mt_b = f >> 6;
  int lb = f & 63;
  int irow_l = mt_b * 16 + (lb & 15);
  int quad_b = lb >> 4;
  int i_g = i0 + irow_l;
  float sqi = ssq[irow_l];
  float mri = smx[irow_l];
  int joff = quad_b * 8 + h * 4;
  bool irow_ok = (i_g < kN);
  const unsigned char* bitb = (const unsigned char*)bitlds + irow_l * 256;

  auto buildP = [&](int k0, int buf) {
    float4 skv = *(const float4*)(sklds + k0 + joff);
    unsigned byte;
    if (irow_ok) {
      byte = bitb[(k0 >> 3) + quad_b];
    } else {
      int d0 = i_g - (k0 + quad_b * 8);
      byte = ((unsigned)d0 < 8u) ? (1u << d0) : 0u;
    }
    unsigned nib = byte >> (h * 4);
    unsigned short us[4];
    float sv[4] = {skv.x, skv.y, skv.z, skv.w};
    #pragma unroll
    for (int dj = 0; dj < 4; ++dj) {
      float s = sqi + sv[dj];
      float lr = fmaxf(s, 0.01f * s);
      float val = ((nib >> dj) & 1u) ? lr : 0.f;
      us[dj] = f2bf_fast(__expf(val - mri));
    }
    uint2 pk;
    pk.x = us[0] | ((unsigned)us[1] << 16);
    pk.y = us[2] | ((unsigned)us[3] << 16);
    *(uint2*)(&pshare[buf][f * 8 + h * 4]) = pk;
  };

  f32x4 acc00 = {0.f, 0.f, 0.f, 0.f}, acc01 = acc00, acc10 = acc00, acc11 = acc00;
  int m = lane & 15, quad = lane >> 4;
  int nbase = w * 32;
  // VtF fragment loads: coalesced, nt0 = w*2, nt1 = w*2+1, per-kc stride 4096
  const unsigned short* vtb = Vt + (size_t)b * 262144;
  const unsigned short* p0 = vtb + (size_t)(w * 2) * 512 + lane * 8;
  const unsigned short* p1 = p0 + 512;

  buildP(0, 0);
  bfrag8 b0n = *(const bfrag8*)p0;
  bfrag8 b1n = *(const bfrag8*)p1;
  __syncthreads();

  for (int k0 = 0; k0 < kC; k0 += 32) {
    int cur = (k0 >> 5) & 1;
    bfrag8 bf0 = b0n, bf1 = b1n;
    if (k0 + 32 < kC) {
      size_t off = (size_t)((k0 >> 5) + 1) * 4096;
      b0n = *(const bfrag8*)(p0 + off);
      b1n = *(const bfrag8*)(p1 + off);
    }
    bfrag8 a0 = *(const bfrag8*)(&pshare[cur][(0 * 64 + lane) * 8]);
    bfrag8 a1 = *(const bfrag8*)(&pshare[cur][(1 * 64 + lane) * 8]);
    acc00 = mfma16(a0, bf0, acc00);
    acc01 = mfma16(a0, bf1, acc01);
    acc10 = mfma16(a1, bf0, acc10);
    acc11 = mfma16(a1, bf1, acc11);
    if (k0 + 32 < kC) buildP(k0 + 32, cur ^ 1);
    __syncthreads();
  }

  #pragma unroll
  for (int reg = 0; reg < 4; ++reg) {
    int il_a = quad * 4 + reg;
    int i_a = i0 + il_a;
    int i_b = i_a + 16;
    float za = szv[il_a];
    float zb = szv[il_a + 16];
    float* oa = outw + ((size_t)b * kC + i_a) * kD + nbase + m;
    float* ob = outw + ((size_t)b * kC + i_b) * kD + nbase + m;
    oa[0]  = acc00[reg] * za;
    oa[16] = acc01[reg] * za;
    ob[0]  = acc10[reg] * zb;
    ob[16] = acc11[reg] * zb;
  }
}

// ---------- K3: mix GEMM (K=256, 64-row tiles); mode1 writes outputs ----------
__global__ __launch_bounds__(256) void k_mix64(Raw r, int l,
    const float* __restrict__ seqb, const float* __restrict__ attnw,
    const unsigned short* __restrict__ wt, const float* __restrict__ bmix,
    float* __restrict__ featsOut, void* __restrict__ outx, float* __restrict__ part,
    int mode)
{
  __shared__ __align__(16) char smem[20480];
  unsigned short (*Ah)[64 * 40] = (unsigned short(*)[64 * 40])smem;
  unsigned short (*Al)[64 * 40] = (unsigned short(*)[64 * 40])(smem + 10240);
  constexpr int K = 256;
  int bid = blockIdx.x, t = threadIdx.x;
  int lane = t & 63, w = t >> 6, m = lane & 15, quad = lane >> 4;
  bool bf = sniff(r);
  int gr0 = bid * 64;
  int b = gr0 >> 11;
  int arow = t >> 2, kq = (t & 3) * 8;
  const float* s0 = seqb  + (size_t)(gr0 + arow) * kD;
  const float* s1 = attnw + (size_t)(gr0 + arow) * kD;
  const unsigned short* wth = wt + (size_t)l * WT_LS + WT_MIXH;
  const unsigned short* wtl = wt + (size_t)l * WT_LS + WT_MIXL;
  const unsigned short* pbh = wth + (size_t)(w * 2) * 512 + lane * 8;
  const unsigned short* pbl = wtl + (size_t)(w * 2) * 512 + lane * 8;

  auto build = [&](int kb, int buf) {
    int kg = kb + kq;
    const float* sp = (kg < kD) ? (s0 + kg) : (s1 + kg - kD);
    float4 xa = *(const float4*)sp;
    float4 xb = *(const float4*)(sp + 4);
    unsigned short h[8], lo[8];
    split2(xa.x, h[0], lo[0]); split2(xa.y, h[1], lo[1]);
    split2(xa.z, h[2], lo[2]); split2(xa.w, h[3], lo[3]);
    split2(xb.x, h[4], lo[4]); split2(xb.y, h[5], lo[5]);
    split2(xb.z, h[6], lo[6]); split2(xb.w, h[7], lo[7]);
    uint4 ph, pl;
    ph.x = h[0] | ((unsigned)h[1] << 16);  ph.y = h[2] | ((unsigned)h[3] << 16);
    ph.z = h[4] | ((unsigned)h[5] << 16);  ph.w = h[6] | ((unsigned)h[7] << 16);
    pl.x = lo[0] | ((unsigned)lo[1] << 16); pl.y = lo[2] | ((unsigned)lo[3] << 16);
    pl.z = lo[4] | ((unsigned)lo[5] << 16); pl.w = lo[6] | ((unsigned)lo[7] << 16);
    *(uint4*)&Ah[buf][arow * 40 + kq] = ph;
    *(uint4*)&Al[buf][arow * 40 + kq] = pl;
  };

  f32x4 acc[4][2];
  #pragma unroll
  for (int mi = 0; mi < 4; ++mi) { acc[mi][0] = {0.f,0.f,0.f,0.f}; acc[mi][1] = {0.f,0.f,0.f,0.f}; }

  build(0, 0);
  __syncthreads();
  for (int kb = 0; kb < K; kb += 32) {
    int cur = (kb >> 5) & 1;
    int kc = kb >> 5;
    bfrag8 bh0 = *(const bfrag8*)(pbh + (size_t)kc * 4096);
    bfrag8 bh1 = *(const bfrag8*)(pbh + (size_t)kc * 4096 + 512);
    bfrag8 bl0 = {}, bl1 = {};
    if (!bf) {
      bl0 = *(const bfrag8*)(pbl + (size_t)kc * 4096);
      bl1 = *(const bfrag8*)(pbl + (size_t)kc * 4096 + 512);
    }
    if (kb + 32 < K) build(kb + 32, cur ^ 1);
    #pragma unroll
    for (int mi = 0; mi < 4; ++mi) {
      bfrag8 ah = *(const bfrag8*)&Ah[cur][(mi * 16 + m) * 40 + quad * 8];
      bfrag8 al = *(const bfrag8*)&Al[cur][(mi * 16 + m) * 40 + quad * 8];
      acc[mi][0] = mfma16(ah, bh0, acc[mi][0]);
      acc[mi][0] = mfma16(al, bh0, acc[mi][0]);
      acc[mi][1] = mfma16(ah, bh1, acc[mi][1]);
      acc[mi][1] = mfma16(al, bh1, acc[mi][1]);
      if (!bf) {
        acc[mi][0] = mfma16(ah, bl0, acc[mi][0]);
        acc[mi][1] = mfma16(ah, bl1, acc[mi][1]);
      }
    }
    __syncthreads();
  }

  int n0 = w * 32 + m;
  float bv0 = bmix[(size_t)l * kD + n0];
  float bv1 = bmix[(size_t)l * kD + n0 + 16];
  if (mode == 0) {
    #pragma unroll
    for (int mi = 0; mi < 4; ++mi)
      #pragma unroll
      for (int reg = 0; reg < 4; ++reg) {
        size_t row = (size_t)gr0 + mi * 16 + quad * 4 + reg;
        featsOut[row * kD + n0]      = acc[mi][0][reg] + bv0;
        featsOut[row * kD + n0 + 16] = acc[mi][1][reg] + bv1;
      }
  } else {
    float sum0 = 0.f, sum1 = 0.f;
    #pragma unroll
    for (int mi = 0; mi < 4; ++mi)
      #pragma unroll
      for (int reg = 0; reg < 4; ++reg) {
        size_t row = (size_t)gr0 + mi * 16 + quad * 4 + reg;
        float v0 = acc[mi][0][reg] + bv0;
        float v1 = acc[mi][1][reg] + bv1;
        if (bf) {
          unsigned short* o = (unsigned short*)outx + 1024;
          o[row * kD + n0]      = f2bf(v0);
          o[row * kD + n0 + 16] = f2bf(v1);
        } else {
          float* o = (float*)outx + 1024;
          o[row * kD + n0]      = v0;
          o[row * kD + n0 + 16] = v1;
        }
        sum0 += v0; sum1 += v1;
      }
    sum0 += __shfl_xor(sum0, 16); sum0 += __shfl_xor(sum0, 32);
    sum1 += __shfl_xor(sum1, 16); sum1 += __shfl_xor(sum1, 32);
    if (quad == 0) {
      atomicAdd(&part[(size_t)b * kD + n0],      sum0);
      atomicAdd(&part[(size_t)b * kD + n0 + 16], sum1);
    }
  }
}

// ---------- K4: final mean ----------
__global__ __launch_bounds__(128) void k_mean(Raw r, const float* __restrict__ part,
                                              void* __restrict__ out) {
  bool bf = sniff(r);
  int b = blockIdx.x, d = threadIdx.x;
  float v = part[(size_t)b * kD + d] * (1.0f / kC);
  if (bf) ((unsigned short*)out)[b * kD + d] = f2bf(v);
  else    ((float*)out)[b * kD + d] = v;
}

extern "C" void kernel_launch(void* const* d_in, const int* in_sizes, int n_in,
                              void* d_out, int out_size, void* d_ws, size_t ws_size,
                              hipStream_t stream) {
  Raw r;
  r.ops = d_in[0];  r.mask = d_in[1];
  r.rel = (const int*)d_in[2]; r.bidx = (const int*)d_in[3]; r.eidx = (const int*)d_in[4];
  r.ibw = d_in[5];  r.ibb = d_in[6];  r.iew = d_in[7];  r.ieb = d_in[8];
  r.bbw = d_in[9];  r.bbb = d_in[10]; r.bew = d_in[11]; r.beb = d_in[12];
  r.sw  = d_in[13]; r.sb  = d_in[14]; r.aw  = d_in[15]; r.ab  = d_in[16];
  r.scw = d_in[17]; r.scb = d_in[18]; r.aow = d_in[19]; r.aob = d_in[20];
  r.mw  = d_in[21]; r.mb  = d_in[22];

  float* ws    = (float*)d_ws;
  float* feats = ws + OF_FEATS;
  float* seq   = ws + OF_SEQ;
  float* attnw = ws + OF_ATTN;
  float* sq    = ws + OF_SQ;
  float* sk    = ws + OF_SK;
  float* u2    = ws + OF_U;
  float* part  = ws + OF_PART;
  float* bmix  = ws + OF_BMIX;
  unsigned short* wt = (unsigned short*)(ws + OF_WT);
  unsigned short* Vt = (unsigned short*)(ws + OF_V);
  unsigned*     bits = (unsigned*)(ws + OF_V + 1048576);

  k_prep<<<RP_TOT, 256, 0, stream>>>(r, feats, bits, wt, bmix, u2, part);

  for (int l = 0; l < kL; ++l) {
    k_stage1<<<528, 256, 0, stream>>>(r, l, feats, wt, u2, seq, Vt, sq, sk);
    k_attn_pv_mfma<<<dim3(64, kB), 256, 0, stream>>>(bits, sq, sk, Vt, attnw);
    k_mix64<<<256, 256, 0, stream>>>(r, l, seq, attnw, wt, bmix, feats, d_out, part,
                                     (l == kL - 1) ? 1 : 0);
  }

  k_mean<<<kB, 128, 0, stream>>>(r, part, d_out);
}